// Round 1
// baseline (4762.745 us; speedup 1.0000x reference)
//
#include <hip/hip_runtime.h>
#include <hip/hip_bf16.h>
#include <cmath>

#define B_   2
#define L_   512
#define HID  2048
#define DH   128
#define NH   8
#define NHH  2
#define ROWS 1024  // B_*L_

typedef float  f32x4  __attribute__((ext_vector_type(4)));
typedef __bf16 bf16x8 __attribute__((ext_vector_type(8)));

#define AS1(p) ((const __attribute__((address_space(1))) unsigned int*)(p))
#define AS3(p) ((__attribute__((address_space(3))) unsigned int*)(p))

// ---------------- f32 -> bf16 elementwise ----------------
__global__ void f2bf_kernel(const float* __restrict__ in, __hip_bfloat16* __restrict__ out, int n) {
  int i = blockIdx.x * 256 + threadIdx.x;
  if (i < n) out[i] = __float2bfloat16(in[i]);
}

// ---------------- f32 (K x N) -> bf16 transposed (N x K) ----------------
__global__ __launch_bounds__(256) void transpose_f2bf(const float* __restrict__ in,
                                                      __hip_bfloat16* __restrict__ out,
                                                      int K, int N) {
  __shared__ float tile[32][33];
  int n0 = blockIdx.x * 32, k0 = blockIdx.y * 32;
  int tx = threadIdx.x, ty = threadIdx.y;  // 32 x 8
#pragma unroll
  for (int i = 0; i < 32; i += 8)
    tile[ty + i][tx] = in[(size_t)(k0 + ty + i) * N + n0 + tx];
  __syncthreads();
#pragma unroll
  for (int i = 0; i < 32; i += 8)
    out[(size_t)(n0 + ty + i) * K + k0 + tx] = __float2bfloat16(tile[tx][ty + i]);
}

// ---------------- bf16 MFMA GEMM: C(MxN) = A(MxK) * BT(NxK)^T ----------------
// 128x128 tile, BK=32, 4 waves (2x2), 4x4 frags of 16x16x32 per wave.
__global__ __launch_bounds__(256) void gemm_bf16(const __hip_bfloat16* __restrict__ A,
                                                 const __hip_bfloat16* __restrict__ BT,
                                                 float* __restrict__ C, int M, int N, int K) {
  __shared__ __align__(16) __hip_bfloat16 lA[128 * 32];
  __shared__ __align__(16) __hip_bfloat16 lB[128 * 32];
  const int tid = threadIdx.x;
  const int lane = tid & 63;
  const int w = tid >> 6;
  const int wr = w >> 1, wc = w & 1;
  const int row0 = blockIdx.y * 128;
  const int col0 = blockIdx.x * 128;
  f32x4 acc[4][4];
#pragma unroll
  for (int m = 0; m < 4; ++m)
#pragma unroll
    for (int n = 0; n < 4; ++n) acc[m][n] = {0.f, 0.f, 0.f, 0.f};
  const int fr = lane & 15;
  const int ko = (lane >> 4) * 8;
  for (int kt = 0; kt < K; kt += 32) {
#pragma unroll
    for (int i = 0; i < 2; ++i) {
      int elem = (w * 2 + i) * 512 + lane * 8;   // linear elem this lane stages
      int rr = elem >> 5, cc = elem & 31;
      const __hip_bfloat16* srcA = A + (size_t)(row0 + rr) * K + kt + cc;
      __builtin_amdgcn_global_load_lds(AS1(srcA), AS3(&lA[(w * 2 + i) * 512]), 16, 0, 0);
      const __hip_bfloat16* srcB = BT + (size_t)(col0 + rr) * K + kt + cc;
      __builtin_amdgcn_global_load_lds(AS1(srcB), AS3(&lB[(w * 2 + i) * 512]), 16, 0, 0);
    }
    __syncthreads();
    bf16x8 af[4], bfr[4];
#pragma unroll
    for (int m = 0; m < 4; ++m)
      af[m] = *reinterpret_cast<const bf16x8*>(&lA[(wr * 64 + m * 16 + fr) * 32 + ko]);
#pragma unroll
    for (int n = 0; n < 4; ++n)
      bfr[n] = *reinterpret_cast<const bf16x8*>(&lB[(wc * 64 + n * 16 + fr) * 32 + ko]);
#pragma unroll
    for (int m = 0; m < 4; ++m)
#pragma unroll
      for (int n = 0; n < 4; ++n)
        acc[m][n] = __builtin_amdgcn_mfma_f32_16x16x32_bf16(af[m], bfr[n], acc[m][n], 0, 0, 0);
    __syncthreads();
  }
  const int rq = (lane >> 4) * 4;
#pragma unroll
  for (int m = 0; m < 4; ++m)
#pragma unroll
    for (int n = 0; n < 4; ++n)
#pragma unroll
      for (int r = 0; r < 4; ++r)
        C[(size_t)(row0 + wr * 64 + m * 16 + rq + r) * N + (col0 + wc * 64 + n * 16 + fr)] =
            acc[m][n][r];
}

// ---------------- small GEMM for Wb (16 cols) and Wa (8 cols), f32 ----------------
__global__ void small_gemm_ba(const float* __restrict__ x, const float* __restrict__ Wb,
                              const float* __restrict__ Wa, float* __restrict__ xb,
                              float* __restrict__ xa) {
  int row = blockIdx.x;
  int col = blockIdx.y;   // 0..23
  int lane = threadIdx.x; // 0..63
  float acc = 0.f;
  if (col < 16) {
    for (int k = lane; k < HID; k += 64) acc += x[(size_t)row * HID + k] * Wb[(size_t)k * 16 + col];
  } else {
    int c = col - 16;
    for (int k = lane; k < HID; k += 64) acc += x[(size_t)row * HID + k] * Wa[(size_t)k * 8 + c];
  }
#pragma unroll
  for (int off = 32; off; off >>= 1) acc += __shfl_down(acc, off);
  if (lane == 0) {
    if (col < 16) xb[(size_t)row * 16 + col] = acc;
    else          xa[(size_t)row * 8 + (col - 16)] = acc;
  }
}

__device__ __forceinline__ float silu_f(float y) { return y / (1.f + __expf(-y)); }

// ---------------- conv + silu + l2norm for q; writes q_s[bh][t][d] ----------------
__global__ __launch_bounds__(128) void conv_q_kernel(const float* __restrict__ qlin,
                                                     const float* __restrict__ wq,
                                                     float* __restrict__ q_s) {
  int bt = blockIdx.x;  // b*512 + t
  int h  = blockIdx.y;  // 0..7
  int d  = threadIdx.x; // 0..127
  int b = bt >> 9, t = bt & 511;
  int c = h * 128 + d;
  float y = 0.f;
#pragma unroll
  for (int tau = 0; tau < 4; ++tau) {
    int tt = t - 3 + tau;
    float xv = (tt >= 0) ? qlin[(size_t)(b * 512 + tt) * 1024 + c] : 0.f;
    y += xv * wq[c * 4 + tau];
  }
  y = silu_f(y);
  __shared__ float red[2];
  float ss = y * y;
#pragma unroll
  for (int off = 32; off; off >>= 1) ss += __shfl_down(ss, off);
  if ((d & 63) == 0) red[d >> 6] = ss;
  __syncthreads();
  float nrm = sqrtf(red[0] + red[1]);
  float scale = (1.f / fmaxf(nrm, 1e-12f)) * 0.08838834764831845f;  // 1/sqrt(128)
  int bh = b * 8 + h;
  q_s[((size_t)bh * 512 + t) * 128 + d] = y * scale;
}

// ---------------- conv + silu + l2norm for k; writes k_s[bh][j][t][d] ----------------
__global__ __launch_bounds__(128) void conv_k_kernel(const float* __restrict__ klin,
                                                     const float* __restrict__ wk,
                                                     float* __restrict__ k_s) {
  int bt = blockIdx.x;
  int jh = blockIdx.y;  // j*8 + h
  int d  = threadIdx.x;
  int b = bt >> 9, t = bt & 511;
  int j = jh >> 3, h = jh & 7;
  int c = j * 1024 + h * 128 + d;
  float y = 0.f;
#pragma unroll
  for (int tau = 0; tau < 4; ++tau) {
    int tt = t - 3 + tau;
    float xv = (tt >= 0) ? klin[(size_t)(b * 512 + tt) * 2048 + c] : 0.f;
    y += xv * wk[c * 4 + tau];
  }
  y = silu_f(y);
  __shared__ float red[2];
  float ss = y * y;
#pragma unroll
  for (int off = 32; off; off >>= 1) ss += __shfl_down(ss, off);
  if ((d & 63) == 0) red[d >> 6] = ss;
  __syncthreads();
  float nrm = sqrtf(red[0] + red[1]);
  float scale = 1.f / fmaxf(nrm, 1e-12f);
  int bh = b * 8 + h;
  k_s[(((size_t)bh * 2 + j) * 512 + t) * 128 + d] = y * scale;
}

// ---------------- conv + silu for v; writes v_s[bh][j][t][d] ----------------
__global__ __launch_bounds__(128) void conv_v_kernel(const float* __restrict__ vlin,
                                                     const float* __restrict__ wv,
                                                     float* __restrict__ v_s) {
  int bt = blockIdx.x;
  int jh = blockIdx.y;
  int d  = threadIdx.x;
  int b = bt >> 9, t = bt & 511;
  int j = jh >> 3, h = jh & 7;
  int c = j * 1024 + h * 128 + d;
  float y = 0.f;
#pragma unroll
  for (int tau = 0; tau < 4; ++tau) {
    int tt = t - 3 + tau;
    float xv = (tt >= 0) ? vlin[(size_t)(b * 512 + tt) * 2048 + c] : 0.f;
    y += xv * wv[c * 4 + tau];
  }
  int bh = b * 8 + h;
  v_s[(((size_t)bh * 2 + j) * 512 + t) * 128 + d] = silu_f(y);
}

// ---------------- beta / exp(g) ----------------
__global__ void bg_kernel(const float* __restrict__ xb, const float* __restrict__ xa,
                          const float* __restrict__ A_log, const float* __restrict__ dt_bias,
                          float* __restrict__ beta_s, float* __restrict__ ge_s) {
  int bt = blockIdx.x;   // b*512 + t
  int i = threadIdx.x;   // 0..31, active 0..23
  int b = bt >> 9, t = bt & 511;
  if (i < 16) {
    int j = i >> 3, h = i & 7;
    float v = xb[(size_t)bt * 16 + i];
    float bv = 2.f / (1.f + __expf(-v));
    beta_s[(((size_t)(b * 8 + h)) * 2 + j) * 512 + t] = bv;
  } else if (i < 24) {
    int h = i - 16;
    float v = xa[(size_t)bt * 8 + h] + dt_bias[h];
    float sp = (v > 20.f) ? v : log1pf(__expf(v));
    float g = -__expf(A_log[h]) * sp;
    ge_s[((size_t)(b * 8 + h)) * 512 + t] = __expf(g);
  }
}

// ---------------- sequential gated delta-product scan ----------------
// 16 blocks (b,h), 128 threads (v). Thread v owns state column S[:,v] in VGPRs.
__global__ __launch_bounds__(128) void scan_kernel(const float* __restrict__ q_s,
                                                   const float* __restrict__ k_s,
                                                   const float* __restrict__ v_s,
                                                   const float* __restrict__ beta_s,
                                                   const float* __restrict__ ge_s,
                                                   float* __restrict__ o_s,
                                                   float* __restrict__ state_out) {
  int bh = blockIdx.x;
  int v = threadIdx.x;
  float st[128];
#pragma unroll
  for (int i = 0; i < 128; ++i) st[i] = 0.f;
  const float* qp0  = q_s + (size_t)bh * 512 * 128;
  const float* k0p0 = k_s + ((size_t)bh * 2 + 0) * 512 * 128;
  const float* k1p0 = k_s + ((size_t)bh * 2 + 1) * 512 * 128;
  const float* v0p0 = v_s + ((size_t)bh * 2 + 0) * 512 * 128;
  const float* v1p0 = v_s + ((size_t)bh * 2 + 1) * 512 * 128;
  const float* b0p = beta_s + ((size_t)bh * 2 + 0) * 512;
  const float* b1p = beta_s + ((size_t)bh * 2 + 1) * 512;
  const float* gp  = ge_s + (size_t)bh * 512;
  for (int t = 0; t < 512; ++t) {
    float eg = gp[t];
    float bb0 = b0p[t], bb1 = b1p[t];
    float mv0 = v0p0[(size_t)t * 128 + v];
    float mv1 = v1p0[(size_t)t * 128 + v];
    const float* k0 = k0p0 + (size_t)t * 128;
    const float* k1 = k1p0 + (size_t)t * 128;
    const float* qq = qp0 + (size_t)t * 128;
    // pass 1: decay + corr0
    float c0 = 0, c1 = 0, c2 = 0, c3 = 0;
#pragma unroll
    for (int i = 0; i < 128; i += 4) {
      st[i]     *= eg; c0 += k0[i]     * st[i];
      st[i + 1] *= eg; c1 += k0[i + 1] * st[i + 1];
      st[i + 2] *= eg; c2 += k0[i + 2] * st[i + 2];
      st[i + 3] *= eg; c3 += k0[i + 3] * st[i + 3];
    }
    float u0 = (mv0 - ((c0 + c1) + (c2 + c3))) * bb0;
    // pass 2: update j0 + corr1 (fused)
    c0 = c1 = c2 = c3 = 0;
#pragma unroll
    for (int i = 0; i < 128; i += 4) {
      st[i]     += k0[i]     * u0; c0 += k1[i]     * st[i];
      st[i + 1] += k0[i + 1] * u0; c1 += k1[i + 1] * st[i + 1];
      st[i + 2] += k0[i + 2] * u0; c2 += k1[i + 2] * st[i + 2];
      st[i + 3] += k0[i + 3] * u0; c3 += k1[i + 3] * st[i + 3];
    }
    float u1 = (mv1 - ((c0 + c1) + (c2 + c3))) * bb1;
    // pass 3: update j1 + output (fused)
    float o0 = 0, o1 = 0, o2 = 0, o3 = 0;
#pragma unroll
    for (int i = 0; i < 128; i += 4) {
      st[i]     += k1[i]     * u1; o0 += qq[i]     * st[i];
      st[i + 1] += k1[i + 1] * u1; o1 += qq[i + 1] * st[i + 1];
      st[i + 2] += k1[i + 2] * u1; o2 += qq[i + 2] * st[i + 2];
      st[i + 3] += k1[i + 3] * u1; o3 += qq[i + 3] * st[i + 3];
    }
    o_s[((size_t)bh * 512 + t) * 128 + v] = (o0 + o1) + (o2 + o3);
  }
#pragma unroll
  for (int i = 0; i < 128; ++i)
    state_out[((size_t)bh * 128 + i) * 128 + v] = st[i];
}

// ---------------- rmsnorm + gate silu -> bf16 A for final GEMM ----------------
__global__ __launch_bounds__(128) void post_kernel(const float* __restrict__ o_s,
                                                   const float* __restrict__ g_lin,
                                                   const float* __restrict__ norm_w,
                                                   __hip_bfloat16* __restrict__ Afin) {
  int bt = blockIdx.x;  // b*512 + t
  int h = blockIdx.y;
  int d = threadIdx.x;
  int b = bt >> 9, t = bt & 511;
  int bh = b * 8 + h;
  float o = o_s[((size_t)bh * 512 + t) * 128 + d];
  __shared__ float red[2];
  float ss = o * o;
#pragma unroll
  for (int off = 32; off; off >>= 1) ss += __shfl_down(ss, off);
  if ((d & 63) == 0) red[d >> 6] = ss;
  __syncthreads();
  float mean = (red[0] + red[1]) * (1.f / 128.f);
  float r = rsqrtf(mean + 1e-5f);
  float gate = g_lin[(size_t)bt * 1024 + h * 128 + d];
  float val = o * r * norm_w[d] * silu_f(gate);
  Afin[(size_t)bt * 1024 + h * 128 + d] = __float2bfloat16(val);
}

extern "C" void kernel_launch(void* const* d_in, const int* in_sizes, int n_in,
                              void* d_out, int out_size, void* d_ws, size_t ws_size,
                              hipStream_t stream) {
  const float* x       = (const float*)d_in[0];
  const float* Wq      = (const float*)d_in[1];
  const float* Wk      = (const float*)d_in[2];
  const float* Wv      = (const float*)d_in[3];
  const float* Wb      = (const float*)d_in[4];
  const float* Wa      = (const float*)d_in[5];
  const float* A_log   = (const float*)d_in[6];
  const float* dt_bias = (const float*)d_in[7];
  const float* cqw     = (const float*)d_in[8];
  const float* ckw     = (const float*)d_in[9];
  const float* cvw     = (const float*)d_in[10];
  const float* Wg      = (const float*)d_in[11];
  const float* norm_w  = (const float*)d_in[12];
  const float* Wo      = (const float*)d_in[13];

  char* ws = (char*)d_ws;
  size_t off = 0;
  auto alloc = [&](size_t bytes) {
    void* p = ws + off;
    off += (bytes + 255) & ~(size_t)255;
    return p;
  };
  __hip_bfloat16* xbf  = (__hip_bfloat16*)alloc((size_t)2097152 * 2);
  __hip_bfloat16* WqT  = (__hip_bfloat16*)alloc((size_t)2097152 * 2);
  __hip_bfloat16* WkT  = (__hip_bfloat16*)alloc((size_t)4194304 * 2);
  __hip_bfloat16* WvT  = (__hip_bfloat16*)alloc((size_t)4194304 * 2);
  __hip_bfloat16* WgT  = (__hip_bfloat16*)alloc((size_t)2097152 * 2);
  __hip_bfloat16* WoT  = (__hip_bfloat16*)alloc((size_t)2097152 * 2);
  float* q_lin  = (float*)alloc((size_t)1048576 * 4);
  float* k_lin  = (float*)alloc((size_t)2097152 * 4);
  float* v_lin  = (float*)alloc((size_t)2097152 * 4);
  float* g_lin  = (float*)alloc((size_t)1048576 * 4);
  float* xb     = (float*)alloc((size_t)16384 * 4);
  float* xa     = (float*)alloc((size_t)8192 * 4);
  float* q_s    = (float*)alloc((size_t)1048576 * 4);
  float* k_s    = (float*)alloc((size_t)2097152 * 4);
  float* v_s    = (float*)alloc((size_t)2097152 * 4);
  float* beta_s = (float*)alloc((size_t)16384 * 4);
  float* ge_s   = (float*)alloc((size_t)8192 * 4);
  float* o_s    = (float*)alloc((size_t)1048576 * 4);
  __hip_bfloat16* Afin = (__hip_bfloat16*)alloc((size_t)1048576 * 2);

  float* out_main  = (float*)d_out;
  float* out_state = out_main + 2097152;

  dim3 tb(32, 8);
  f2bf_kernel<<<8192, 256, 0, stream>>>(x, xbf, 2097152);
  transpose_f2bf<<<dim3(32, 64), tb, 0, stream>>>(Wq, WqT, 2048, 1024);
  transpose_f2bf<<<dim3(64, 64), tb, 0, stream>>>(Wk, WkT, 2048, 2048);
  transpose_f2bf<<<dim3(64, 64), tb, 0, stream>>>(Wv, WvT, 2048, 2048);
  transpose_f2bf<<<dim3(32, 64), tb, 0, stream>>>(Wg, WgT, 2048, 1024);
  transpose_f2bf<<<dim3(64, 32), tb, 0, stream>>>(Wo, WoT, 1024, 2048);

  gemm_bf16<<<dim3(8, 8),  256, 0, stream>>>(xbf, WqT, q_lin, 1024, 1024, 2048);
  gemm_bf16<<<dim3(16, 8), 256, 0, stream>>>(xbf, WkT, k_lin, 1024, 2048, 2048);
  gemm_bf16<<<dim3(16, 8), 256, 0, stream>>>(xbf, WvT, v_lin, 1024, 2048, 2048);
  gemm_bf16<<<dim3(8, 8),  256, 0, stream>>>(xbf, WgT, g_lin, 1024, 1024, 2048);
  small_gemm_ba<<<dim3(1024, 24), 64, 0, stream>>>(x, Wb, Wa, xb, xa);

  conv_q_kernel<<<dim3(1024, 8),  128, 0, stream>>>(q_lin, cqw, q_s);
  conv_k_kernel<<<dim3(1024, 16), 128, 0, stream>>>(k_lin, ckw, k_s);
  conv_v_kernel<<<dim3(1024, 16), 128, 0, stream>>>(v_lin, cvw, v_s);
  bg_kernel<<<1024, 32, 0, stream>>>(xb, xa, A_log, dt_bias, beta_s, ge_s);

  scan_kernel<<<16, 128, 0, stream>>>(q_s, k_s, v_s, beta_s, ge_s, o_s, out_state);

  post_kernel<<<dim3(1024, 8), 128, 0, stream>>>(o_s, g_lin, norm_w, Afin);
  gemm_bf16<<<dim3(16, 8), 256, 0, stream>>>(Afin, WoT, out_main, 1024, 2048, 1024);
}

// Round 2
// 2182.026 us; speedup vs baseline: 2.1827x; 2.1827x over previous
//
#include <hip/hip_runtime.h>
#include <hip/hip_bf16.h>
#include <cmath>

#define B_   2
#define L_   512
#define HID  2048
#define DH   128
#define NH   8
#define NHH  2
#define ROWS 1024  // B_*L_

typedef float  f32x4  __attribute__((ext_vector_type(4)));
typedef __bf16 bf16x8 __attribute__((ext_vector_type(8)));

#define AS1(p) ((const __attribute__((address_space(1))) unsigned int*)(p))
#define AS3(p) ((__attribute__((address_space(3))) unsigned int*)(p))

// ---------------- f32 -> bf16 elementwise ----------------
__global__ void f2bf_kernel(const float* __restrict__ in, __hip_bfloat16* __restrict__ out, int n) {
  int i = blockIdx.x * 256 + threadIdx.x;
  if (i < n) out[i] = __float2bfloat16(in[i]);
}

// ---------------- f32 (K x N) -> bf16 transposed (N x K) ----------------
__global__ __launch_bounds__(256) void transpose_f2bf(const float* __restrict__ in,
                                                      __hip_bfloat16* __restrict__ out,
                                                      int K, int N) {
  __shared__ float tile[32][33];
  int n0 = blockIdx.x * 32, k0 = blockIdx.y * 32;
  int tx = threadIdx.x, ty = threadIdx.y;  // 32 x 8
#pragma unroll
  for (int i = 0; i < 32; i += 8)
    tile[ty + i][tx] = in[(size_t)(k0 + ty + i) * N + n0 + tx];
  __syncthreads();
#pragma unroll
  for (int i = 0; i < 32; i += 8)
    out[(size_t)(n0 + ty + i) * K + k0 + tx] = __float2bfloat16(tile[tx][ty + i]);
}

// ---------------- bf16 MFMA GEMM: C(MxN) = A(MxK) * BT(NxK)^T ----------------
// 128x128 tile, BK=32, 4 waves (2x2), 4x4 frags of 16x16x32 per wave.
__global__ __launch_bounds__(256) void gemm_bf16(const __hip_bfloat16* __restrict__ A,
                                                 const __hip_bfloat16* __restrict__ BT,
                                                 float* __restrict__ C, int M, int N, int K) {
  __shared__ __align__(16) __hip_bfloat16 lA[128 * 32];
  __shared__ __align__(16) __hip_bfloat16 lB[128 * 32];
  const int tid = threadIdx.x;
  const int lane = tid & 63;
  const int w = tid >> 6;
  const int wr = w >> 1, wc = w & 1;
  const int row0 = blockIdx.y * 128;
  const int col0 = blockIdx.x * 128;
  f32x4 acc[4][4];
#pragma unroll
  for (int m = 0; m < 4; ++m)
#pragma unroll
    for (int n = 0; n < 4; ++n) acc[m][n] = {0.f, 0.f, 0.f, 0.f};
  const int fr = lane & 15;
  const int ko = (lane >> 4) * 8;
  for (int kt = 0; kt < K; kt += 32) {
#pragma unroll
    for (int i = 0; i < 2; ++i) {
      int elem = (w * 2 + i) * 512 + lane * 8;   // linear elem this lane stages
      int rr = elem >> 5, cc = elem & 31;
      const __hip_bfloat16* srcA = A + (size_t)(row0 + rr) * K + kt + cc;
      __builtin_amdgcn_global_load_lds(AS1(srcA), AS3(&lA[(w * 2 + i) * 512]), 16, 0, 0);
      const __hip_bfloat16* srcB = BT + (size_t)(col0 + rr) * K + kt + cc;
      __builtin_amdgcn_global_load_lds(AS1(srcB), AS3(&lB[(w * 2 + i) * 512]), 16, 0, 0);
    }
    __syncthreads();
    bf16x8 af[4], bfr[4];
#pragma unroll
    for (int m = 0; m < 4; ++m)
      af[m] = *reinterpret_cast<const bf16x8*>(&lA[(wr * 64 + m * 16 + fr) * 32 + ko]);
#pragma unroll
    for (int n = 0; n < 4; ++n)
      bfr[n] = *reinterpret_cast<const bf16x8*>(&lB[(wc * 64 + n * 16 + fr) * 32 + ko]);
#pragma unroll
    for (int m = 0; m < 4; ++m)
#pragma unroll
      for (int n = 0; n < 4; ++n)
        acc[m][n] = __builtin_amdgcn_mfma_f32_16x16x32_bf16(af[m], bfr[n], acc[m][n], 0, 0, 0);
    __syncthreads();
  }
  const int rq = (lane >> 4) * 4;
#pragma unroll
  for (int m = 0; m < 4; ++m)
#pragma unroll
    for (int n = 0; n < 4; ++n)
#pragma unroll
      for (int r = 0; r < 4; ++r)
        C[(size_t)(row0 + wr * 64 + m * 16 + rq + r) * N + (col0 + wc * 64 + n * 16 + fr)] =
            acc[m][n][r];
}

// ---------------- small GEMM for Wb (16 cols) and Wa (8 cols), f32 ----------------
__global__ void small_gemm_ba(const float* __restrict__ x, const float* __restrict__ Wb,
                              const float* __restrict__ Wa, float* __restrict__ xb,
                              float* __restrict__ xa) {
  int row = blockIdx.x;
  int col = blockIdx.y;   // 0..23
  int lane = threadIdx.x; // 0..63
  float acc = 0.f;
  if (col < 16) {
    for (int k = lane; k < HID; k += 64) acc += x[(size_t)row * HID + k] * Wb[(size_t)k * 16 + col];
  } else {
    int c = col - 16;
    for (int k = lane; k < HID; k += 64) acc += x[(size_t)row * HID + k] * Wa[(size_t)k * 8 + c];
  }
#pragma unroll
  for (int off = 32; off; off >>= 1) acc += __shfl_down(acc, off);
  if (lane == 0) {
    if (col < 16) xb[(size_t)row * 16 + col] = acc;
    else          xa[(size_t)row * 8 + (col - 16)] = acc;
  }
}

__device__ __forceinline__ float silu_f(float y) { return y / (1.f + __expf(-y)); }

// ---------------- conv + silu + l2norm for q; writes q_s[bh][t][d] ----------------
__global__ __launch_bounds__(128) void conv_q_kernel(const float* __restrict__ qlin,
                                                     const float* __restrict__ wq,
                                                     float* __restrict__ q_s) {
  int bt = blockIdx.x;  // b*512 + t
  int h  = blockIdx.y;  // 0..7
  int d  = threadIdx.x; // 0..127
  int b = bt >> 9, t = bt & 511;
  int c = h * 128 + d;
  float y = 0.f;
#pragma unroll
  for (int tau = 0; tau < 4; ++tau) {
    int tt = t - 3 + tau;
    float xv = (tt >= 0) ? qlin[(size_t)(b * 512 + tt) * 1024 + c] : 0.f;
    y += xv * wq[c * 4 + tau];
  }
  y = silu_f(y);
  __shared__ float red[2];
  float ss = y * y;
#pragma unroll
  for (int off = 32; off; off >>= 1) ss += __shfl_down(ss, off);
  if ((d & 63) == 0) red[d >> 6] = ss;
  __syncthreads();
  float nrm = sqrtf(red[0] + red[1]);
  float scale = (1.f / fmaxf(nrm, 1e-12f)) * 0.08838834764831845f;  // 1/sqrt(128)
  int bh = b * 8 + h;
  q_s[((size_t)bh * 512 + t) * 128 + d] = y * scale;
}

// ---------------- conv + silu + l2norm for k; writes k_s[bh][j][t][d] ----------------
__global__ __launch_bounds__(128) void conv_k_kernel(const float* __restrict__ klin,
                                                     const float* __restrict__ wk,
                                                     float* __restrict__ k_s) {
  int bt = blockIdx.x;
  int jh = blockIdx.y;  // j*8 + h
  int d  = threadIdx.x;
  int b = bt >> 9, t = bt & 511;
  int j = jh >> 3, h = jh & 7;
  int c = j * 1024 + h * 128 + d;
  float y = 0.f;
#pragma unroll
  for (int tau = 0; tau < 4; ++tau) {
    int tt = t - 3 + tau;
    float xv = (tt >= 0) ? klin[(size_t)(b * 512 + tt) * 2048 + c] : 0.f;
    y += xv * wk[c * 4 + tau];
  }
  y = silu_f(y);
  __shared__ float red[2];
  float ss = y * y;
#pragma unroll
  for (int off = 32; off; off >>= 1) ss += __shfl_down(ss, off);
  if ((d & 63) == 0) red[d >> 6] = ss;
  __syncthreads();
  float nrm = sqrtf(red[0] + red[1]);
  float scale = 1.f / fmaxf(nrm, 1e-12f);
  int bh = b * 8 + h;
  k_s[(((size_t)bh * 2 + j) * 512 + t) * 128 + d] = y * scale;
}

// ---------------- conv + silu for v; writes v_s[bh][j][t][d] ----------------
__global__ __launch_bounds__(128) void conv_v_kernel(const float* __restrict__ vlin,
                                                     const float* __restrict__ wv,
                                                     float* __restrict__ v_s) {
  int bt = blockIdx.x;
  int jh = blockIdx.y;
  int d  = threadIdx.x;
  int b = bt >> 9, t = bt & 511;
  int j = jh >> 3, h = jh & 7;
  int c = j * 1024 + h * 128 + d;
  float y = 0.f;
#pragma unroll
  for (int tau = 0; tau < 4; ++tau) {
    int tt = t - 3 + tau;
    float xv = (tt >= 0) ? vlin[(size_t)(b * 512 + tt) * 2048 + c] : 0.f;
    y += xv * wv[c * 4 + tau];
  }
  int bh = b * 8 + h;
  v_s[(((size_t)bh * 2 + j) * 512 + t) * 128 + d] = silu_f(y);
}

// ---------------- beta / exp(g) ----------------
__global__ void bg_kernel(const float* __restrict__ xb, const float* __restrict__ xa,
                          const float* __restrict__ A_log, const float* __restrict__ dt_bias,
                          float* __restrict__ beta_s, float* __restrict__ ge_s) {
  int bt = blockIdx.x;   // b*512 + t
  int i = threadIdx.x;   // 0..31, active 0..23
  int b = bt >> 9, t = bt & 511;
  if (i < 16) {
    int j = i >> 3, h = i & 7;
    float v = xb[(size_t)bt * 16 + i];
    float bv = 2.f / (1.f + __expf(-v));
    beta_s[(((size_t)(b * 8 + h)) * 2 + j) * 512 + t] = bv;
  } else if (i < 24) {
    int h = i - 16;
    float v = xa[(size_t)bt * 8 + h] + dt_bias[h];
    float sp = (v > 20.f) ? v : log1pf(__expf(v));
    float g = -__expf(A_log[h]) * sp;
    ge_s[((size_t)(b * 8 + h)) * 512 + t] = __expf(g);
  }
}

// ---------------- sequential gated delta-product scan ----------------
// 16 blocks (b,h), 128 threads (v). Thread v owns state column S[:,v] held in
// 32 NAMED f32x4 SSA values (guaranteed VGPR residency — the array form spilled
// to scratch: VGPR_Count=84, 13x slowdown). No cross-lane traffic needed:
// corr/u/o are all local to the v-column.
#define R32(X) X(0) X(1) X(2) X(3) X(4) X(5) X(6) X(7) X(8) X(9) X(10) X(11) \
  X(12) X(13) X(14) X(15) X(16) X(17) X(18) X(19) X(20) X(21) X(22) X(23) \
  X(24) X(25) X(26) X(27) X(28) X(29) X(30) X(31)

__global__ __launch_bounds__(128, 1) void scan_kernel(const float* __restrict__ q_s,
                                                      const float* __restrict__ k_s,
                                                      const float* __restrict__ v_s,
                                                      const float* __restrict__ beta_s,
                                                      const float* __restrict__ ge_s,
                                                      float* __restrict__ o_s,
                                                      float* __restrict__ state_out) {
  const int bh = blockIdx.x;
  const int v = threadIdx.x;
#define DECL(n) f32x4 s##n = {0.f, 0.f, 0.f, 0.f};
  R32(DECL)
#undef DECL
  const float* qp0  = q_s + (size_t)bh * 512 * 128;
  const float* k0p0 = k_s + ((size_t)bh * 2 + 0) * 512 * 128;
  const float* k1p0 = k_s + ((size_t)bh * 2 + 1) * 512 * 128;
  const float* v0p0 = v_s + ((size_t)bh * 2 + 0) * 512 * 128;
  const float* v1p0 = v_s + ((size_t)bh * 2 + 1) * 512 * 128;
  const float* b0p = beta_s + ((size_t)bh * 2 + 0) * 512;
  const float* b1p = beta_s + ((size_t)bh * 2 + 1) * 512;
  const float* gp  = ge_s + (size_t)bh * 512;
  for (int t = 0; t < 512; ++t) {
    const float eg = gp[t];
    const float bb0 = b0p[t], bb1 = b1p[t];
    const float mv0 = v0p0[(size_t)t * 128 + v];
    const float mv1 = v1p0[(size_t)t * 128 + v];
    const f32x4* __restrict__ k0 = (const f32x4*)(k0p0 + (size_t)t * 128);
    const f32x4* __restrict__ k1 = (const f32x4*)(k1p0 + (size_t)t * 128);
    const f32x4* __restrict__ qv = (const f32x4*)(qp0 + (size_t)t * 128);
    // pass 1: decay + corr0
    f32x4 acc = {0.f, 0.f, 0.f, 0.f};
#define PASS1(n) { f32x4 kv = k0[n]; s##n *= eg; acc += kv * s##n; }
    R32(PASS1)
#undef PASS1
    const float u0 = (mv0 - ((acc[0] + acc[1]) + (acc[2] + acc[3]))) * bb0;
    // pass 2: update j0 + corr1
    acc = (f32x4){0.f, 0.f, 0.f, 0.f};
#define PASS2(n) { f32x4 kv = k0[n]; f32x4 kw = k1[n]; s##n += kv * u0; acc += kw * s##n; }
    R32(PASS2)
#undef PASS2
    const float u1 = (mv1 - ((acc[0] + acc[1]) + (acc[2] + acc[3]))) * bb1;
    // pass 3: update j1 + output
    acc = (f32x4){0.f, 0.f, 0.f, 0.f};
#define PASS3(n) { f32x4 kw = k1[n]; f32x4 qz = qv[n]; s##n += kw * u1; acc += qz * s##n; }
    R32(PASS3)
#undef PASS3
    o_s[((size_t)bh * 512 + t) * 128 + v] = (acc[0] + acc[1]) + (acc[2] + acc[3]);
  }
  float* base = state_out + (size_t)bh * 128 * 128 + v;
#define WOUT(n) { base[(n * 4 + 0) * 128] = s##n[0]; base[(n * 4 + 1) * 128] = s##n[1]; \
                  base[(n * 4 + 2) * 128] = s##n[2]; base[(n * 4 + 3) * 128] = s##n[3]; }
  R32(WOUT)
#undef WOUT
}

// ---------------- rmsnorm + gate silu -> bf16 A for final GEMM ----------------
__global__ __launch_bounds__(128) void post_kernel(const float* __restrict__ o_s,
                                                   const float* __restrict__ g_lin,
                                                   const float* __restrict__ norm_w,
                                                   __hip_bfloat16* __restrict__ Afin) {
  int bt = blockIdx.x;  // b*512 + t
  int h = blockIdx.y;
  int d = threadIdx.x;
  int b = bt >> 9, t = bt & 511;
  int bh = b * 8 + h;
  float o = o_s[((size_t)bh * 512 + t) * 128 + d];
  __shared__ float red[2];
  float ss = o * o;
#pragma unroll
  for (int off = 32; off; off >>= 1) ss += __shfl_down(ss, off);
  if ((d & 63) == 0) red[d >> 6] = ss;
  __syncthreads();
  float mean = (red[0] + red[1]) * (1.f / 128.f);
  float r = rsqrtf(mean + 1e-5f);
  float gate = g_lin[(size_t)bt * 1024 + h * 128 + d];
  float val = o * r * norm_w[d] * silu_f(gate);
  Afin[(size_t)bt * 1024 + h * 128 + d] = __float2bfloat16(val);
}

extern "C" void kernel_launch(void* const* d_in, const int* in_sizes, int n_in,
                              void* d_out, int out_size, void* d_ws, size_t ws_size,
                              hipStream_t stream) {
  const float* x       = (const float*)d_in[0];
  const float* Wq      = (const float*)d_in[1];
  const float* Wk      = (const float*)d_in[2];
  const float* Wv      = (const float*)d_in[3];
  const float* Wb      = (const float*)d_in[4];
  const float* Wa      = (const float*)d_in[5];
  const float* A_log   = (const float*)d_in[6];
  const float* dt_bias = (const float*)d_in[7];
  const float* cqw     = (const float*)d_in[8];
  const float* ckw     = (const float*)d_in[9];
  const float* cvw     = (const float*)d_in[10];
  const float* Wg      = (const float*)d_in[11];
  const float* norm_w  = (const float*)d_in[12];
  const float* Wo      = (const float*)d_in[13];

  char* ws = (char*)d_ws;
  size_t off = 0;
  auto alloc = [&](size_t bytes) {
    void* p = ws + off;
    off += (bytes + 255) & ~(size_t)255;
    return p;
  };
  __hip_bfloat16* xbf  = (__hip_bfloat16*)alloc((size_t)2097152 * 2);
  __hip_bfloat16* WqT  = (__hip_bfloat16*)alloc((size_t)2097152 * 2);
  __hip_bfloat16* WkT  = (__hip_bfloat16*)alloc((size_t)4194304 * 2);
  __hip_bfloat16* WvT  = (__hip_bfloat16*)alloc((size_t)4194304 * 2);
  __hip_bfloat16* WgT  = (__hip_bfloat16*)alloc((size_t)2097152 * 2);
  __hip_bfloat16* WoT  = (__hip_bfloat16*)alloc((size_t)2097152 * 2);
  float* q_lin  = (float*)alloc((size_t)1048576 * 4);
  float* k_lin  = (float*)alloc((size_t)2097152 * 4);
  float* v_lin  = (float*)alloc((size_t)2097152 * 4);
  float* g_lin  = (float*)alloc((size_t)1048576 * 4);
  float* xb     = (float*)alloc((size_t)16384 * 4);
  float* xa     = (float*)alloc((size_t)8192 * 4);
  float* q_s    = (float*)alloc((size_t)1048576 * 4);
  float* k_s    = (float*)alloc((size_t)2097152 * 4);
  float* v_s    = (float*)alloc((size_t)2097152 * 4);
  float* beta_s = (float*)alloc((size_t)16384 * 4);
  float* ge_s   = (float*)alloc((size_t)8192 * 4);
  float* o_s    = (float*)alloc((size_t)1048576 * 4);
  __hip_bfloat16* Afin = (__hip_bfloat16*)alloc((size_t)1048576 * 2);

  float* out_main  = (float*)d_out;
  float* out_state = out_main + 2097152;

  dim3 tb(32, 8);
  f2bf_kernel<<<8192, 256, 0, stream>>>(x, xbf, 2097152);
  transpose_f2bf<<<dim3(32, 64), tb, 0, stream>>>(Wq, WqT, 2048, 1024);
  transpose_f2bf<<<dim3(64, 64), tb, 0, stream>>>(Wk, WkT, 2048, 2048);
  transpose_f2bf<<<dim3(64, 64), tb, 0, stream>>>(Wv, WvT, 2048, 2048);
  transpose_f2bf<<<dim3(32, 64), tb, 0, stream>>>(Wg, WgT, 2048, 1024);
  transpose_f2bf<<<dim3(64, 32), tb, 0, stream>>>(Wo, WoT, 1024, 2048);

  gemm_bf16<<<dim3(8, 8),  256, 0, stream>>>(xbf, WqT, q_lin, 1024, 1024, 2048);
  gemm_bf16<<<dim3(16, 8), 256, 0, stream>>>(xbf, WkT, k_lin, 1024, 2048, 2048);
  gemm_bf16<<<dim3(16, 8), 256, 0, stream>>>(xbf, WvT, v_lin, 1024, 2048, 2048);
  gemm_bf16<<<dim3(8, 8),  256, 0, stream>>>(xbf, WgT, g_lin, 1024, 1024, 2048);
  small_gemm_ba<<<dim3(1024, 24), 64, 0, stream>>>(x, Wb, Wa, xb, xa);

  conv_q_kernel<<<dim3(1024, 8),  128, 0, stream>>>(q_lin, cqw, q_s);
  conv_k_kernel<<<dim3(1024, 16), 128, 0, stream>>>(k_lin, ckw, k_s);
  conv_v_kernel<<<dim3(1024, 16), 128, 0, stream>>>(v_lin, cvw, v_s);
  bg_kernel<<<1024, 32, 0, stream>>>(xb, xa, A_log, dt_bias, beta_s, ge_s);

  scan_kernel<<<16, 128, 0, stream>>>(q_s, k_s, v_s, beta_s, ge_s, o_s, out_state);

  post_kernel<<<dim3(1024, 8), 128, 0, stream>>>(o_s, g_lin, norm_w, Afin);
  gemm_bf16<<<dim3(16, 8), 256, 0, stream>>>(Afin, WoT, out_main, 1024, 2048, 1024);
}

// Round 3
// 977.752 us; speedup vs baseline: 4.8711x; 2.2317x over previous
//
#include <hip/hip_runtime.h>
#include <hip/hip_bf16.h>
#include <cmath>

#define B_   2
#define L_   512
#define HID  2048
#define DH   128
#define NH   8
#define NHH  2
#define ROWS 1024  // B_*L_

typedef float  f32x4  __attribute__((ext_vector_type(4)));
typedef __bf16 bf16x8 __attribute__((ext_vector_type(8)));

#define AS1(p) ((const __attribute__((address_space(1))) unsigned int*)(p))
#define AS3(p) ((__attribute__((address_space(3))) unsigned int*)(p))

// ---------------- f32 -> bf16 elementwise ----------------
__global__ void f2bf_kernel(const float* __restrict__ in, __hip_bfloat16* __restrict__ out, int n) {
  int i = blockIdx.x * 256 + threadIdx.x;
  if (i < n) out[i] = __float2bfloat16(in[i]);
}

// ---------------- f32 (K x N) -> bf16 transposed (N x K) ----------------
__global__ __launch_bounds__(256) void transpose_f2bf(const float* __restrict__ in,
                                                      __hip_bfloat16* __restrict__ out,
                                                      int K, int N) {
  __shared__ float tile[32][33];
  int n0 = blockIdx.x * 32, k0 = blockIdx.y * 32;
  int tx = threadIdx.x, ty = threadIdx.y;  // 32 x 8
#pragma unroll
  for (int i = 0; i < 32; i += 8)
    tile[ty + i][tx] = in[(size_t)(k0 + ty + i) * N + n0 + tx];
  __syncthreads();
#pragma unroll
  for (int i = 0; i < 32; i += 8)
    out[(size_t)(n0 + ty + i) * K + k0 + tx] = __float2bfloat16(tile[tx][ty + i]);
}

// ---------------- bf16 MFMA GEMM: C(MxN) = A(MxK) * BT(NxK)^T ----------------
__global__ __launch_bounds__(256) void gemm_bf16(const __hip_bfloat16* __restrict__ A,
                                                 const __hip_bfloat16* __restrict__ BT,
                                                 float* __restrict__ C, int M, int N, int K) {
  __shared__ __align__(16) __hip_bfloat16 lA[128 * 32];
  __shared__ __align__(16) __hip_bfloat16 lB[128 * 32];
  const int tid = threadIdx.x;
  const int lane = tid & 63;
  const int w = tid >> 6;
  const int wr = w >> 1, wc = w & 1;
  const int row0 = blockIdx.y * 128;
  const int col0 = blockIdx.x * 128;
  f32x4 acc[4][4];
#pragma unroll
  for (int m = 0; m < 4; ++m)
#pragma unroll
    for (int n = 0; n < 4; ++n) acc[m][n] = {0.f, 0.f, 0.f, 0.f};
  const int fr = lane & 15;
  const int ko = (lane >> 4) * 8;
  for (int kt = 0; kt < K; kt += 32) {
#pragma unroll
    for (int i = 0; i < 2; ++i) {
      int elem = (w * 2 + i) * 512 + lane * 8;
      int rr = elem >> 5, cc = elem & 31;
      const __hip_bfloat16* srcA = A + (size_t)(row0 + rr) * K + kt + cc;
      __builtin_amdgcn_global_load_lds(AS1(srcA), AS3(&lA[(w * 2 + i) * 512]), 16, 0, 0);
      const __hip_bfloat16* srcB = BT + (size_t)(col0 + rr) * K + kt + cc;
      __builtin_amdgcn_global_load_lds(AS1(srcB), AS3(&lB[(w * 2 + i) * 512]), 16, 0, 0);
    }
    __syncthreads();
    bf16x8 af[4], bfr[4];
#pragma unroll
    for (int m = 0; m < 4; ++m)
      af[m] = *reinterpret_cast<const bf16x8*>(&lA[(wr * 64 + m * 16 + fr) * 32 + ko]);
#pragma unroll
    for (int n = 0; n < 4; ++n)
      bfr[n] = *reinterpret_cast<const bf16x8*>(&lB[(wc * 64 + n * 16 + fr) * 32 + ko]);
#pragma unroll
    for (int m = 0; m < 4; ++m)
#pragma unroll
      for (int n = 0; n < 4; ++n)
        acc[m][n] = __builtin_amdgcn_mfma_f32_16x16x32_bf16(af[m], bfr[n], acc[m][n], 0, 0, 0);
    __syncthreads();
  }
  const int rq = (lane >> 4) * 4;
#pragma unroll
  for (int m = 0; m < 4; ++m)
#pragma unroll
    for (int n = 0; n < 4; ++n)
#pragma unroll
      for (int r = 0; r < 4; ++r)
        C[(size_t)(row0 + wr * 64 + m * 16 + rq + r) * N + (col0 + wc * 64 + n * 16 + fr)] =
            acc[m][n][r];
}

// ---------------- small GEMM for Wb (16 cols) and Wa (8 cols), f32 ----------------
__global__ void small_gemm_ba(const float* __restrict__ x, const float* __restrict__ Wb,
                              const float* __restrict__ Wa, float* __restrict__ xb,
                              float* __restrict__ xa) {
  int row = blockIdx.x;
  int col = blockIdx.y;
  int lane = threadIdx.x;
  float acc = 0.f;
  if (col < 16) {
    for (int k = lane; k < HID; k += 64) acc += x[(size_t)row * HID + k] * Wb[(size_t)k * 16 + col];
  } else {
    int c = col - 16;
    for (int k = lane; k < HID; k += 64) acc += x[(size_t)row * HID + k] * Wa[(size_t)k * 8 + c];
  }
#pragma unroll
  for (int off = 32; off; off >>= 1) acc += __shfl_down(acc, off);
  if (lane == 0) {
    if (col < 16) xb[(size_t)row * 16 + col] = acc;
    else          xa[(size_t)row * 8 + (col - 16)] = acc;
  }
}

__device__ __forceinline__ float silu_f(float y) { return y / (1.f + __expf(-y)); }

// ---------------- conv + silu + l2norm for q ----------------
__global__ __launch_bounds__(128) void conv_q_kernel(const float* __restrict__ qlin,
                                                     const float* __restrict__ wq,
                                                     float* __restrict__ q_s) {
  int bt = blockIdx.x;
  int h  = blockIdx.y;
  int d  = threadIdx.x;
  int b = bt >> 9, t = bt & 511;
  int c = h * 128 + d;
  float y = 0.f;
#pragma unroll
  for (int tau = 0; tau < 4; ++tau) {
    int tt = t - 3 + tau;
    float xv = (tt >= 0) ? qlin[(size_t)(b * 512 + tt) * 1024 + c] : 0.f;
    y += xv * wq[c * 4 + tau];
  }
  y = silu_f(y);
  __shared__ float red[2];
  float ss = y * y;
#pragma unroll
  for (int off = 32; off; off >>= 1) ss += __shfl_down(ss, off);
  if ((d & 63) == 0) red[d >> 6] = ss;
  __syncthreads();
  float nrm = sqrtf(red[0] + red[1]);
  float scale = (1.f / fmaxf(nrm, 1e-12f)) * 0.08838834764831845f;
  int bh = b * 8 + h;
  q_s[((size_t)bh * 512 + t) * 128 + d] = y * scale;
}

// ---------------- conv + silu + l2norm for k ----------------
__global__ __launch_bounds__(128) void conv_k_kernel(const float* __restrict__ klin,
                                                     const float* __restrict__ wk,
                                                     float* __restrict__ k_s) {
  int bt = blockIdx.x;
  int jh = blockIdx.y;
  int d  = threadIdx.x;
  int b = bt >> 9, t = bt & 511;
  int j = jh >> 3, h = jh & 7;
  int c = j * 1024 + h * 128 + d;
  float y = 0.f;
#pragma unroll
  for (int tau = 0; tau < 4; ++tau) {
    int tt = t - 3 + tau;
    float xv = (tt >= 0) ? klin[(size_t)(b * 512 + tt) * 2048 + c] : 0.f;
    y += xv * wk[c * 4 + tau];
  }
  y = silu_f(y);
  __shared__ float red[2];
  float ss = y * y;
#pragma unroll
  for (int off = 32; off; off >>= 1) ss += __shfl_down(ss, off);
  if ((d & 63) == 0) red[d >> 6] = ss;
  __syncthreads();
  float nrm = sqrtf(red[0] + red[1]);
  float scale = 1.f / fmaxf(nrm, 1e-12f);
  int bh = b * 8 + h;
  k_s[(((size_t)bh * 2 + j) * 512 + t) * 128 + d] = y * scale;
}

// ---------------- conv + silu for v ----------------
__global__ __launch_bounds__(128) void conv_v_kernel(const float* __restrict__ vlin,
                                                     const float* __restrict__ wv,
                                                     float* __restrict__ v_s) {
  int bt = blockIdx.x;
  int jh = blockIdx.y;
  int d  = threadIdx.x;
  int b = bt >> 9, t = bt & 511;
  int j = jh >> 3, h = jh & 7;
  int c = j * 1024 + h * 128 + d;
  float y = 0.f;
#pragma unroll
  for (int tau = 0; tau < 4; ++tau) {
    int tt = t - 3 + tau;
    float xv = (tt >= 0) ? vlin[(size_t)(b * 512 + tt) * 2048 + c] : 0.f;
    y += xv * wv[c * 4 + tau];
  }
  int bh = b * 8 + h;
  v_s[(((size_t)bh * 2 + j) * 512 + t) * 128 + d] = silu_f(y);
}

// ---------------- beta / exp(g) ----------------
__global__ void bg_kernel(const float* __restrict__ xb, const float* __restrict__ xa,
                          const float* __restrict__ A_log, const float* __restrict__ dt_bias,
                          float* __restrict__ beta_s, float* __restrict__ ge_s) {
  int bt = blockIdx.x;
  int i = threadIdx.x;
  int b = bt >> 9, t = bt & 511;
  if (i < 16) {
    int j = i >> 3, h = i & 7;
    float v = xb[(size_t)bt * 16 + i];
    float bv = 2.f / (1.f + __expf(-v));
    beta_s[(((size_t)(b * 8 + h)) * 2 + j) * 512 + t] = bv;
  } else if (i < 24) {
    int h = i - 16;
    float v = xa[(size_t)bt * 8 + h] + dt_bias[h];
    float sp = (v > 20.f) ? v : log1pf(__expf(v));
    float g = -__expf(A_log[h]) * sp;
    ge_s[((size_t)(b * 8 + h)) * 512 + t] = __expf(g);
  }
}

// ---------------- sequential gated delta-product scan, k-split x v-split ----------------
// Grid: 32 blocks = 16 chains x 2 v-groups. Block: 256 thr = 4 waves.
// Thread (kq, vl): owns state rows [kq*32, kq*32+32) of column v = vg*64+vl —
// 32 floats = 8 named f32x4 (prev: 128 floats/thread spilled @ VGPR=108).
// Per-pass k-reduction: LDS 4-way partial sum, parity-double-buffered slots,
// 3 barriers/step.
#define R8(X) X(0) X(1) X(2) X(3) X(4) X(5) X(6) X(7)

__global__ __launch_bounds__(256, 1) void scan_kernel(const float* __restrict__ q_s,
                                                      const float* __restrict__ k_s,
                                                      const float* __restrict__ v_s,
                                                      const float* __restrict__ beta_s,
                                                      const float* __restrict__ ge_s,
                                                      float* __restrict__ o_s,
                                                      float* __restrict__ state_out) {
  const int bh = blockIdx.x >> 1;
  const int vg = blockIdx.x & 1;
  const int tid = threadIdx.x;
  const int kq = tid >> 6;         // k-quarter 0..3
  const int vl = tid & 63;
  const int v  = vg * 64 + vl;     // global v column

  __shared__ float red[2][3][4][64];

#define DECL(n) f32x4 s##n = {0.f, 0.f, 0.f, 0.f};
  R8(DECL)
#undef DECL

  const float* qp0  = q_s + (size_t)bh * 512 * 128 + kq * 32;
  const float* k0p0 = k_s + ((size_t)bh * 2 + 0) * 512 * 128 + kq * 32;
  const float* k1p0 = k_s + ((size_t)bh * 2 + 1) * 512 * 128 + kq * 32;
  const float* v0p0 = v_s + ((size_t)bh * 2 + 0) * 512 * 128 + v;
  const float* v1p0 = v_s + ((size_t)bh * 2 + 1) * 512 * 128 + v;
  const float* b0p = beta_s + ((size_t)bh * 2 + 0) * 512;
  const float* b1p = beta_s + ((size_t)bh * 2 + 1) * 512;
  const float* gp  = ge_s + (size_t)bh * 512;

  for (int t = 0; t < 512; ++t) {
    const int par = t & 1;
    const float eg  = gp[t];
    const float bb0 = b0p[t], bb1 = b1p[t];
    const float mv0 = v0p0[(size_t)t * 128];
    const float mv1 = v1p0[(size_t)t * 128];
    const f32x4* __restrict__ k0p = (const f32x4*)(k0p0 + (size_t)t * 128);
    const f32x4* __restrict__ k1p = (const f32x4*)(k1p0 + (size_t)t * 128);
    const f32x4* __restrict__ qp  = (const f32x4*)(qp0  + (size_t)t * 128);
    // hoist all loads for this step (24 f32x4; wave-uniform addresses)
#define LD(n) f32x4 a##n = k0p[n]; f32x4 b##n = k1p[n]; f32x4 c##n = qp[n];
    R8(LD)
#undef LD
    // pass 1: decay + corr0 partial
    f32x4 acc = {0.f, 0.f, 0.f, 0.f};
#define P1(n) { s##n *= eg; acc += a##n * s##n; }
    R8(P1)
#undef P1
    red[par][0][kq][vl] = (acc[0] + acc[1]) + (acc[2] + acc[3]);
    __syncthreads();
    const float corr0 = (red[par][0][0][vl] + red[par][0][1][vl]) +
                        (red[par][0][2][vl] + red[par][0][3][vl]);
    const float u0 = (mv0 - corr0) * bb0;
    // pass 2: update j0 + corr1 partial
    acc = (f32x4){0.f, 0.f, 0.f, 0.f};
#define P2(n) { s##n += a##n * u0; acc += b##n * s##n; }
    R8(P2)
#undef P2
    red[par][1][kq][vl] = (acc[0] + acc[1]) + (acc[2] + acc[3]);
    __syncthreads();
    const float corr1 = (red[par][1][0][vl] + red[par][1][1][vl]) +
                        (red[par][1][2][vl] + red[par][1][3][vl]);
    const float u1 = (mv1 - corr1) * bb1;
    // pass 3: update j1 + output partial
    acc = (f32x4){0.f, 0.f, 0.f, 0.f};
#define P3(n) { s##n += b##n * u1; acc += c##n * s##n; }
    R8(P3)
#undef P3
    red[par][2][kq][vl] = (acc[0] + acc[1]) + (acc[2] + acc[3]);
    __syncthreads();
    if (kq == 0) {
      const float o = (red[par][2][0][vl] + red[par][2][1][vl]) +
                      (red[par][2][2][vl] + red[par][2][3][vl]);
      o_s[((size_t)bh * 512 + t) * 128 + v] = o;
    }
  }
  float* base = state_out + (size_t)bh * 128 * 128 + v;
#define WOUT(n) { base[(kq * 32 + n * 4 + 0) * 128] = s##n[0]; \
                  base[(kq * 32 + n * 4 + 1) * 128] = s##n[1]; \
                  base[(kq * 32 + n * 4 + 2) * 128] = s##n[2]; \
                  base[(kq * 32 + n * 4 + 3) * 128] = s##n[3]; }
  R8(WOUT)
#undef WOUT
}

// ---------------- rmsnorm + gate silu -> bf16 A for final GEMM ----------------
__global__ __launch_bounds__(128) void post_kernel(const float* __restrict__ o_s,
                                                   const float* __restrict__ g_lin,
                                                   const float* __restrict__ norm_w,
                                                   __hip_bfloat16* __restrict__ Afin) {
  int bt = blockIdx.x;
  int h = blockIdx.y;
  int d = threadIdx.x;
  int b = bt >> 9, t = bt & 511;
  int bh = b * 8 + h;
  float o = o_s[((size_t)bh * 512 + t) * 128 + d];
  __shared__ float red[2];
  float ss = o * o;
#pragma unroll
  for (int off = 32; off; off >>= 1) ss += __shfl_down(ss, off);
  if ((d & 63) == 0) red[d >> 6] = ss;
  __syncthreads();
  float mean = (red[0] + red[1]) * (1.f / 128.f);
  float r = rsqrtf(mean + 1e-5f);
  float gate = g_lin[(size_t)bt * 1024 + h * 128 + d];
  float val = o * r * norm_w[d] * silu_f(gate);
  Afin[(size_t)bt * 1024 + h * 128 + d] = __float2bfloat16(val);
}

extern "C" void kernel_launch(void* const* d_in, const int* in_sizes, int n_in,
                              void* d_out, int out_size, void* d_ws, size_t ws_size,
                              hipStream_t stream) {
  const float* x       = (const float*)d_in[0];
  const float* Wq      = (const float*)d_in[1];
  const float* Wk      = (const float*)d_in[2];
  const float* Wv      = (const float*)d_in[3];
  const float* Wb      = (const float*)d_in[4];
  const float* Wa      = (const float*)d_in[5];
  const float* A_log   = (const float*)d_in[6];
  const float* dt_bias = (const float*)d_in[7];
  const float* cqw     = (const float*)d_in[8];
  const float* ckw     = (const float*)d_in[9];
  const float* cvw     = (const float*)d_in[10];
  const float* Wg      = (const float*)d_in[11];
  const float* norm_w  = (const float*)d_in[12];
  const float* Wo      = (const float*)d_in[13];

  char* ws = (char*)d_ws;
  size_t off = 0;
  auto alloc = [&](size_t bytes) {
    void* p = ws + off;
    off += (bytes + 255) & ~(size_t)255;
    return p;
  };
  __hip_bfloat16* xbf  = (__hip_bfloat16*)alloc((size_t)2097152 * 2);
  __hip_bfloat16* WqT  = (__hip_bfloat16*)alloc((size_t)2097152 * 2);
  __hip_bfloat16* WkT  = (__hip_bfloat16*)alloc((size_t)4194304 * 2);
  __hip_bfloat16* WvT  = (__hip_bfloat16*)alloc((size_t)4194304 * 2);
  __hip_bfloat16* WgT  = (__hip_bfloat16*)alloc((size_t)2097152 * 2);
  __hip_bfloat16* WoT  = (__hip_bfloat16*)alloc((size_t)2097152 * 2);
  float* q_lin  = (float*)alloc((size_t)1048576 * 4);
  float* k_lin  = (float*)alloc((size_t)2097152 * 4);
  float* v_lin  = (float*)alloc((size_t)2097152 * 4);
  float* g_lin  = (float*)alloc((size_t)1048576 * 4);
  float* xb     = (float*)alloc((size_t)16384 * 4);
  float* xa     = (float*)alloc((size_t)8192 * 4);
  float* q_s    = (float*)alloc((size_t)1048576 * 4);
  float* k_s    = (float*)alloc((size_t)2097152 * 4);
  float* v_s    = (float*)alloc((size_t)2097152 * 4);
  float* beta_s = (float*)alloc((size_t)16384 * 4);
  float* ge_s   = (float*)alloc((size_t)8192 * 4);
  float* o_s    = (float*)alloc((size_t)1048576 * 4);
  __hip_bfloat16* Afin = (__hip_bfloat16*)alloc((size_t)1048576 * 2);

  float* out_main  = (float*)d_out;
  float* out_state = out_main + 2097152;

  dim3 tb(32, 8);
  f2bf_kernel<<<8192, 256, 0, stream>>>(x, xbf, 2097152);
  transpose_f2bf<<<dim3(32, 64), tb, 0, stream>>>(Wq, WqT, 2048, 1024);
  transpose_f2bf<<<dim3(64, 64), tb, 0, stream>>>(Wk, WkT, 2048, 2048);
  transpose_f2bf<<<dim3(64, 64), tb, 0, stream>>>(Wv, WvT, 2048, 2048);
  transpose_f2bf<<<dim3(32, 64), tb, 0, stream>>>(Wg, WgT, 2048, 1024);
  transpose_f2bf<<<dim3(64, 32), tb, 0, stream>>>(Wo, WoT, 1024, 2048);

  gemm_bf16<<<dim3(8, 8),  256, 0, stream>>>(xbf, WqT, q_lin, 1024, 1024, 2048);
  gemm_bf16<<<dim3(16, 8), 256, 0, stream>>>(xbf, WkT, k_lin, 1024, 2048, 2048);
  gemm_bf16<<<dim3(16, 8), 256, 0, stream>>>(xbf, WvT, v_lin, 1024, 2048, 2048);
  gemm_bf16<<<dim3(8, 8),  256, 0, stream>>>(xbf, WgT, g_lin, 1024, 1024, 2048);
  small_gemm_ba<<<dim3(1024, 24), 64, 0, stream>>>(x, Wb, Wa, xb, xa);

  conv_q_kernel<<<dim3(1024, 8),  128, 0, stream>>>(q_lin, cqw, q_s);
  conv_k_kernel<<<dim3(1024, 16), 128, 0, stream>>>(k_lin, ckw, k_s);
  conv_v_kernel<<<dim3(1024, 16), 128, 0, stream>>>(v_lin, cvw, v_s);
  bg_kernel<<<1024, 32, 0, stream>>>(xb, xa, A_log, dt_bias, beta_s, ge_s);

  scan_kernel<<<32, 256, 0, stream>>>(q_s, k_s, v_s, beta_s, ge_s, o_s, out_state);

  post_kernel<<<dim3(1024, 8), 128, 0, stream>>>(o_s, g_lin, norm_w, Afin);
  gemm_bf16<<<dim3(16, 8), 256, 0, stream>>>(Afin, WoT, out_main, 1024, 2048, 1024);
}

// Round 4
// 826.159 us; speedup vs baseline: 5.7649x; 1.1835x over previous
//
#include <hip/hip_runtime.h>
#include <hip/hip_bf16.h>
#include <cmath>

#define B_   2
#define L_   512
#define HID  2048
#define DH   128
#define NH   8
#define NHH  2
#define ROWS 1024  // B_*L_

typedef float  f32x4  __attribute__((ext_vector_type(4)));
typedef __bf16 bf16x8 __attribute__((ext_vector_type(8)));

#define AS1(p) ((const __attribute__((address_space(1))) unsigned int*)(p))
#define AS3(p) ((__attribute__((address_space(3))) unsigned int*)(p))

// ---------------- f32 -> bf16 elementwise ----------------
__global__ void f2bf_kernel(const float* __restrict__ in, __hip_bfloat16* __restrict__ out, int n) {
  int i = blockIdx.x * 256 + threadIdx.x;
  if (i < n) out[i] = __float2bfloat16(in[i]);
}

// ---------------- f32 (K x N) -> bf16 transposed (N x K) ----------------
__global__ __launch_bounds__(256) void transpose_f2bf(const float* __restrict__ in,
                                                      __hip_bfloat16* __restrict__ out,
                                                      int K, int N) {
  __shared__ float tile[32][33];
  int n0 = blockIdx.x * 32, k0 = blockIdx.y * 32;
  int tx = threadIdx.x, ty = threadIdx.y;  // 32 x 8
#pragma unroll
  for (int i = 0; i < 32; i += 8)
    tile[ty + i][tx] = in[(size_t)(k0 + ty + i) * N + n0 + tx];
  __syncthreads();
#pragma unroll
  for (int i = 0; i < 32; i += 8)
    out[(size_t)(n0 + ty + i) * K + k0 + tx] = __float2bfloat16(tile[tx][ty + i]);
}

// ---------------- bf16 MFMA GEMM: C(MxN) = A(MxK) * BT(NxK)^T ----------------
__global__ __launch_bounds__(256) void gemm_bf16(const __hip_bfloat16* __restrict__ A,
                                                 const __hip_bfloat16* __restrict__ BT,
                                                 float* __restrict__ C, int M, int N, int K) {
  __shared__ __align__(16) __hip_bfloat16 lA[128 * 32];
  __shared__ __align__(16) __hip_bfloat16 lB[128 * 32];
  const int tid = threadIdx.x;
  const int lane = tid & 63;
  const int w = tid >> 6;
  const int wr = w >> 1, wc = w & 1;
  const int row0 = blockIdx.y * 128;
  const int col0 = blockIdx.x * 128;
  f32x4 acc[4][4];
#pragma unroll
  for (int m = 0; m < 4; ++m)
#pragma unroll
    for (int n = 0; n < 4; ++n) acc[m][n] = {0.f, 0.f, 0.f, 0.f};
  const int fr = lane & 15;
  const int ko = (lane >> 4) * 8;
  for (int kt = 0; kt < K; kt += 32) {
#pragma unroll
    for (int i = 0; i < 2; ++i) {
      int elem = (w * 2 + i) * 512 + lane * 8;
      int rr = elem >> 5, cc = elem & 31;
      const __hip_bfloat16* srcA = A + (size_t)(row0 + rr) * K + kt + cc;
      __builtin_amdgcn_global_load_lds(AS1(srcA), AS3(&lA[(w * 2 + i) * 512]), 16, 0, 0);
      const __hip_bfloat16* srcB = BT + (size_t)(col0 + rr) * K + kt + cc;
      __builtin_amdgcn_global_load_lds(AS1(srcB), AS3(&lB[(w * 2 + i) * 512]), 16, 0, 0);
    }
    __syncthreads();
    bf16x8 af[4], bfr[4];
#pragma unroll
    for (int m = 0; m < 4; ++m)
      af[m] = *reinterpret_cast<const bf16x8*>(&lA[(wr * 64 + m * 16 + fr) * 32 + ko]);
#pragma unroll
    for (int n = 0; n < 4; ++n)
      bfr[n] = *reinterpret_cast<const bf16x8*>(&lB[(wc * 64 + n * 16 + fr) * 32 + ko]);
#pragma unroll
    for (int m = 0; m < 4; ++m)
#pragma unroll
      for (int n = 0; n < 4; ++n)
        acc[m][n] = __builtin_amdgcn_mfma_f32_16x16x32_bf16(af[m], bfr[n], acc[m][n], 0, 0, 0);
    __syncthreads();
  }
  const int rq = (lane >> 4) * 4;
#pragma unroll
  for (int m = 0; m < 4; ++m)
#pragma unroll
    for (int n = 0; n < 4; ++n)
#pragma unroll
      for (int r = 0; r < 4; ++r)
        C[(size_t)(row0 + wr * 64 + m * 16 + rq + r) * N + (col0 + wc * 64 + n * 16 + fr)] =
            acc[m][n][r];
}

// ---------------- small GEMM for Wb (16 cols) and Wa (8 cols), f32 ----------------
__global__ void small_gemm_ba(const float* __restrict__ x, const float* __restrict__ Wb,
                              const float* __restrict__ Wa, float* __restrict__ xb,
                              float* __restrict__ xa) {
  int row = blockIdx.x;
  int col = blockIdx.y;
  int lane = threadIdx.x;
  float acc = 0.f;
  if (col < 16) {
    for (int k = lane; k < HID; k += 64) acc += x[(size_t)row * HID + k] * Wb[(size_t)k * 16 + col];
  } else {
    int c = col - 16;
    for (int k = lane; k < HID; k += 64) acc += x[(size_t)row * HID + k] * Wa[(size_t)k * 8 + c];
  }
#pragma unroll
  for (int off = 32; off; off >>= 1) acc += __shfl_down(acc, off);
  if (lane == 0) {
    if (col < 16) xb[(size_t)row * 16 + col] = acc;
    else          xa[(size_t)row * 8 + (col - 16)] = acc;
  }
}

__device__ __forceinline__ float silu_f(float y) { return y / (1.f + __expf(-y)); }

// ---------------- conv + silu + l2norm for q ----------------
__global__ __launch_bounds__(128) void conv_q_kernel(const float* __restrict__ qlin,
                                                     const float* __restrict__ wq,
                                                     float* __restrict__ q_s) {
  int bt = blockIdx.x;
  int h  = blockIdx.y;
  int d  = threadIdx.x;
  int b = bt >> 9, t = bt & 511;
  int c = h * 128 + d;
  float y = 0.f;
#pragma unroll
  for (int tau = 0; tau < 4; ++tau) {
    int tt = t - 3 + tau;
    float xv = (tt >= 0) ? qlin[(size_t)(b * 512 + tt) * 1024 + c] : 0.f;
    y += xv * wq[c * 4 + tau];
  }
  y = silu_f(y);
  __shared__ float red[2];
  float ss = y * y;
#pragma unroll
  for (int off = 32; off; off >>= 1) ss += __shfl_down(ss, off);
  if ((d & 63) == 0) red[d >> 6] = ss;
  __syncthreads();
  float nrm = sqrtf(red[0] + red[1]);
  float scale = (1.f / fmaxf(nrm, 1e-12f)) * 0.08838834764831845f;
  int bh = b * 8 + h;
  q_s[((size_t)bh * 512 + t) * 128 + d] = y * scale;
}

// ---------------- conv + silu + l2norm for k ----------------
__global__ __launch_bounds__(128) void conv_k_kernel(const float* __restrict__ klin,
                                                     const float* __restrict__ wk,
                                                     float* __restrict__ k_s) {
  int bt = blockIdx.x;
  int jh = blockIdx.y;
  int d  = threadIdx.x;
  int b = bt >> 9, t = bt & 511;
  int j = jh >> 3, h = jh & 7;
  int c = j * 1024 + h * 128 + d;
  float y = 0.f;
#pragma unroll
  for (int tau = 0; tau < 4; ++tau) {
    int tt = t - 3 + tau;
    float xv = (tt >= 0) ? klin[(size_t)(b * 512 + tt) * 2048 + c] : 0.f;
    y += xv * wk[c * 4 + tau];
  }
  y = silu_f(y);
  __shared__ float red[2];
  float ss = y * y;
#pragma unroll
  for (int off = 32; off; off >>= 1) ss += __shfl_down(ss, off);
  if ((d & 63) == 0) red[d >> 6] = ss;
  __syncthreads();
  float nrm = sqrtf(red[0] + red[1]);
  float scale = 1.f / fmaxf(nrm, 1e-12f);
  int bh = b * 8 + h;
  k_s[(((size_t)bh * 2 + j) * 512 + t) * 128 + d] = y * scale;
}

// ---------------- conv + silu for v ----------------
__global__ __launch_bounds__(128) void conv_v_kernel(const float* __restrict__ vlin,
                                                     const float* __restrict__ wv,
                                                     float* __restrict__ v_s) {
  int bt = blockIdx.x;
  int jh = blockIdx.y;
  int d  = threadIdx.x;
  int b = bt >> 9, t = bt & 511;
  int j = jh >> 3, h = jh & 7;
  int c = j * 1024 + h * 128 + d;
  float y = 0.f;
#pragma unroll
  for (int tau = 0; tau < 4; ++tau) {
    int tt = t - 3 + tau;
    float xv = (tt >= 0) ? vlin[(size_t)(b * 512 + tt) * 2048 + c] : 0.f;
    y += xv * wv[c * 4 + tau];
  }
  int bh = b * 8 + h;
  v_s[(((size_t)bh * 2 + j) * 512 + t) * 128 + d] = silu_f(y);
}

// ---------------- beta / exp(g) ----------------
__global__ void bg_kernel(const float* __restrict__ xb, const float* __restrict__ xa,
                          const float* __restrict__ A_log, const float* __restrict__ dt_bias,
                          float* __restrict__ beta_s, float* __restrict__ ge_s) {
  int bt = blockIdx.x;
  int i = threadIdx.x;
  int b = bt >> 9, t = bt & 511;
  if (i < 16) {
    int j = i >> 3, h = i & 7;
    float v = xb[(size_t)bt * 16 + i];
    float bv = 2.f / (1.f + __expf(-v));
    beta_s[(((size_t)(b * 8 + h)) * 2 + j) * 512 + t] = bv;
  } else if (i < 24) {
    int h = i - 16;
    float v = xa[(size_t)bt * 8 + h] + dt_bias[h];
    float sp = (v > 20.f) ? v : log1pf(__expf(v));
    float g = -__expf(A_log[h]) * sp;
    ge_s[((size_t)(b * 8 + h)) * 512 + t] = __expf(g);
  }
}

// ---------------- sequential gated delta-product scan, barrier-free ----------------
// 128 blocks x 64 thr = 16 chains x 8 independent waves. Wave covers 16
// v-columns with FULL k-state: lane = kq*16+vi, thread owns state rows
// [kq*32, kq*32+32) of column v = wg*16+vi (8 named f32x4 — non-spilling).
// k-reduction = in-wave butterfly (shfl_xor 16,32) — zero barriers, zero LDS;
// compiler free to prefetch step t+1 loads during step t compute.
#define R8(X) X(0) X(1) X(2) X(3) X(4) X(5) X(6) X(7)

__global__ __launch_bounds__(64, 1) void scan_kernel(const float* __restrict__ q_s,
                                                     const float* __restrict__ k_s,
                                                     const float* __restrict__ v_s,
                                                     const float* __restrict__ beta_s,
                                                     const float* __restrict__ ge_s,
                                                     float* __restrict__ o_s,
                                                     float* __restrict__ state_out) {
  const int blk = blockIdx.x;      // 0..127
  const int bh  = blk >> 3;        // chain 0..15
  const int wg  = blk & 7;         // v-group 0..7
  const int lane = threadIdx.x;    // 0..63
  const int kq = lane >> 4;        // k-quarter 0..3
  const int vi = lane & 15;
  const int v  = wg * 16 + vi;     // global v column 0..127

#define DECL(n) f32x4 s##n = {0.f, 0.f, 0.f, 0.f};
  R8(DECL)
#undef DECL

  const float* qp0  = q_s + (size_t)bh * 512 * 128 + kq * 32;
  const float* k0p0 = k_s + ((size_t)bh * 2 + 0) * 512 * 128 + kq * 32;
  const float* k1p0 = k_s + ((size_t)bh * 2 + 1) * 512 * 128 + kq * 32;
  const float* v0p0 = v_s + ((size_t)bh * 2 + 0) * 512 * 128 + v;
  const float* v1p0 = v_s + ((size_t)bh * 2 + 1) * 512 * 128 + v;
  const float* b0p = beta_s + ((size_t)bh * 2 + 0) * 512;
  const float* b1p = beta_s + ((size_t)bh * 2 + 1) * 512;
  const float* gp  = ge_s + (size_t)bh * 512;

  for (int t = 0; t < 512; ++t) {
    const float eg  = gp[t];
    const float bb0 = b0p[t], bb1 = b1p[t];
    const float mv0 = v0p0[(size_t)t * 128];
    const float mv1 = v1p0[(size_t)t * 128];
    const f32x4* __restrict__ k0p = (const f32x4*)(k0p0 + (size_t)t * 128);
    const f32x4* __restrict__ k1p = (const f32x4*)(k1p0 + (size_t)t * 128);
    const f32x4* __restrict__ qp  = (const f32x4*)(qp0  + (size_t)t * 128);
#define LD(n) f32x4 a##n = k0p[n]; f32x4 b##n = k1p[n]; f32x4 c##n = qp[n];
    R8(LD)
#undef LD
    // pass 1: decay + corr0 partial
    f32x4 acc = {0.f, 0.f, 0.f, 0.f};
#define P1(n) { s##n *= eg; acc += a##n * s##n; }
    R8(P1)
#undef P1
    float p = (acc[0] + acc[1]) + (acc[2] + acc[3]);
    p += __shfl_xor(p, 16);
    p += __shfl_xor(p, 32);
    const float u0 = (mv0 - p) * bb0;
    // pass 2: update j0 + corr1 partial
    acc = (f32x4){0.f, 0.f, 0.f, 0.f};
#define P2(n) { s##n += a##n * u0; acc += b##n * s##n; }
    R8(P2)
#undef P2
    p = (acc[0] + acc[1]) + (acc[2] + acc[3]);
    p += __shfl_xor(p, 16);
    p += __shfl_xor(p, 32);
    const float u1 = (mv1 - p) * bb1;
    // pass 3: update j1 + output partial
    acc = (f32x4){0.f, 0.f, 0.f, 0.f};
#define P3(n) { s##n += b##n * u1; acc += c##n * s##n; }
    R8(P3)
#undef P3
    p = (acc[0] + acc[1]) + (acc[2] + acc[3]);
    p += __shfl_xor(p, 16);
    p += __shfl_xor(p, 32);
    if (kq == 0) o_s[((size_t)bh * 512 + t) * 128 + v] = p;
  }
  float* base = state_out + (size_t)bh * 128 * 128 + v;
#define WOUT(n) { base[(kq * 32 + n * 4 + 0) * 128] = s##n[0]; \
                  base[(kq * 32 + n * 4 + 1) * 128] = s##n[1]; \
                  base[(kq * 32 + n * 4 + 2) * 128] = s##n[2]; \
                  base[(kq * 32 + n * 4 + 3) * 128] = s##n[3]; }
  R8(WOUT)
#undef WOUT
}

// ---------------- rmsnorm + gate silu -> bf16 A for final GEMM ----------------
__global__ __launch_bounds__(128) void post_kernel(const float* __restrict__ o_s,
                                                   const float* __restrict__ g_lin,
                                                   const float* __restrict__ norm_w,
                                                   __hip_bfloat16* __restrict__ Afin) {
  int bt = blockIdx.x;
  int h = blockIdx.y;
  int d = threadIdx.x;
  int b = bt >> 9, t = bt & 511;
  int bh = b * 8 + h;
  float o = o_s[((size_t)bh * 512 + t) * 128 + d];
  __shared__ float red[2];
  float ss = o * o;
#pragma unroll
  for (int off = 32; off; off >>= 1) ss += __shfl_down(ss, off);
  if ((d & 63) == 0) red[d >> 6] = ss;
  __syncthreads();
  float mean = (red[0] + red[1]) * (1.f / 128.f);
  float r = rsqrtf(mean + 1e-5f);
  float gate = g_lin[(size_t)bt * 1024 + h * 128 + d];
  float val = o * r * norm_w[d] * silu_f(gate);
  Afin[(size_t)bt * 1024 + h * 128 + d] = __float2bfloat16(val);
}

extern "C" void kernel_launch(void* const* d_in, const int* in_sizes, int n_in,
                              void* d_out, int out_size, void* d_ws, size_t ws_size,
                              hipStream_t stream) {
  const float* x       = (const float*)d_in[0];
  const float* Wq      = (const float*)d_in[1];
  const float* Wk      = (const float*)d_in[2];
  const float* Wv      = (const float*)d_in[3];
  const float* Wb      = (const float*)d_in[4];
  const float* Wa      = (const float*)d_in[5];
  const float* A_log   = (const float*)d_in[6];
  const float* dt_bias = (const float*)d_in[7];
  const float* cqw     = (const float*)d_in[8];
  const float* ckw     = (const float*)d_in[9];
  const float* cvw     = (const float*)d_in[10];
  const float* Wg      = (const float*)d_in[11];
  const float* norm_w  = (const float*)d_in[12];
  const float* Wo      = (const float*)d_in[13];

  char* ws = (char*)d_ws;
  size_t off = 0;
  auto alloc = [&](size_t bytes) {
    void* p = ws + off;
    off += (bytes + 255) & ~(size_t)255;
    return p;
  };
  __hip_bfloat16* xbf  = (__hip_bfloat16*)alloc((size_t)2097152 * 2);
  __hip_bfloat16* WqT  = (__hip_bfloat16*)alloc((size_t)2097152 * 2);
  __hip_bfloat16* WkT  = (__hip_bfloat16*)alloc((size_t)4194304 * 2);
  __hip_bfloat16* WvT  = (__hip_bfloat16*)alloc((size_t)4194304 * 2);
  __hip_bfloat16* WgT  = (__hip_bfloat16*)alloc((size_t)2097152 * 2);
  __hip_bfloat16* WoT  = (__hip_bfloat16*)alloc((size_t)2097152 * 2);
  float* q_lin  = (float*)alloc((size_t)1048576 * 4);
  float* k_lin  = (float*)alloc((size_t)2097152 * 4);
  float* v_lin  = (float*)alloc((size_t)2097152 * 4);
  float* g_lin  = (float*)alloc((size_t)1048576 * 4);
  float* xb     = (float*)alloc((size_t)16384 * 4);
  float* xa     = (float*)alloc((size_t)8192 * 4);
  float* q_s    = (float*)alloc((size_t)1048576 * 4);
  float* k_s    = (float*)alloc((size_t)2097152 * 4);
  float* v_s    = (float*)alloc((size_t)2097152 * 4);
  float* beta_s = (float*)alloc((size_t)16384 * 4);
  float* ge_s   = (float*)alloc((size_t)8192 * 4);
  float* o_s    = (float*)alloc((size_t)1048576 * 4);
  __hip_bfloat16* Afin = (__hip_bfloat16*)alloc((size_t)1048576 * 2);

  float* out_main  = (float*)d_out;
  float* out_state = out_main + 2097152;

  dim3 tb(32, 8);
  f2bf_kernel<<<8192, 256, 0, stream>>>(x, xbf, 2097152);
  transpose_f2bf<<<dim3(32, 64), tb, 0, stream>>>(Wq, WqT, 2048, 1024);
  transpose_f2bf<<<dim3(64, 64), tb, 0, stream>>>(Wk, WkT, 2048, 2048);
  transpose_f2bf<<<dim3(64, 64), tb, 0, stream>>>(Wv, WvT, 2048, 2048);
  transpose_f2bf<<<dim3(32, 64), tb, 0, stream>>>(Wg, WgT, 2048, 1024);
  transpose_f2bf<<<dim3(64, 32), tb, 0, stream>>>(Wo, WoT, 1024, 2048);

  gemm_bf16<<<dim3(8, 8),  256, 0, stream>>>(xbf, WqT, q_lin, 1024, 1024, 2048);
  gemm_bf16<<<dim3(16, 8), 256, 0, stream>>>(xbf, WkT, k_lin, 1024, 2048, 2048);
  gemm_bf16<<<dim3(16, 8), 256, 0, stream>>>(xbf, WvT, v_lin, 1024, 2048, 2048);
  gemm_bf16<<<dim3(8, 8),  256, 0, stream>>>(xbf, WgT, g_lin, 1024, 1024, 2048);
  small_gemm_ba<<<dim3(1024, 24), 64, 0, stream>>>(x, Wb, Wa, xb, xa);

  conv_q_kernel<<<dim3(1024, 8),  128, 0, stream>>>(q_lin, cqw, q_s);
  conv_k_kernel<<<dim3(1024, 16), 128, 0, stream>>>(k_lin, ckw, k_s);
  conv_v_kernel<<<dim3(1024, 16), 128, 0, stream>>>(v_lin, cvw, v_s);
  bg_kernel<<<1024, 32, 0, stream>>>(xb, xa, A_log, dt_bias, beta_s, ge_s);

  scan_kernel<<<128, 64, 0, stream>>>(q_s, k_s, v_s, beta_s, ge_s, o_s, out_state);

  post_kernel<<<dim3(1024, 8), 128, 0, stream>>>(o_s, g_lin, norm_w, Afin);
  gemm_bf16<<<dim3(16, 8), 256, 0, stream>>>(Afin, WoT, out_main, 1024, 2048, 1024);
}

// Round 5
// 652.804 us; speedup vs baseline: 7.2958x; 1.2656x over previous
//
#include <hip/hip_runtime.h>
#include <hip/hip_bf16.h>
#include <cmath>

#define B_   2
#define L_   512
#define HID  2048
#define DH   128
#define NH   8
#define NHH  2
#define ROWS 1024  // B_*L_
#define NFUSE 6144 // 1024(q)+2048(k)+2048(v)+1024(g)

typedef float  f32x4  __attribute__((ext_vector_type(4)));
typedef __bf16 bf16x8 __attribute__((ext_vector_type(8)));

#define AS1(p) ((const __attribute__((address_space(1))) unsigned int*)(p))
#define AS3(p) ((__attribute__((address_space(3))) unsigned int*)(p))

__device__ __forceinline__ float dpp_xor1(float x) {
  int r = __builtin_amdgcn_update_dpp(0, __float_as_int(x), 0xB1, 0xF, 0xF, true);
  return __int_as_float(r);
}
__device__ __forceinline__ float dpp_xor2(float x) {
  int r = __builtin_amdgcn_update_dpp(0, __float_as_int(x), 0x4E, 0xF, 0xF, true);
  return __int_as_float(r);
}

// ---------------- f32 -> bf16 elementwise ----------------
__global__ void f2bf_kernel(const float* __restrict__ in, __hip_bfloat16* __restrict__ out, int n) {
  int i = blockIdx.x * 256 + threadIdx.x;
  if (i < n) out[i] = __float2bfloat16(in[i]);
}

// ---------------- f32 (K x N) -> bf16 transposed (N x K) ----------------
__global__ __launch_bounds__(256) void transpose_f2bf(const float* __restrict__ in,
                                                      __hip_bfloat16* __restrict__ out,
                                                      int K, int N) {
  __shared__ float tile[32][33];
  int n0 = blockIdx.x * 32, k0 = blockIdx.y * 32;
  int tx = threadIdx.x, ty = threadIdx.y;  // 32 x 8
#pragma unroll
  for (int i = 0; i < 32; i += 8)
    tile[ty + i][tx] = in[(size_t)(k0 + ty + i) * N + n0 + tx];
  __syncthreads();
#pragma unroll
  for (int i = 0; i < 32; i += 8)
    out[(size_t)(n0 + ty + i) * K + k0 + tx] = __float2bfloat16(tile[tx][ty + i]);
}

// ---------------- bf16 MFMA GEMM: C(MxN) = A(MxK) * BT(NxK)^T ----------------
__global__ __launch_bounds__(256) void gemm_bf16(const __hip_bfloat16* __restrict__ A,
                                                 const __hip_bfloat16* __restrict__ BT,
                                                 float* __restrict__ C, int M, int N, int K) {
  __shared__ __align__(16) __hip_bfloat16 lA[128 * 32];
  __shared__ __align__(16) __hip_bfloat16 lB[128 * 32];
  const int tid = threadIdx.x;
  const int lane = tid & 63;
  const int w = tid >> 6;
  const int wr = w >> 1, wc = w & 1;
  const int row0 = blockIdx.y * 128;
  const int col0 = blockIdx.x * 128;
  f32x4 acc[4][4];
#pragma unroll
  for (int m = 0; m < 4; ++m)
#pragma unroll
    for (int n = 0; n < 4; ++n) acc[m][n] = {0.f, 0.f, 0.f, 0.f};
  const int fr = lane & 15;
  const int ko = (lane >> 4) * 8;
  for (int kt = 0; kt < K; kt += 32) {
#pragma unroll
    for (int i = 0; i < 2; ++i) {
      int elem = (w * 2 + i) * 512 + lane * 8;
      int rr = elem >> 5, cc = elem & 31;
      const __hip_bfloat16* srcA = A + (size_t)(row0 + rr) * K + kt + cc;
      __builtin_amdgcn_global_load_lds(AS1(srcA), AS3(&lA[(w * 2 + i) * 512]), 16, 0, 0);
      const __hip_bfloat16* srcB = BT + (size_t)(col0 + rr) * K + kt + cc;
      __builtin_amdgcn_global_load_lds(AS1(srcB), AS3(&lB[(w * 2 + i) * 512]), 16, 0, 0);
    }
    __syncthreads();
    bf16x8 af[4], bfr[4];
#pragma unroll
    for (int m = 0; m < 4; ++m)
      af[m] = *reinterpret_cast<const bf16x8*>(&lA[(wr * 64 + m * 16 + fr) * 32 + ko]);
#pragma unroll
    for (int n = 0; n < 4; ++n)
      bfr[n] = *reinterpret_cast<const bf16x8*>(&lB[(wc * 64 + n * 16 + fr) * 32 + ko]);
#pragma unroll
    for (int m = 0; m < 4; ++m)
#pragma unroll
      for (int n = 0; n < 4; ++n)
        acc[m][n] = __builtin_amdgcn_mfma_f32_16x16x32_bf16(af[m], bfr[n], acc[m][n], 0, 0, 0);
    __syncthreads();
  }
  const int rq = (lane >> 4) * 4;
#pragma unroll
  for (int m = 0; m < 4; ++m)
#pragma unroll
    for (int n = 0; n < 4; ++n)
#pragma unroll
      for (int r = 0; r < 4; ++r)
        C[(size_t)(row0 + wr * 64 + m * 16 + rq + r) * N + (col0 + wc * 64 + n * 16 + fr)] =
            acc[m][n][r];
}

// ---------------- small GEMM for Wb (16 cols) and Wa (8 cols), f32 ----------------
__global__ void small_gemm_ba(const float* __restrict__ x, const float* __restrict__ Wb,
                              const float* __restrict__ Wa, float* __restrict__ xb,
                              float* __restrict__ xa) {
  int row = blockIdx.x;
  int col = blockIdx.y;
  int lane = threadIdx.x;
  float acc = 0.f;
  if (col < 16) {
    for (int k = lane; k < HID; k += 64) acc += x[(size_t)row * HID + k] * Wb[(size_t)k * 16 + col];
  } else {
    int c = col - 16;
    for (int k = lane; k < HID; k += 64) acc += x[(size_t)row * HID + k] * Wa[(size_t)k * 8 + c];
  }
#pragma unroll
  for (int off = 32; off; off >>= 1) acc += __shfl_down(acc, off);
  if (lane == 0) {
    if (col < 16) xb[(size_t)row * 16 + col] = acc;
    else          xa[(size_t)row * 8 + (col - 16)] = acc;
  }
}

__device__ __forceinline__ float silu_f(float y) { return y / (1.f + __expf(-y)); }

// ---------------- conv + silu + l2norm for q (reads fused qkvg, col base 0) ------
__global__ __launch_bounds__(128) void conv_q_kernel(const float* __restrict__ qkvg,
                                                     const float* __restrict__ wq,
                                                     float* __restrict__ q_s) {
  int bt = blockIdx.x;
  int h  = blockIdx.y;
  int d  = threadIdx.x;
  int b = bt >> 9, t = bt & 511;
  int c = h * 128 + d;
  float y = 0.f;
#pragma unroll
  for (int tau = 0; tau < 4; ++tau) {
    int tt = t - 3 + tau;
    float xv = (tt >= 0) ? qkvg[(size_t)(b * 512 + tt) * NFUSE + c] : 0.f;
    y += xv * wq[c * 4 + tau];
  }
  y = silu_f(y);
  __shared__ float red[2];
  float ss = y * y;
#pragma unroll
  for (int off = 32; off; off >>= 1) ss += __shfl_down(ss, off);
  if ((d & 63) == 0) red[d >> 6] = ss;
  __syncthreads();
  float nrm = sqrtf(red[0] + red[1]);
  float scale = (1.f / fmaxf(nrm, 1e-12f)) * 0.08838834764831845f;
  int bh = b * 8 + h;
  q_s[((size_t)bh * 512 + t) * 128 + d] = y * scale;
}

// ---------------- conv + silu + l2norm for k (col base 1024) ----------------
__global__ __launch_bounds__(128) void conv_k_kernel(const float* __restrict__ qkvg,
                                                     const float* __restrict__ wk,
                                                     float* __restrict__ k_s) {
  int bt = blockIdx.x;
  int jh = blockIdx.y;
  int d  = threadIdx.x;
  int b = bt >> 9, t = bt & 511;
  int j = jh >> 3, h = jh & 7;
  int c = j * 1024 + h * 128 + d;
  float y = 0.f;
#pragma unroll
  for (int tau = 0; tau < 4; ++tau) {
    int tt = t - 3 + tau;
    float xv = (tt >= 0) ? qkvg[(size_t)(b * 512 + tt) * NFUSE + 1024 + c] : 0.f;
    y += xv * wk[c * 4 + tau];
  }
  y = silu_f(y);
  __shared__ float red[2];
  float ss = y * y;
#pragma unroll
  for (int off = 32; off; off >>= 1) ss += __shfl_down(ss, off);
  if ((d & 63) == 0) red[d >> 6] = ss;
  __syncthreads();
  float nrm = sqrtf(red[0] + red[1]);
  float scale = 1.f / fmaxf(nrm, 1e-12f);
  int bh = b * 8 + h;
  k_s[(((size_t)bh * 2 + j) * 512 + t) * 128 + d] = y * scale;
}

// ---------------- conv + silu for v (col base 3072) ----------------
__global__ __launch_bounds__(128) void conv_v_kernel(const float* __restrict__ qkvg,
                                                     const float* __restrict__ wv,
                                                     float* __restrict__ v_s) {
  int bt = blockIdx.x;
  int jh = blockIdx.y;
  int d  = threadIdx.x;
  int b = bt >> 9, t = bt & 511;
  int j = jh >> 3, h = jh & 7;
  int c = j * 1024 + h * 128 + d;
  float y = 0.f;
#pragma unroll
  for (int tau = 0; tau < 4; ++tau) {
    int tt = t - 3 + tau;
    float xv = (tt >= 0) ? qkvg[(size_t)(b * 512 + tt) * NFUSE + 3072 + c] : 0.f;
    y += xv * wv[c * 4 + tau];
  }
  int bh = b * 8 + h;
  v_s[(((size_t)bh * 2 + j) * 512 + t) * 128 + d] = silu_f(y);
}

// ---------------- beta / exp(g) ----------------
__global__ void bg_kernel(const float* __restrict__ xb, const float* __restrict__ xa,
                          const float* __restrict__ A_log, const float* __restrict__ dt_bias,
                          float* __restrict__ beta_s, float* __restrict__ ge_s) {
  int bt = blockIdx.x;
  int i = threadIdx.x;
  int b = bt >> 9, t = bt & 511;
  if (i < 16) {
    int j = i >> 3, h = i & 7;
    float v = xb[(size_t)bt * 16 + i];
    float bv = 2.f / (1.f + __expf(-v));
    beta_s[(((size_t)(b * 8 + h)) * 2 + j) * 512 + t] = bv;
  } else if (i < 24) {
    int h = i - 16;
    float v = xa[(size_t)bt * 8 + h] + dt_bias[h];
    float sp = (v > 20.f) ? v : log1pf(__expf(v));
    float g = -__expf(A_log[h]) * sp;
    ge_s[((size_t)(b * 8 + h)) * 512 + t] = __expf(g);
  }
}

// ---------------- sequential gated delta-product scan ----------------
// 128 blocks x 64 thr = 16 chains x 8 independent waves (zero barriers/LDS).
// Lane = vi*4 + kq (kq in bits 0-1): k-reduction = DPP quad_perm xor1+xor2
// (VALU speed, no DS ops). Thread owns state rows [kq*32,kq*32+32) of column
// v = wg*16 + vi as 8 named f32x4.
// Unroll-2 with TWO named load sets (A/B): loads for step t+1 are issued
// before compute of step t -> L2 latency off the critical path (round-4
// counters showed VGPR=52: compiler had serialized loads through ~8 regs).
#define R8(X) X(0) X(1) X(2) X(3) X(4) X(5) X(6) X(7)

__global__ __launch_bounds__(64, 1) void scan_kernel(const float* __restrict__ q_s,
                                                     const float* __restrict__ k_s,
                                                     const float* __restrict__ v_s,
                                                     const float* __restrict__ beta_s,
                                                     const float* __restrict__ ge_s,
                                                     float* __restrict__ o_s,
                                                     float* __restrict__ state_out) {
  const int blk = blockIdx.x;      // 0..127
  const int bh  = blk >> 3;        // chain 0..15
  const int wg  = blk & 7;         // v-group 0..7
  const int lane = threadIdx.x;    // 0..63
  const int kq = lane & 3;         // k-quarter 0..3
  const int vi = lane >> 2;        // 0..15
  const int v  = wg * 16 + vi;     // global v column 0..127

#define DECL(n) f32x4 s##n = {0.f, 0.f, 0.f, 0.f}; \
                f32x4 aA##n, bA##n, cA##n, aB##n, bB##n, cB##n;
  R8(DECL)
#undef DECL
  float egA, p0A, p1A, m0A, m1A;
  float egB, p0B, p1B, m0B, m1B;

  const float* qp0  = q_s + (size_t)bh * 512 * 128 + kq * 32;
  const float* k0p0 = k_s + ((size_t)bh * 2 + 0) * 512 * 128 + kq * 32;
  const float* k1p0 = k_s + ((size_t)bh * 2 + 1) * 512 * 128 + kq * 32;
  const float* v0p0 = v_s + ((size_t)bh * 2 + 0) * 512 * 128 + v;
  const float* v1p0 = v_s + ((size_t)bh * 2 + 1) * 512 * 128 + v;
  const float* b0p = beta_s + ((size_t)bh * 2 + 0) * 512;
  const float* b1p = beta_s + ((size_t)bh * 2 + 1) * 512;
  const float* gp  = ge_s + (size_t)bh * 512;

#define LD_A(n) aA##n = k0p[n]; bA##n = k1p[n]; cA##n = qp[n];
#define LD_B(n) aB##n = k0p[n]; bB##n = k1p[n]; cB##n = qp[n];
#define LOAD_A(tt) { const f32x4* __restrict__ k0p = (const f32x4*)(k0p0 + (size_t)(tt) * 128); \
                     const f32x4* __restrict__ k1p = (const f32x4*)(k1p0 + (size_t)(tt) * 128); \
                     const f32x4* __restrict__ qp  = (const f32x4*)(qp0  + (size_t)(tt) * 128); \
                     R8(LD_A) \
                     egA = gp[tt]; p0A = b0p[tt]; p1A = b1p[tt]; \
                     m0A = v0p0[(size_t)(tt) * 128]; m1A = v1p0[(size_t)(tt) * 128]; }
#define LOAD_B(tt) { const f32x4* __restrict__ k0p = (const f32x4*)(k0p0 + (size_t)(tt) * 128); \
                     const f32x4* __restrict__ k1p = (const f32x4*)(k1p0 + (size_t)(tt) * 128); \
                     const f32x4* __restrict__ qp  = (const f32x4*)(qp0  + (size_t)(tt) * 128); \
                     R8(LD_B) \
                     egB = gp[tt]; p0B = b0p[tt]; p1B = b1p[tt]; \
                     m0B = v0p0[(size_t)(tt) * 128]; m1B = v1p0[(size_t)(tt) * 128]; }

#define P1_A(n) { s##n *= egA; acc += aA##n * s##n; }
#define P2_A(n) { s##n += aA##n * u0; acc += bA##n * s##n; }
#define P3_A(n) { s##n += bA##n * u1; acc += cA##n * s##n; }
#define P1_B(n) { s##n *= egB; acc += aB##n * s##n; }
#define P2_B(n) { s##n += aB##n * u0; acc += bB##n * s##n; }
#define P3_B(n) { s##n += bB##n * u1; acc += cB##n * s##n; }

#define COMPUTE(S, tt) { \
    f32x4 acc = {0.f, 0.f, 0.f, 0.f}; \
    R8(P1_##S) \
    float p = (acc[0] + acc[1]) + (acc[2] + acc[3]); \
    p += dpp_xor1(p); p += dpp_xor2(p); \
    const float u0 = (m0##S - p) * p0##S; \
    acc = (f32x4){0.f, 0.f, 0.f, 0.f}; \
    R8(P2_##S) \
    p = (acc[0] + acc[1]) + (acc[2] + acc[3]); \
    p += dpp_xor1(p); p += dpp_xor2(p); \
    const float u1 = (m1##S - p) * p1##S; \
    acc = (f32x4){0.f, 0.f, 0.f, 0.f}; \
    R8(P3_##S) \
    p = (acc[0] + acc[1]) + (acc[2] + acc[3]); \
    p += dpp_xor1(p); p += dpp_xor2(p); \
    if (kq == 0) o_s[((size_t)bh * 512 + (tt)) * 128 + v] = p; }

  LOAD_A(0)
  for (int t = 0; t < 512; t += 2) {
    LOAD_B(t + 1)
    COMPUTE(A, t)
    const int tn = (t + 2) & 511;  // wraps to 0 on last iter (dummy, harmless)
    LOAD_A(tn)
    COMPUTE(B, t + 1)
  }

  float* base = state_out + (size_t)bh * 128 * 128 + v;
#define WOUT(n) { base[(kq * 32 + n * 4 + 0) * 128] = s##n[0]; \
                  base[(kq * 32 + n * 4 + 1) * 128] = s##n[1]; \
                  base[(kq * 32 + n * 4 + 2) * 128] = s##n[2]; \
                  base[(kq * 32 + n * 4 + 3) * 128] = s##n[3]; }
  R8(WOUT)
#undef WOUT
}

// ---------------- rmsnorm + gate silu -> bf16 A for final GEMM ----------------
__global__ __launch_bounds__(128) void post_kernel(const float* __restrict__ o_s,
                                                   const float* __restrict__ qkvg,
                                                   const float* __restrict__ norm_w,
                                                   __hip_bfloat16* __restrict__ Afin) {
  int bt = blockIdx.x;
  int h = blockIdx.y;
  int d = threadIdx.x;
  int b = bt >> 9, t = bt & 511;
  int bh = b * 8 + h;
  float o = o_s[((size_t)bh * 512 + t) * 128 + d];
  __shared__ float red[2];
  float ss = o * o;
#pragma unroll
  for (int off = 32; off; off >>= 1) ss += __shfl_down(ss, off);
  if ((d & 63) == 0) red[d >> 6] = ss;
  __syncthreads();
  float mean = (red[0] + red[1]) * (1.f / 128.f);
  float r = rsqrtf(mean + 1e-5f);
  float gate = qkvg[(size_t)bt * NFUSE + 5120 + h * 128 + d];
  float val = o * r * norm_w[d] * silu_f(gate);
  Afin[(size_t)bt * 1024 + h * 128 + d] = __float2bfloat16(val);
}

extern "C" void kernel_launch(void* const* d_in, const int* in_sizes, int n_in,
                              void* d_out, int out_size, void* d_ws, size_t ws_size,
                              hipStream_t stream) {
  const float* x       = (const float*)d_in[0];
  const float* Wq      = (const float*)d_in[1];
  const float* Wk      = (const float*)d_in[2];
  const float* Wv      = (const float*)d_in[3];
  const float* Wb      = (const float*)d_in[4];
  const float* Wa      = (const float*)d_in[5];
  const float* A_log   = (const float*)d_in[6];
  const float* dt_bias = (const float*)d_in[7];
  const float* cqw     = (const float*)d_in[8];
  const float* ckw     = (const float*)d_in[9];
  const float* cvw     = (const float*)d_in[10];
  const float* Wg      = (const float*)d_in[11];
  const float* norm_w  = (const float*)d_in[12];
  const float* Wo      = (const float*)d_in[13];

  char* ws = (char*)d_ws;
  size_t off = 0;
  auto alloc = [&](size_t bytes) {
    void* p = ws + off;
    off += (bytes + 255) & ~(size_t)255;
    return p;
  };
  __hip_bfloat16* xbf  = (__hip_bfloat16*)alloc((size_t)2097152 * 2);
  __hip_bfloat16* WT   = (__hip_bfloat16*)alloc((size_t)NFUSE * 2048 * 2);  // fused q|k|v|g, [N][K]
  __hip_bfloat16* WoT  = (__hip_bfloat16*)alloc((size_t)2097152 * 2);
  float* qkvg   = (float*)alloc((size_t)ROWS * NFUSE * 4);
  float* xb     = (float*)alloc((size_t)16384 * 4);
  float* xa     = (float*)alloc((size_t)8192 * 4);
  float* q_s    = (float*)alloc((size_t)1048576 * 4);
  float* k_s    = (float*)alloc((size_t)2097152 * 4);
  float* v_s    = (float*)alloc((size_t)2097152 * 4);
  float* beta_s = (float*)alloc((size_t)16384 * 4);
  float* ge_s   = (float*)alloc((size_t)8192 * 4);
  float* o_s    = (float*)alloc((size_t)1048576 * 4);
  __hip_bfloat16* Afin = (__hip_bfloat16*)alloc((size_t)1048576 * 2);

  float* out_main  = (float*)d_out;
  float* out_state = out_main + 2097152;

  dim3 tb(32, 8);
  f2bf_kernel<<<8192, 256, 0, stream>>>(x, xbf, 2097152);
  transpose_f2bf<<<dim3(32, 64), tb, 0, stream>>>(Wq, WT,                        2048, 1024);
  transpose_f2bf<<<dim3(64, 64), tb, 0, stream>>>(Wk, WT + (size_t)1024 * 2048,  2048, 2048);
  transpose_f2bf<<<dim3(64, 64), tb, 0, stream>>>(Wv, WT + (size_t)3072 * 2048,  2048, 2048);
  transpose_f2bf<<<dim3(32, 64), tb, 0, stream>>>(Wg, WT + (size_t)5120 * 2048,  2048, 1024);
  transpose_f2bf<<<dim3(64, 32), tb, 0, stream>>>(Wo, WoT, 1024, 2048);

  gemm_bf16<<<dim3(48, 8), 256, 0, stream>>>(xbf, WT, qkvg, 1024, NFUSE, 2048);
  small_gemm_ba<<<dim3(1024, 24), 64, 0, stream>>>(x, Wb, Wa, xb, xa);

  conv_q_kernel<<<dim3(1024, 8),  128, 0, stream>>>(qkvg, cqw, q_s);
  conv_k_kernel<<<dim3(1024, 16), 128, 0, stream>>>(qkvg, ckw, k_s);
  conv_v_kernel<<<dim3(1024, 16), 128, 0, stream>>>(qkvg, cvw, v_s);
  bg_kernel<<<1024, 32, 0, stream>>>(xb, xa, A_log, dt_bias, beta_s, ge_s);

  scan_kernel<<<128, 64, 0, stream>>>(q_s, k_s, v_s, beta_s, ge_s, o_s, out_state);

  post_kernel<<<dim3(1024, 8), 128, 0, stream>>>(o_s, qkvg, norm_w, Afin);
  gemm_bf16<<<dim3(16, 8), 256, 0, stream>>>(Afin, WoT, out_main, 1024, 2048, 1024);
}

// Round 6
// 493.375 us; speedup vs baseline: 9.6534x; 1.3231x over previous
//
#include <hip/hip_runtime.h>
#include <hip/hip_bf16.h>
#include <cmath>

#define B_   2
#define L_   512
#define HID  2048
#define DH   128
#define NH   8
#define NHH  2
#define ROWS 1024  // B_*L_
#define NFUSE 6144 // 1024(q)+2048(k)+2048(v)+1024(g)

typedef float  f32x4  __attribute__((ext_vector_type(4)));
typedef __bf16 bf16x8 __attribute__((ext_vector_type(8)));

#define AS1(p) ((const __attribute__((address_space(1))) unsigned int*)(p))
#define AS3(p) ((__attribute__((address_space(3))) unsigned int*)(p))

__device__ __forceinline__ float dpp_xor1(float x) {
  int r = __builtin_amdgcn_update_dpp(0, __float_as_int(x), 0xB1, 0xF, 0xF, true);
  return __int_as_float(r);
}
__device__ __forceinline__ float dpp_xor2(float x) {
  int r = __builtin_amdgcn_update_dpp(0, __float_as_int(x), 0x4E, 0xF, 0xF, true);
  return __int_as_float(r);
}

// ---------------- f32 -> bf16 elementwise ----------------
__global__ void f2bf_kernel(const float* __restrict__ in, __hip_bfloat16* __restrict__ out, int n) {
  int i = blockIdx.x * 256 + threadIdx.x;
  if (i < n) out[i] = __float2bfloat16(in[i]);
}

// ---------------- f32 (K x N) -> bf16 transposed (N x K) ----------------
__global__ __launch_bounds__(256) void transpose_f2bf(const float* __restrict__ in,
                                                      __hip_bfloat16* __restrict__ out,
                                                      int K, int N) {
  __shared__ float tile[32][33];
  int n0 = blockIdx.x * 32, k0 = blockIdx.y * 32;
  int tx = threadIdx.x, ty = threadIdx.y;  // 32 x 8
#pragma unroll
  for (int i = 0; i < 32; i += 8)
    tile[ty + i][tx] = in[(size_t)(k0 + ty + i) * N + n0 + tx];
  __syncthreads();
#pragma unroll
  for (int i = 0; i < 32; i += 8)
    out[(size_t)(n0 + ty + i) * K + k0 + tx] = __float2bfloat16(tile[tx][ty + i]);
}

// ---------------- bf16 MFMA GEMM: C(MxN) = A(MxK) * BT(NxK)^T ----------------
__global__ __launch_bounds__(256) void gemm_bf16(const __hip_bfloat16* __restrict__ A,
                                                 const __hip_bfloat16* __restrict__ BT,
                                                 float* __restrict__ C, int M, int N, int K) {
  __shared__ __align__(16) __hip_bfloat16 lA[128 * 32];
  __shared__ __align__(16) __hip_bfloat16 lB[128 * 32];
  const int tid = threadIdx.x;
  const int lane = tid & 63;
  const int w = tid >> 6;
  const int wr = w >> 1, wc = w & 1;
  const int row0 = blockIdx.y * 128;
  const int col0 = blockIdx.x * 128;
  f32x4 acc[4][4];
#pragma unroll
  for (int m = 0; m < 4; ++m)
#pragma unroll
    for (int n = 0; n < 4; ++n) acc[m][n] = {0.f, 0.f, 0.f, 0.f};
  const int fr = lane & 15;
  const int ko = (lane >> 4) * 8;
  for (int kt = 0; kt < K; kt += 32) {
#pragma unroll
    for (int i = 0; i < 2; ++i) {
      int elem = (w * 2 + i) * 512 + lane * 8;
      int rr = elem >> 5, cc = elem & 31;
      const __hip_bfloat16* srcA = A + (size_t)(row0 + rr) * K + kt + cc;
      __builtin_amdgcn_global_load_lds(AS1(srcA), AS3(&lA[(w * 2 + i) * 512]), 16, 0, 0);
      const __hip_bfloat16* srcB = BT + (size_t)(col0 + rr) * K + kt + cc;
      __builtin_amdgcn_global_load_lds(AS1(srcB), AS3(&lB[(w * 2 + i) * 512]), 16, 0, 0);
    }
    __syncthreads();
    bf16x8 af[4], bfr[4];
#pragma unroll
    for (int m = 0; m < 4; ++m)
      af[m] = *reinterpret_cast<const bf16x8*>(&lA[(wr * 64 + m * 16 + fr) * 32 + ko]);
#pragma unroll
    for (int n = 0; n < 4; ++n)
      bfr[n] = *reinterpret_cast<const bf16x8*>(&lB[(wc * 64 + n * 16 + fr) * 32 + ko]);
#pragma unroll
    for (int m = 0; m < 4; ++m)
#pragma unroll
      for (int n = 0; n < 4; ++n)
        acc[m][n] = __builtin_amdgcn_mfma_f32_16x16x32_bf16(af[m], bfr[n], acc[m][n], 0, 0, 0);
    __syncthreads();
  }
  const int rq = (lane >> 4) * 4;
#pragma unroll
  for (int m = 0; m < 4; ++m)
#pragma unroll
    for (int n = 0; n < 4; ++n)
#pragma unroll
      for (int r = 0; r < 4; ++r)
        C[(size_t)(row0 + wr * 64 + m * 16 + rq + r) * N + (col0 + wc * 64 + n * 16 + fr)] =
            acc[m][n][r];
}

// ---------------- small GEMM for Wb (16 cols) and Wa (8 cols), f32 ----------------
__global__ void small_gemm_ba(const float* __restrict__ x, const float* __restrict__ Wb,
                              const float* __restrict__ Wa, float* __restrict__ xb,
                              float* __restrict__ xa) {
  int row = blockIdx.x;
  int col = blockIdx.y;
  int lane = threadIdx.x;
  float acc = 0.f;
  if (col < 16) {
    for (int k = lane; k < HID; k += 64) acc += x[(size_t)row * HID + k] * Wb[(size_t)k * 16 + col];
  } else {
    int c = col - 16;
    for (int k = lane; k < HID; k += 64) acc += x[(size_t)row * HID + k] * Wa[(size_t)k * 8 + c];
  }
#pragma unroll
  for (int off = 32; off; off >>= 1) acc += __shfl_down(acc, off);
  if (lane == 0) {
    if (col < 16) xb[(size_t)row * 16 + col] = acc;
    else          xa[(size_t)row * 8 + (col - 16)] = acc;
  }
}

__device__ __forceinline__ float silu_f(float y) { return y / (1.f + __expf(-y)); }

// ---------------- conv + silu + l2norm for q (reads fused qkvg, col base 0) ------
__global__ __launch_bounds__(128) void conv_q_kernel(const float* __restrict__ qkvg,
                                                     const float* __restrict__ wq,
                                                     float* __restrict__ q_s) {
  int bt = blockIdx.x;
  int h  = blockIdx.y;
  int d  = threadIdx.x;
  int b = bt >> 9, t = bt & 511;
  int c = h * 128 + d;
  float y = 0.f;
#pragma unroll
  for (int tau = 0; tau < 4; ++tau) {
    int tt = t - 3 + tau;
    float xv = (tt >= 0) ? qkvg[(size_t)(b * 512 + tt) * NFUSE + c] : 0.f;
    y += xv * wq[c * 4 + tau];
  }
  y = silu_f(y);
  __shared__ float red[2];
  float ss = y * y;
#pragma unroll
  for (int off = 32; off; off >>= 1) ss += __shfl_down(ss, off);
  if ((d & 63) == 0) red[d >> 6] = ss;
  __syncthreads();
  float nrm = sqrtf(red[0] + red[1]);
  float scale = (1.f / fmaxf(nrm, 1e-12f)) * 0.08838834764831845f;
  int bh = b * 8 + h;
  q_s[((size_t)bh * 512 + t) * 128 + d] = y * scale;
}

// ---------------- conv + silu + l2norm for k (col base 1024) ----------------
__global__ __launch_bounds__(128) void conv_k_kernel(const float* __restrict__ qkvg,
                                                     const float* __restrict__ wk,
                                                     float* __restrict__ k_s) {
  int bt = blockIdx.x;
  int jh = blockIdx.y;
  int d  = threadIdx.x;
  int b = bt >> 9, t = bt & 511;
  int j = jh >> 3, h = jh & 7;
  int c = j * 1024 + h * 128 + d;
  float y = 0.f;
#pragma unroll
  for (int tau = 0; tau < 4; ++tau) {
    int tt = t - 3 + tau;
    float xv = (tt >= 0) ? qkvg[(size_t)(b * 512 + tt) * NFUSE + 1024 + c] : 0.f;
    y += xv * wk[c * 4 + tau];
  }
  y = silu_f(y);
  __shared__ float red[2];
  float ss = y * y;
#pragma unroll
  for (int off = 32; off; off >>= 1) ss += __shfl_down(ss, off);
  if ((d & 63) == 0) red[d >> 6] = ss;
  __syncthreads();
  float nrm = sqrtf(red[0] + red[1]);
  float scale = 1.f / fmaxf(nrm, 1e-12f);
  int bh = b * 8 + h;
  k_s[(((size_t)bh * 2 + j) * 512 + t) * 128 + d] = y * scale;
}

// ---------------- conv + silu for v (col base 3072) ----------------
__global__ __launch_bounds__(128) void conv_v_kernel(const float* __restrict__ qkvg,
                                                     const float* __restrict__ wv,
                                                     float* __restrict__ v_s) {
  int bt = blockIdx.x;
  int jh = blockIdx.y;
  int d  = threadIdx.x;
  int b = bt >> 9, t = bt & 511;
  int j = jh >> 3, h = jh & 7;
  int c = j * 1024 + h * 128 + d;
  float y = 0.f;
#pragma unroll
  for (int tau = 0; tau < 4; ++tau) {
    int tt = t - 3 + tau;
    float xv = (tt >= 0) ? qkvg[(size_t)(b * 512 + tt) * NFUSE + 3072 + c] : 0.f;
    y += xv * wv[c * 4 + tau];
  }
  int bh = b * 8 + h;
  v_s[(((size_t)bh * 2 + j) * 512 + t) * 128 + d] = silu_f(y);
}

// ---------------- beta / exp(g) ----------------
__global__ void bg_kernel(const float* __restrict__ xb, const float* __restrict__ xa,
                          const float* __restrict__ A_log, const float* __restrict__ dt_bias,
                          float* __restrict__ beta_s, float* __restrict__ ge_s) {
  int bt = blockIdx.x;
  int i = threadIdx.x;
  int b = bt >> 9, t = bt & 511;
  if (i < 16) {
    int j = i >> 3, h = i & 7;
    float v = xb[(size_t)bt * 16 + i];
    float bv = 2.f / (1.f + __expf(-v));
    beta_s[(((size_t)(b * 8 + h)) * 2 + j) * 512 + t] = bv;
  } else if (i < 24) {
    int h = i - 16;
    float v = xa[(size_t)bt * 8 + h] + dt_bias[h];
    float sp = (v > 20.f) ? v : log1pf(__expf(v));
    float g = -__expf(A_log[h]) * sp;
    ge_s[((size_t)(b * 8 + h)) * 512 + t] = __expf(g);
  }
}

// ---------------- sequential gated delta-product scan, LDS-staged ----------------
// 128 blocks x 64 thr (ONE wave — no barriers) = 16 chains x 8 v-groups.
// Lane = vi*4+kq; state rows [kq*32,kq*32+32) of col v=wg*16+vi as 8 named f32x4.
// k0/k1/q staged per 16-step tile into LDS (double buffer): G-regs load tile T+1
// one full tile-compute ahead (vmcnt free); ds_write at head of tile T; hot-path
// reads are conflict-free ds_read_b128 (quad rows padded to 36 floats:
// bank = 4*kq + 4*n  -> distinct per quad; 16-lane same-addr broadcast free).
// Round-5 lesson: register double-buffer of global loads was un-allocatable
// (VGPR=96); LDS staging moves the latency budget from per-step to per-tile.
#define R8(X) X(0) X(1) X(2) X(3) X(4) X(5) X(6) X(7)
#define TROW 36                 // padded row floats (32 data + 4 pad)
#define TILE_FLOATS (16 * 3 * 4 * TROW)   // 6912 per buffer

__global__ __launch_bounds__(64, 1) void scan_kernel(const float* __restrict__ q_s,
                                                     const float* __restrict__ k_s,
                                                     const float* __restrict__ v_s,
                                                     const float* __restrict__ beta_s,
                                                     const float* __restrict__ ge_s,
                                                     float* __restrict__ o_s,
                                                     float* __restrict__ state_out) {
  const int blk = blockIdx.x;      // 0..127
  const int bh  = blk >> 3;        // chain 0..15
  const int wg  = blk & 7;         // v-group 0..7
  const int lane = threadIdx.x;    // 0..63
  const int kq = lane & 3;         // k-quarter 0..3 (compute mapping)
  const int vi = lane >> 2;        // 0..15
  const int v  = wg * 16 + vi;     // global v column 0..127

  // staging lane decomposition (independent of compute mapping)
  const int s_n  = lane & 7;          // f32x4 col within quad row
  const int s_kq = (lane >> 3) & 3;   // quad row
  const int s_th = lane >> 5;         // tloc parity base

  __shared__ __align__(16) float lds[2][TILE_FLOATS];

#define DECL(n) f32x4 s##n = {0.f, 0.f, 0.f, 0.f}; f32x4 G0_##n, G1_##n, G2_##n;
  R8(DECL)
#undef DECL

  const float* g_k0 = k_s + ((size_t)bh * 2 + 0) * 512 * 128;
  const float* g_k1 = k_s + ((size_t)bh * 2 + 1) * 512 * 128;
  const float* g_q  = q_s + (size_t)bh * 512 * 128;
  const float* v0p0 = v_s + ((size_t)bh * 2 + 0) * 512 * 128 + v;
  const float* v1p0 = v_s + ((size_t)bh * 2 + 1) * 512 * 128 + v;
  const float* b0p = beta_s + ((size_t)bh * 2 + 0) * 512;
  const float* b1p = beta_s + ((size_t)bh * 2 + 1) * 512;
  const float* gp  = ge_s + (size_t)bh * 512;

  // tile T: operand blocks of 2048 contiguous floats (16 steps x 128)
#define LD1(j) { G0_##j = p0[lane + j * 64]; G1_##j = p1[lane + j * 64]; G2_##j = pq[lane + j * 64]; }
#define LOAD_G(T) { const f32x4* __restrict__ p0 = (const f32x4*)(g_k0 + (size_t)(T) * 2048); \
                    const f32x4* __restrict__ p1 = (const f32x4*)(g_k1 + (size_t)(T) * 2048); \
                    const f32x4* __restrict__ pq = (const f32x4*)(g_q  + (size_t)(T) * 2048); \
                    R8(LD1) }
  // dest float off = ((tloc*3 + o)*4 + s_kq)*TROW + s_n*4, tloc = s_th + 2j
#define WR1(j) { int tl = s_th + 2 * j; \
    *(f32x4*)&lds[bsel][((tl * 3 + 0) * 4 + s_kq) * TROW + s_n * 4] = G0_##j; \
    *(f32x4*)&lds[bsel][((tl * 3 + 1) * 4 + s_kq) * TROW + s_n * 4] = G1_##j; \
    *(f32x4*)&lds[bsel][((tl * 3 + 2) * 4 + s_kq) * TROW + s_n * 4] = G2_##j; }
#define WRITE_G(b) { const int bsel = (b); R8(WR1) }

  LOAD_G(0)
  WRITE_G(0)     // compiler inserts vmcnt wait via data dependency
  LOAD_G(1)

  for (int T = 0; T < 32; ++T) {
    const int buf = T & 1;
    if (T < 31) { WRITE_G(buf ^ 1) }       // stage tile T+1 (G loaded last iter)
    if (T < 30) { LOAD_G(T + 2) }          // issue next tile's loads (deep prefetch)
    for (int tl = 0; tl < 16; ++tl) {
      const int t = T * 16 + tl;
      const float eg  = gp[t];
      const float bb0 = b0p[t], bb1 = b1p[t];
      const float mv0 = v0p0[(size_t)t * 128];
      const float mv1 = v1p0[(size_t)t * 128];
      const f32x4* __restrict__ pk0 = (const f32x4*)&lds[buf][((tl * 3 + 0) * 4 + kq) * TROW];
      const f32x4* __restrict__ pk1 = (const f32x4*)&lds[buf][((tl * 3 + 1) * 4 + kq) * TROW];
      const f32x4* __restrict__ pq  = (const f32x4*)&lds[buf][((tl * 3 + 2) * 4 + kq) * TROW];
#define LDS_LD(n) f32x4 a##n = pk0[n]; f32x4 b##n = pk1[n]; f32x4 c##n = pq[n];
      R8(LDS_LD)
#undef LDS_LD
      f32x4 acc = {0.f, 0.f, 0.f, 0.f};
#define P1(n) { s##n *= eg; acc += a##n * s##n; }
      R8(P1)
#undef P1
      float p = (acc[0] + acc[1]) + (acc[2] + acc[3]);
      p += dpp_xor1(p); p += dpp_xor2(p);
      const float u0 = (mv0 - p) * bb0;
      acc = (f32x4){0.f, 0.f, 0.f, 0.f};
#define P2(n) { s##n += a##n * u0; acc += b##n * s##n; }
      R8(P2)
#undef P2
      p = (acc[0] + acc[1]) + (acc[2] + acc[3]);
      p += dpp_xor1(p); p += dpp_xor2(p);
      const float u1 = (mv1 - p) * bb1;
      acc = (f32x4){0.f, 0.f, 0.f, 0.f};
#define P3(n) { s##n += b##n * u1; acc += c##n * s##n; }
      R8(P3)
#undef P3
      p = (acc[0] + acc[1]) + (acc[2] + acc[3]);
      p += dpp_xor1(p); p += dpp_xor2(p);
      if (kq == 0) o_s[((size_t)bh * 512 + t) * 128 + v] = p;
    }
  }

  float* base = state_out + (size_t)bh * 128 * 128 + v;
#define WOUT(n) { base[(kq * 32 + n * 4 + 0) * 128] = s##n[0]; \
                  base[(kq * 32 + n * 4 + 1) * 128] = s##n[1]; \
                  base[(kq * 32 + n * 4 + 2) * 128] = s##n[2]; \
                  base[(kq * 32 + n * 4 + 3) * 128] = s##n[3]; }
  R8(WOUT)
#undef WOUT
}

// ---------------- rmsnorm + gate silu -> bf16 A for final GEMM ----------------
__global__ __launch_bounds__(128) void post_kernel(const float* __restrict__ o_s,
                                                   const float* __restrict__ qkvg,
                                                   const float* __restrict__ norm_w,
                                                   __hip_bfloat16* __restrict__ Afin) {
  int bt = blockIdx.x;
  int h = blockIdx.y;
  int d = threadIdx.x;
  int b = bt >> 9, t = bt & 511;
  int bh = b * 8 + h;
  float o = o_s[((size_t)bh * 512 + t) * 128 + d];
  __shared__ float red[2];
  float ss = o * o;
#pragma unroll
  for (int off = 32; off; off >>= 1) ss += __shfl_down(ss, off);
  if ((d & 63) == 0) red[d >> 6] = ss;
  __syncthreads();
  float mean = (red[0] + red[1]) * (1.f / 128.f);
  float r = rsqrtf(mean + 1e-5f);
  float gate = qkvg[(size_t)bt * NFUSE + 5120 + h * 128 + d];
  float val = o * r * norm_w[d] * silu_f(gate);
  Afin[(size_t)bt * 1024 + h * 128 + d] = __float2bfloat16(val);
}

extern "C" void kernel_launch(void* const* d_in, const int* in_sizes, int n_in,
                              void* d_out, int out_size, void* d_ws, size_t ws_size,
                              hipStream_t stream) {
  const float* x       = (const float*)d_in[0];
  const float* Wq      = (const float*)d_in[1];
  const float* Wk      = (const float*)d_in[2];
  const float* Wv      = (const float*)d_in[3];
  const float* Wb      = (const float*)d_in[4];
  const float* Wa      = (const float*)d_in[5];
  const float* A_log   = (const float*)d_in[6];
  const float* dt_bias = (const float*)d_in[7];
  const float* cqw     = (const float*)d_in[8];
  const float* ckw     = (const float*)d_in[9];
  const float* cvw     = (const float*)d_in[10];
  const float* Wg      = (const float*)d_in[11];
  const float* norm_w  = (const float*)d_in[12];
  const float* Wo      = (const float*)d_in[13];

  char* ws = (char*)d_ws;
  size_t off = 0;
  auto alloc = [&](size_t bytes) {
    void* p = ws + off;
    off += (bytes + 255) & ~(size_t)255;
    return p;
  };
  __hip_bfloat16* xbf  = (__hip_bfloat16*)alloc((size_t)2097152 * 2);
  __hip_bfloat16* WT   = (__hip_bfloat16*)alloc((size_t)NFUSE * 2048 * 2);  // fused q|k|v|g, [N][K]
  __hip_bfloat16* WoT  = (__hip_bfloat16*)alloc((size_t)2097152 * 2);
  float* qkvg   = (float*)alloc((size_t)ROWS * NFUSE * 4);
  float* xb     = (float*)alloc((size_t)16384 * 4);
  float* xa     = (float*)alloc((size_t)8192 * 4);
  float* q_s    = (float*)alloc((size_t)1048576 * 4);
  float* k_s    = (float*)alloc((size_t)2097152 * 4);
  float* v_s    = (float*)alloc((size_t)2097152 * 4);
  float* beta_s = (float*)alloc((size_t)16384 * 4);
  float* ge_s   = (float*)alloc((size_t)8192 * 4);
  float* o_s    = (float*)alloc((size_t)1048576 * 4);
  __hip_bfloat16* Afin = (__hip_bfloat16*)alloc((size_t)1048576 * 2);

  float* out_main  = (float*)d_out;
  float* out_state = out_main + 2097152;

  dim3 tb(32, 8);
  f2bf_kernel<<<8192, 256, 0, stream>>>(x, xbf, 2097152);
  transpose_f2bf<<<dim3(32, 64), tb, 0, stream>>>(Wq, WT,                        2048, 1024);
  transpose_f2bf<<<dim3(64, 64), tb, 0, stream>>>(Wk, WT + (size_t)1024 * 2048,  2048, 2048);
  transpose_f2bf<<<dim3(64, 64), tb, 0, stream>>>(Wv, WT + (size_t)3072 * 2048,  2048, 2048);
  transpose_f2bf<<<dim3(32, 64), tb, 0, stream>>>(Wg, WT + (size_t)5120 * 2048,  2048, 1024);
  transpose_f2bf<<<dim3(64, 32), tb, 0, stream>>>(Wo, WoT, 1024, 2048);

  gemm_bf16<<<dim3(48, 8), 256, 0, stream>>>(xbf, WT, qkvg, 1024, NFUSE, 2048);
  small_gemm_ba<<<dim3(1024, 24), 64, 0, stream>>>(x, Wb, Wa, xb, xa);

  conv_q_kernel<<<dim3(1024, 8),  128, 0, stream>>>(qkvg, cqw, q_s);
  conv_k_kernel<<<dim3(1024, 16), 128, 0, stream>>>(qkvg, ckw, k_s);
  conv_v_kernel<<<dim3(1024, 16), 128, 0, stream>>>(qkvg, cvw, v_s);
  bg_kernel<<<1024, 32, 0, stream>>>(xb, xa, A_log, dt_bias, beta_s, ge_s);

  scan_kernel<<<128, 64, 0, stream>>>(q_s, k_s, v_s, beta_s, ge_s, o_s, out_state);

  post_kernel<<<dim3(1024, 8), 128, 0, stream>>>(o_s, qkvg, norm_w, Afin);
  gemm_bf16<<<dim3(16, 8), 256, 0, stream>>>(Afin, WoT, out_main, 1024, 2048, 1024);
}

// Round 7
// 361.572 us; speedup vs baseline: 13.1723x; 1.3645x over previous
//
#include <hip/hip_runtime.h>
#include <hip/hip_bf16.h>
#include <cmath>

#define B_   2
#define L_   512
#define HID  2048
#define DH   128
#define NH   8
#define NHH  2
#define ROWS 1024  // B_*L_
#define NFUSE 6144 // 1024(q)+2048(k)+2048(v)+1024(g)

typedef float  f32x2  __attribute__((ext_vector_type(2)));
typedef float  f32x4  __attribute__((ext_vector_type(4)));
typedef __bf16 bf16x8 __attribute__((ext_vector_type(8)));

#define AS1(p) ((const __attribute__((address_space(1))) unsigned int*)(p))
#define AS3(p) ((__attribute__((address_space(3))) unsigned int*)(p))

__device__ __forceinline__ float dpp_xor1(float x) {
  int r = __builtin_amdgcn_update_dpp(0, __float_as_int(x), 0xB1, 0xF, 0xF, true);
  return __int_as_float(r);
}
__device__ __forceinline__ float dpp_xor2(float x) {
  int r = __builtin_amdgcn_update_dpp(0, __float_as_int(x), 0x4E, 0xF, 0xF, true);
  return __int_as_float(r);
}
__device__ __forceinline__ float dpp_hmirror(float x) {  // lane l <- l^7 within each 8
  int r = __builtin_amdgcn_update_dpp(0, __float_as_int(x), 0x141, 0xF, 0xF, true);
  return __int_as_float(r);
}

// ---------------- f32 -> bf16 elementwise ----------------
__global__ void f2bf_kernel(const float* __restrict__ in, __hip_bfloat16* __restrict__ out, int n) {
  int i = blockIdx.x * 256 + threadIdx.x;
  if (i < n) out[i] = __float2bfloat16(in[i]);
}

// ---------------- f32 (K x N) -> bf16 transposed (N x K) ----------------
__global__ __launch_bounds__(256) void transpose_f2bf(const float* __restrict__ in,
                                                      __hip_bfloat16* __restrict__ out,
                                                      int K, int N) {
  __shared__ float tile[32][33];
  int n0 = blockIdx.x * 32, k0 = blockIdx.y * 32;
  int tx = threadIdx.x, ty = threadIdx.y;  // 32 x 8
#pragma unroll
  for (int i = 0; i < 32; i += 8)
    tile[ty + i][tx] = in[(size_t)(k0 + ty + i) * N + n0 + tx];
  __syncthreads();
#pragma unroll
  for (int i = 0; i < 32; i += 8)
    out[(size_t)(n0 + ty + i) * K + k0 + tx] = __float2bfloat16(tile[tx][ty + i]);
}

// ---------------- bf16 MFMA GEMM: C(MxN) = A(MxK) * BT(NxK)^T ----------------
__global__ __launch_bounds__(256) void gemm_bf16(const __hip_bfloat16* __restrict__ A,
                                                 const __hip_bfloat16* __restrict__ BT,
                                                 float* __restrict__ C, int M, int N, int K) {
  __shared__ __align__(16) __hip_bfloat16 lA[128 * 32];
  __shared__ __align__(16) __hip_bfloat16 lB[128 * 32];
  const int tid = threadIdx.x;
  const int lane = tid & 63;
  const int w = tid >> 6;
  const int wr = w >> 1, wc = w & 1;
  const int row0 = blockIdx.y * 128;
  const int col0 = blockIdx.x * 128;
  f32x4 acc[4][4];
#pragma unroll
  for (int m = 0; m < 4; ++m)
#pragma unroll
    for (int n = 0; n < 4; ++n) acc[m][n] = {0.f, 0.f, 0.f, 0.f};
  const int fr = lane & 15;
  const int ko = (lane >> 4) * 8;
  for (int kt = 0; kt < K; kt += 32) {
#pragma unroll
    for (int i = 0; i < 2; ++i) {
      int elem = (w * 2 + i) * 512 + lane * 8;
      int rr = elem >> 5, cc = elem & 31;
      const __hip_bfloat16* srcA = A + (size_t)(row0 + rr) * K + kt + cc;
      __builtin_amdgcn_global_load_lds(AS1(srcA), AS3(&lA[(w * 2 + i) * 512]), 16, 0, 0);
      const __hip_bfloat16* srcB = BT + (size_t)(col0 + rr) * K + kt + cc;
      __builtin_amdgcn_global_load_lds(AS1(srcB), AS3(&lB[(w * 2 + i) * 512]), 16, 0, 0);
    }
    __syncthreads();
    bf16x8 af[4], bfr[4];
#pragma unroll
    for (int m = 0; m < 4; ++m)
      af[m] = *reinterpret_cast<const bf16x8*>(&lA[(wr * 64 + m * 16 + fr) * 32 + ko]);
#pragma unroll
    for (int n = 0; n < 4; ++n)
      bfr[n] = *reinterpret_cast<const bf16x8*>(&lB[(wc * 64 + n * 16 + fr) * 32 + ko]);
#pragma unroll
    for (int m = 0; m < 4; ++m)
#pragma unroll
      for (int n = 0; n < 4; ++n)
        acc[m][n] = __builtin_amdgcn_mfma_f32_16x16x32_bf16(af[m], bfr[n], acc[m][n], 0, 0, 0);
    __syncthreads();
  }
  const int rq = (lane >> 4) * 4;
#pragma unroll
  for (int m = 0; m < 4; ++m)
#pragma unroll
    for (int n = 0; n < 4; ++n)
#pragma unroll
      for (int r = 0; r < 4; ++r)
        C[(size_t)(row0 + wr * 64 + m * 16 + rq + r) * N + (col0 + wc * 64 + n * 16 + fr)] =
            acc[m][n][r];
}

// ---------------- small GEMM for Wb (16 cols) and Wa (8 cols), f32 ----------------
__global__ void small_gemm_ba(const float* __restrict__ x, const float* __restrict__ Wb,
                              const float* __restrict__ Wa, float* __restrict__ xb,
                              float* __restrict__ xa) {
  int row = blockIdx.x;
  int col = blockIdx.y;
  int lane = threadIdx.x;
  float acc = 0.f;
  if (col < 16) {
    for (int k = lane; k < HID; k += 64) acc += x[(size_t)row * HID + k] * Wb[(size_t)k * 16 + col];
  } else {
    int c = col - 16;
    for (int k = lane; k < HID; k += 64) acc += x[(size_t)row * HID + k] * Wa[(size_t)k * 8 + c];
  }
#pragma unroll
  for (int off = 32; off; off >>= 1) acc += __shfl_down(acc, off);
  if (lane == 0) {
    if (col < 16) xb[(size_t)row * 16 + col] = acc;
    else          xa[(size_t)row * 8 + (col - 16)] = acc;
  }
}

__device__ __forceinline__ float silu_f(float y) { return y / (1.f + __expf(-y)); }

// ---------------- fused conv + silu (+l2norm for q/k) for q,k,v ----------------
// blockIdx.y: 0..7 = q head; 8..23 = k (j,h); 24..39 = v (j,h)
__global__ __launch_bounds__(128) void conv_qkv_kernel(const float* __restrict__ qkvg,
                                                       const float* __restrict__ wq,
                                                       const float* __restrict__ wk,
                                                       const float* __restrict__ wv,
                                                       float* __restrict__ q_s,
                                                       float* __restrict__ k_s,
                                                       float* __restrict__ v_s) {
  int bt = blockIdx.x;
  int yy = blockIdx.y;
  int d  = threadIdx.x;
  int b = bt >> 9, t = bt & 511;
  __shared__ float red[2];
  if (yy < 8) {
    int h = yy, c = h * 128 + d;
    float y = 0.f;
#pragma unroll
    for (int tau = 0; tau < 4; ++tau) {
      int tt = t - 3 + tau;
      float xv = (tt >= 0) ? qkvg[(size_t)(b * 512 + tt) * NFUSE + c] : 0.f;
      y += xv * wq[c * 4 + tau];
    }
    y = silu_f(y);
    float ss = y * y;
#pragma unroll
    for (int off = 32; off; off >>= 1) ss += __shfl_down(ss, off);
    if ((d & 63) == 0) red[d >> 6] = ss;
    __syncthreads();
    float scale = (1.f / fmaxf(sqrtf(red[0] + red[1]), 1e-12f)) * 0.08838834764831845f;
    q_s[((size_t)(b * 8 + h) * 512 + t) * 128 + d] = y * scale;
  } else if (yy < 24) {
    int jh = yy - 8;
    int j = jh >> 3, h = jh & 7;
    int c = j * 1024 + h * 128 + d;
    float y = 0.f;
#pragma unroll
    for (int tau = 0; tau < 4; ++tau) {
      int tt = t - 3 + tau;
      float xv = (tt >= 0) ? qkvg[(size_t)(b * 512 + tt) * NFUSE + 1024 + c] : 0.f;
      y += xv * wk[c * 4 + tau];
    }
    y = silu_f(y);
    float ss = y * y;
#pragma unroll
    for (int off = 32; off; off >>= 1) ss += __shfl_down(ss, off);
    if ((d & 63) == 0) red[d >> 6] = ss;
    __syncthreads();
    float scale = 1.f / fmaxf(sqrtf(red[0] + red[1]), 1e-12f);
    k_s[(((size_t)(b * 8 + h) * 2 + j) * 512 + t) * 128 + d] = y * scale;
  } else {
    int jh = yy - 24;
    int j = jh >> 3, h = jh & 7;
    int c = j * 1024 + h * 128 + d;
    float y = 0.f;
#pragma unroll
    for (int tau = 0; tau < 4; ++tau) {
      int tt = t - 3 + tau;
      float xv = (tt >= 0) ? qkvg[(size_t)(b * 512 + tt) * NFUSE + 3072 + c] : 0.f;
      y += xv * wv[c * 4 + tau];
    }
    v_s[(((size_t)(b * 8 + h) * 2 + j) * 512 + t) * 128 + d] = silu_f(y);
  }
}

// ---------------- beta / exp(g) ----------------
__global__ void bg_kernel(const float* __restrict__ xb, const float* __restrict__ xa,
                          const float* __restrict__ A_log, const float* __restrict__ dt_bias,
                          float* __restrict__ beta_s, float* __restrict__ ge_s) {
  int bt = blockIdx.x;
  int i = threadIdx.x;
  int b = bt >> 9, t = bt & 511;
  if (i < 16) {
    int j = i >> 3, h = i & 7;
    float v = xb[(size_t)bt * 16 + i];
    float bv = 2.f / (1.f + __expf(-v));
    beta_s[(((size_t)(b * 8 + h)) * 2 + j) * 512 + t] = bv;
  } else if (i < 24) {
    int h = i - 16;
    float v = xa[(size_t)bt * 8 + h] + dt_bias[h];
    float sp = (v > 20.f) ? v : log1pf(__expf(v));
    float g = -__expf(A_log[h]) * sp;
    ge_s[((size_t)(b * 8 + h)) * 512 + t] = __expf(g);
  }
}

// ---------------- sequential gated delta-product scan, LDS-staged, full-chip ------
// 256 blocks x 64 thr (ONE wave, no barriers) = 16 chains x 16 v-groups (8 cols).
// lane = vi*8 + kq: kq 0..7 owns state rows [kq*16,kq*16+16) of col v=wg*8+vi
// (4 named f32x4). 8-way k-reduce is all-DPP: quad xor1 + quad xor2 +
// row_half_mirror (adds lane^7's quad-sum) — no DS ops, no barriers.
// Staged per 16-step tile in LDS: k0/k1/q in 20-float-padded 16-chunks
// (8 kq addrs -> disjoint bank quads {0,20,8,28,16,4,24,12} mod 32), v0/v1
// tiles, and beta/g arrays preloaded whole -> per-step hot path has ZERO
// global loads (round-6 residual: v/beta/g globals + half the chip idle).
#define R4(X) X(0) X(1) X(2) X(3)
#define R8(X) X(0) X(1) X(2) X(3) X(4) X(5) X(6) X(7)
#define CH 20                        // padded chunk stride (16 data + 4)
#define STEPF (3 * 8 * CH)           // 480 floats per step row-group
#define TILEF (16 * STEPF)           // 7680 floats per buffer

__global__ __launch_bounds__(64, 1) void scan_kernel(const float* __restrict__ q_s,
                                                     const float* __restrict__ k_s,
                                                     const float* __restrict__ v_s,
                                                     const float* __restrict__ beta_s,
                                                     const float* __restrict__ ge_s,
                                                     float* __restrict__ o_s,
                                                     float* __restrict__ state_out) {
  const int blk = blockIdx.x;      // 0..255
  const int bh  = blk >> 4;        // chain 0..15
  const int wg  = blk & 15;        // v-group 0..15 (8 cols)
  const int lane = threadIdx.x;    // 0..63
  const int kq = lane & 7;         // k-eighth 0..7
  const int vi = lane >> 3;        // 0..7
  const int v  = wg * 8 + vi;      // global v column

  __shared__ __align__(16) float lds[2][TILEF];
  __shared__ __align__(16) float vbuf[2][2][16][8];
  __shared__ __align__(16) float lds_bg[3][512];

#define DECL(n) f32x4 s##n = {0.f, 0.f, 0.f, 0.f};
  R4(DECL)
#undef DECL
#define DECLG(j) f32x4 Gk0_##j, Gk1_##j, Gq_##j;
  R8(DECLG)
#undef DECLG
  f32x2 Gv0, Gv1;

  const float* g_k0 = k_s + ((size_t)bh * 2 + 0) * 512 * 128;
  const float* g_k1 = k_s + ((size_t)bh * 2 + 1) * 512 * 128;
  const float* g_q  = q_s + (size_t)bh * 512 * 128;
  const float* g_v0w = v_s + ((size_t)bh * 2 + 0) * 512 * 128 + wg * 8;
  const float* g_v1w = v_s + ((size_t)bh * 2 + 1) * 512 * 128 + wg * 8;
  const float* b0p = beta_s + ((size_t)bh * 2 + 0) * 512;
  const float* b1p = beta_s + ((size_t)bh * 2 + 1) * 512;
  const float* gp  = ge_s + (size_t)bh * 512;

  // preload beta/g wholesale (read-before-first-use, same wave -> ordered)
#pragma unroll
  for (int i = 0; i < 2; ++i) {
    int c4 = lane + i * 64;
    *(f32x4*)&lds_bg[0][c4 * 4] = *(const f32x4*)(gp  + c4 * 4);
    *(f32x4*)&lds_bg[1][c4 * 4] = *(const f32x4*)(b0p + c4 * 4);
    *(f32x4*)&lds_bg[2][c4 * 4] = *(const f32x4*)(b1p + c4 * 4);
  }

#define LD1(j) { Gk0_##j = p0[lane + j * 64]; Gk1_##j = p1[lane + j * 64]; Gq_##j = pq[lane + j * 64]; }
#define LOAD_G(T) { const f32x4* __restrict__ p0 = (const f32x4*)(g_k0 + (size_t)(T) * 2048); \
                    const f32x4* __restrict__ p1 = (const f32x4*)(g_k1 + (size_t)(T) * 2048); \
                    const f32x4* __restrict__ pq = (const f32x4*)(g_q  + (size_t)(T) * 2048); \
                    R8(LD1) }
#define LOAD_V(T) { Gv0 = *(const f32x2*)(g_v0w + (size_t)(T) * 2048 + (lane >> 2) * 128 + (lane & 3) * 2); \
                    Gv1 = *(const f32x2*)(g_v1w + (size_t)(T) * 2048 + (lane >> 2) * 128 + (lane & 3) * 2); }
  // float idx = 4*lane + 256*j; t_loc = idx>>7; r = idx&127; chunk = r>>4; c = r&15
#define WR1(j) { int idx = 4 * lane + 256 * j; int tl_ = idx >> 7; int r_ = idx & 127; \
                 int ck = r_ >> 4; int cc = r_ & 15; \
    *(f32x4*)&lds[bsel][(tl_ * 24 + 0 + ck) * CH + cc] = Gk0_##j; \
    *(f32x4*)&lds[bsel][(tl_ * 24 + 8 + ck) * CH + cc] = Gk1_##j; \
    *(f32x4*)&lds[bsel][(tl_ * 24 + 16 + ck) * CH + cc] = Gq_##j; }
#define WRITE_G(b) { const int bsel = (b); R8(WR1) }
#define WRITE_V(b) { *(f32x2*)&vbuf[b][0][lane >> 2][(lane & 3) * 2] = Gv0; \
                     *(f32x2*)&vbuf[b][1][lane >> 2][(lane & 3) * 2] = Gv1; }

  LOAD_G(0) LOAD_V(0)
  WRITE_G(0) WRITE_V(0)
  LOAD_G(1) LOAD_V(1)

  for (int T = 0; T < 32; ++T) {
    const int buf = T & 1;
    if (T < 31) { WRITE_G(buf ^ 1) WRITE_V(buf ^ 1) }
    if (T < 30) { LOAD_G(T + 2) LOAD_V(T + 2) }
#pragma unroll
    for (int tl = 0; tl < 16; ++tl) {
      const int t = T * 16 + tl;
      const float eg  = lds_bg[0][t];
      const float bb0 = lds_bg[1][t];
      const float bb1 = lds_bg[2][t];
      const float mv0 = vbuf[buf][0][tl][vi];
      const float mv1 = vbuf[buf][1][tl][vi];
      const f32x4* __restrict__ pk0 = (const f32x4*)&lds[buf][(tl * 24 + 0 + kq) * CH];
      const f32x4* __restrict__ pk1 = (const f32x4*)&lds[buf][(tl * 24 + 8 + kq) * CH];
      const f32x4* __restrict__ pq  = (const f32x4*)&lds[buf][(tl * 24 + 16 + kq) * CH];
#define LDS_LD(n) f32x4 a##n = pk0[n]; f32x4 b##n = pk1[n]; f32x4 c##n = pq[n];
      R4(LDS_LD)
#undef LDS_LD
      f32x4 acc = {0.f, 0.f, 0.f, 0.f};
#define P1(n) { s##n *= eg; acc += a##n * s##n; }
      R4(P1)
#undef P1
      float p = (acc[0] + acc[1]) + (acc[2] + acc[3]);
      p += dpp_xor1(p); p += dpp_xor2(p); p += dpp_hmirror(p);
      const float u0 = (mv0 - p) * bb0;
      acc = (f32x4){0.f, 0.f, 0.f, 0.f};
#define P2(n) { s##n += a##n * u0; acc += b##n * s##n; }
      R4(P2)
#undef P2
      p = (acc[0] + acc[1]) + (acc[2] + acc[3]);
      p += dpp_xor1(p); p += dpp_xor2(p); p += dpp_hmirror(p);
      const float u1 = (mv1 - p) * bb1;
      acc = (f32x4){0.f, 0.f, 0.f, 0.f};
#define P3(n) { s##n += b##n * u1; acc += c##n * s##n; }
      R4(P3)
#undef P3
      p = (acc[0] + acc[1]) + (acc[2] + acc[3]);
      p += dpp_xor1(p); p += dpp_xor2(p); p += dpp_hmirror(p);
      if (kq == 0) o_s[((size_t)bh * 512 + t) * 128 + v] = p;
    }
  }

  float* base = state_out + (size_t)bh * 128 * 128 + v;
#define WOUT(n) { base[(kq * 16 + n * 4 + 0) * 128] = s##n[0]; \
                  base[(kq * 16 + n * 4 + 1) * 128] = s##n[1]; \
                  base[(kq * 16 + n * 4 + 2) * 128] = s##n[2]; \
                  base[(kq * 16 + n * 4 + 3) * 128] = s##n[3]; }
  R4(WOUT)
#undef WOUT
}

// ---------------- rmsnorm + gate silu -> bf16 A for final GEMM ----------------
__global__ __launch_bounds__(128) void post_kernel(const float* __restrict__ o_s,
                                                   const float* __restrict__ qkvg,
                                                   const float* __restrict__ norm_w,
                                                   __hip_bfloat16* __restrict__ Afin) {
  int bt = blockIdx.x;
  int h = blockIdx.y;
  int d = threadIdx.x;
  int b = bt >> 9, t = bt & 511;
  int bh = b * 8 + h;
  float o = o_s[((size_t)bh * 512 + t) * 128 + d];
  __shared__ float red[2];
  float ss = o * o;
#pragma unroll
  for (int off = 32; off; off >>= 1) ss += __shfl_down(ss, off);
  if ((d & 63) == 0) red[d >> 6] = ss;
  __syncthreads();
  float mean = (red[0] + red[1]) * (1.f / 128.f);
  float r = rsqrtf(mean + 1e-5f);
  float gate = qkvg[(size_t)bt * NFUSE + 5120 + h * 128 + d];
  float val = o * r * norm_w[d] * silu_f(gate);
  Afin[(size_t)bt * 1024 + h * 128 + d] = __float2bfloat16(val);
}

extern "C" void kernel_launch(void* const* d_in, const int* in_sizes, int n_in,
                              void* d_out, int out_size, void* d_ws, size_t ws_size,
                              hipStream_t stream) {
  const float* x       = (const float*)d_in[0];
  const float* Wq      = (const float*)d_in[1];
  const float* Wk      = (const float*)d_in[2];
  const float* Wv      = (const float*)d_in[3];
  const float* Wb      = (const float*)d_in[4];
  const float* Wa      = (const float*)d_in[5];
  const float* A_log   = (const float*)d_in[6];
  const float* dt_bias = (const float*)d_in[7];
  const float* cqw     = (const float*)d_in[8];
  const float* ckw     = (const float*)d_in[9];
  const float* cvw     = (const float*)d_in[10];
  const float* Wg      = (const float*)d_in[11];
  const float* norm_w  = (const float*)d_in[12];
  const float* Wo      = (const float*)d_in[13];

  char* ws = (char*)d_ws;
  size_t off = 0;
  auto alloc = [&](size_t bytes) {
    void* p = ws + off;
    off += (bytes + 255) & ~(size_t)255;
    return p;
  };
  __hip_bfloat16* xbf  = (__hip_bfloat16*)alloc((size_t)2097152 * 2);
  __hip_bfloat16* WT   = (__hip_bfloat16*)alloc((size_t)NFUSE * 2048 * 2);  // fused q|k|v|g, [N][K]
  __hip_bfloat16* WoT  = (__hip_bfloat16*)alloc((size_t)2097152 * 2);
  float* qkvg   = (float*)alloc((size_t)ROWS * NFUSE * 4);
  float* xb     = (float*)alloc((size_t)16384 * 4);
  float* xa     = (float*)alloc((size_t)8192 * 4);
  float* q_s    = (float*)alloc((size_t)1048576 * 4);
  float* k_s    = (float*)alloc((size_t)2097152 * 4);
  float* v_s    = (float*)alloc((size_t)2097152 * 4);
  float* beta_s = (float*)alloc((size_t)16384 * 4);
  float* ge_s   = (float*)alloc((size_t)8192 * 4);
  float* o_s    = (float*)alloc((size_t)1048576 * 4);
  __hip_bfloat16* Afin = (__hip_bfloat16*)alloc((size_t)1048576 * 2);

  float* out_main  = (float*)d_out;
  float* out_state = out_main + 2097152;

  dim3 tb(32, 8);
  f2bf_kernel<<<8192, 256, 0, stream>>>(x, xbf, 2097152);
  transpose_f2bf<<<dim3(32, 64), tb, 0, stream>>>(Wq, WT,                        2048, 1024);
  transpose_f2bf<<<dim3(64, 64), tb, 0, stream>>>(Wk, WT + (size_t)1024 * 2048,  2048, 2048);
  transpose_f2bf<<<dim3(64, 64), tb, 0, stream>>>(Wv, WT + (size_t)3072 * 2048,  2048, 2048);
  transpose_f2bf<<<dim3(32, 64), tb, 0, stream>>>(Wg, WT + (size_t)5120 * 2048,  2048, 1024);
  transpose_f2bf<<<dim3(64, 32), tb, 0, stream>>>(Wo, WoT, 1024, 2048);

  gemm_bf16<<<dim3(48, 8), 256, 0, stream>>>(xbf, WT, qkvg, 1024, NFUSE, 2048);
  small_gemm_ba<<<dim3(1024, 24), 64, 0, stream>>>(x, Wb, Wa, xb, xa);

  conv_qkv_kernel<<<dim3(1024, 40), 128, 0, stream>>>(qkvg, cqw, ckw, cvw, q_s, k_s, v_s);
  bg_kernel<<<1024, 32, 0, stream>>>(xb, xa, A_log, dt_bias, beta_s, ge_s);

  scan_kernel<<<256, 64, 0, stream>>>(q_s, k_s, v_s, beta_s, ge_s, o_s, out_state);

  post_kernel<<<dim3(1024, 8), 128, 0, stream>>>(o_s, qkvg, norm_w, Afin);
  gemm_bf16<<<dim3(16, 8), 256, 0, stream>>>(Afin, WoT, out_main, 1024, 2048, 1024);
}

// Round 8
// 353.010 us; speedup vs baseline: 13.4918x; 1.0243x over previous
//
#include <hip/hip_runtime.h>
#include <hip/hip_bf16.h>
#include <cmath>

#define B_   2
#define L_   512
#define HID  2048
#define DH   128
#define NH   8
#define NHH  2
#define ROWS 1024  // B_*L_
#define NFUSE 6144 // 1024(q)+2048(k)+2048(v)+1024(g)

typedef float  f32x2  __attribute__((ext_vector_type(2)));
typedef float  f32x4  __attribute__((ext_vector_type(4)));
typedef __bf16 bf16x8 __attribute__((ext_vector_type(8)));

#define AS1(p) ((const __attribute__((address_space(1))) unsigned int*)(p))
#define AS3(p) ((__attribute__((address_space(3))) unsigned int*)(p))

__device__ __forceinline__ float dpp_xor1(float x) {
  int r = __builtin_amdgcn_update_dpp(0, __float_as_int(x), 0xB1, 0xF, 0xF, true);
  return __int_as_float(r);
}
__device__ __forceinline__ float dpp_xor2(float x) {
  int r = __builtin_amdgcn_update_dpp(0, __float_as_int(x), 0x4E, 0xF, 0xF, true);
  return __int_as_float(r);
}
__device__ __forceinline__ float dpp_hmirror(float x) {  // mirror within 8
  int r = __builtin_amdgcn_update_dpp(0, __float_as_int(x), 0x141, 0xF, 0xF, true);
  return __int_as_float(r);
}
__device__ __forceinline__ float dpp_rmirror(float x) {  // mirror within 16
  int r = __builtin_amdgcn_update_dpp(0, __float_as_int(x), 0x140, 0xF, 0xF, true);
  return __int_as_float(r);
}

// ---------------- f32 -> bf16 elementwise ----------------
__global__ void f2bf_kernel(const float* __restrict__ in, __hip_bfloat16* __restrict__ out, int n) {
  int i = blockIdx.x * 256 + threadIdx.x;
  if (i < n) out[i] = __float2bfloat16(in[i]);
}

// ---------------- f32 (K x N) -> bf16 transposed (N x K) ----------------
__global__ __launch_bounds__(256) void transpose_f2bf(const float* __restrict__ in,
                                                      __hip_bfloat16* __restrict__ out,
                                                      int K, int N) {
  __shared__ float tile[32][33];
  int n0 = blockIdx.x * 32, k0 = blockIdx.y * 32;
  int tx = threadIdx.x, ty = threadIdx.y;  // 32 x 8
#pragma unroll
  for (int i = 0; i < 32; i += 8)
    tile[ty + i][tx] = in[(size_t)(k0 + ty + i) * N + n0 + tx];
  __syncthreads();
#pragma unroll
  for (int i = 0; i < 32; i += 8)
    out[(size_t)(n0 + ty + i) * K + k0 + tx] = __float2bfloat16(tile[tx][ty + i]);
}

// ---------------- bf16 MFMA GEMM: C(MxN) = A(MxK) * BT(NxK)^T ----------------
__global__ __launch_bounds__(256) void gemm_bf16(const __hip_bfloat16* __restrict__ A,
                                                 const __hip_bfloat16* __restrict__ BT,
                                                 float* __restrict__ C, int M, int N, int K) {
  __shared__ __align__(16) __hip_bfloat16 lA[128 * 32];
  __shared__ __align__(16) __hip_bfloat16 lB[128 * 32];
  const int tid = threadIdx.x;
  const int lane = tid & 63;
  const int w = tid >> 6;
  const int wr = w >> 1, wc = w & 1;
  const int row0 = blockIdx.y * 128;
  const int col0 = blockIdx.x * 128;
  f32x4 acc[4][4];
#pragma unroll
  for (int m = 0; m < 4; ++m)
#pragma unroll
    for (int n = 0; n < 4; ++n) acc[m][n] = {0.f, 0.f, 0.f, 0.f};
  const int fr = lane & 15;
  const int ko = (lane >> 4) * 8;
  for (int kt = 0; kt < K; kt += 32) {
#pragma unroll
    for (int i = 0; i < 2; ++i) {
      int elem = (w * 2 + i) * 512 + lane * 8;
      int rr = elem >> 5, cc = elem & 31;
      const __hip_bfloat16* srcA = A + (size_t)(row0 + rr) * K + kt + cc;
      __builtin_amdgcn_global_load_lds(AS1(srcA), AS3(&lA[(w * 2 + i) * 512]), 16, 0, 0);
      const __hip_bfloat16* srcB = BT + (size_t)(col0 + rr) * K + kt + cc;
      __builtin_amdgcn_global_load_lds(AS1(srcB), AS3(&lB[(w * 2 + i) * 512]), 16, 0, 0);
    }
    __syncthreads();
    bf16x8 af[4], bfr[4];
#pragma unroll
    for (int m = 0; m < 4; ++m)
      af[m] = *reinterpret_cast<const bf16x8*>(&lA[(wr * 64 + m * 16 + fr) * 32 + ko]);
#pragma unroll
    for (int n = 0; n < 4; ++n)
      bfr[n] = *reinterpret_cast<const bf16x8*>(&lB[(wc * 64 + n * 16 + fr) * 32 + ko]);
#pragma unroll
    for (int m = 0; m < 4; ++m)
#pragma unroll
      for (int n = 0; n < 4; ++n)
        acc[m][n] = __builtin_amdgcn_mfma_f32_16x16x32_bf16(af[m], bfr[n], acc[m][n], 0, 0, 0);
    __syncthreads();
  }
  const int rq = (lane >> 4) * 4;
#pragma unroll
  for (int m = 0; m < 4; ++m)
#pragma unroll
    for (int n = 0; n < 4; ++n)
#pragma unroll
      for (int r = 0; r < 4; ++r)
        C[(size_t)(row0 + wr * 64 + m * 16 + rq + r) * N + (col0 + wc * 64 + n * 16 + fr)] =
            acc[m][n][r];
}

// ---------------- small GEMM for Wb (16 cols) and Wa (8 cols), f32 ----------------
__global__ void small_gemm_ba(const float* __restrict__ x, const float* __restrict__ Wb,
                              const float* __restrict__ Wa, float* __restrict__ xb,
                              float* __restrict__ xa) {
  int row = blockIdx.x;
  int col = blockIdx.y;
  int lane = threadIdx.x;
  float acc = 0.f;
  if (col < 16) {
    for (int k = lane; k < HID; k += 64) acc += x[(size_t)row * HID + k] * Wb[(size_t)k * 16 + col];
  } else {
    int c = col - 16;
    for (int k = lane; k < HID; k += 64) acc += x[(size_t)row * HID + k] * Wa[(size_t)k * 8 + c];
  }
#pragma unroll
  for (int off = 32; off; off >>= 1) acc += __shfl_down(acc, off);
  if (lane == 0) {
    if (col < 16) xb[(size_t)row * 16 + col] = acc;
    else          xa[(size_t)row * 8 + (col - 16)] = acc;
  }
}

__device__ __forceinline__ float silu_f(float y) { return y / (1.f + __expf(-y)); }

// ---------------- fused conv + silu (+l2norm for q/k) for q,k,v ----------------
__global__ __launch_bounds__(128) void conv_qkv_kernel(const float* __restrict__ qkvg,
                                                       const float* __restrict__ wq,
                                                       const float* __restrict__ wk,
                                                       const float* __restrict__ wv,
                                                       float* __restrict__ q_s,
                                                       float* __restrict__ k_s,
                                                       float* __restrict__ v_s) {
  int bt = blockIdx.x;
  int yy = blockIdx.y;
  int d  = threadIdx.x;
  int b = bt >> 9, t = bt & 511;
  __shared__ float red[2];
  if (yy < 8) {
    int h = yy, c = h * 128 + d;
    float y = 0.f;
#pragma unroll
    for (int tau = 0; tau < 4; ++tau) {
      int tt = t - 3 + tau;
      float xv = (tt >= 0) ? qkvg[(size_t)(b * 512 + tt) * NFUSE + c] : 0.f;
      y += xv * wq[c * 4 + tau];
    }
    y = silu_f(y);
    float ss = y * y;
#pragma unroll
    for (int off = 32; off; off >>= 1) ss += __shfl_down(ss, off);
    if ((d & 63) == 0) red[d >> 6] = ss;
    __syncthreads();
    float scale = (1.f / fmaxf(sqrtf(red[0] + red[1]), 1e-12f)) * 0.08838834764831845f;
    q_s[((size_t)(b * 8 + h) * 512 + t) * 128 + d] = y * scale;
  } else if (yy < 24) {
    int jh = yy - 8;
    int j = jh >> 3, h = jh & 7;
    int c = j * 1024 + h * 128 + d;
    float y = 0.f;
#pragma unroll
    for (int tau = 0; tau < 4; ++tau) {
      int tt = t - 3 + tau;
      float xv = (tt >= 0) ? qkvg[(size_t)(b * 512 + tt) * NFUSE + 1024 + c] : 0.f;
      y += xv * wk[c * 4 + tau];
    }
    y = silu_f(y);
    float ss = y * y;
#pragma unroll
    for (int off = 32; off; off >>= 1) ss += __shfl_down(ss, off);
    if ((d & 63) == 0) red[d >> 6] = ss;
    __syncthreads();
    float scale = 1.f / fmaxf(sqrtf(red[0] + red[1]), 1e-12f);
    k_s[(((size_t)(b * 8 + h) * 2 + j) * 512 + t) * 128 + d] = y * scale;
  } else {
    int jh = yy - 24;
    int j = jh >> 3, h = jh & 7;
    int c = j * 1024 + h * 128 + d;
    float y = 0.f;
#pragma unroll
    for (int tau = 0; tau < 4; ++tau) {
      int tt = t - 3 + tau;
      float xv = (tt >= 0) ? qkvg[(size_t)(b * 512 + tt) * NFUSE + 3072 + c] : 0.f;
      y += xv * wv[c * 4 + tau];
    }
    v_s[(((size_t)(b * 8 + h) * 2 + j) * 512 + t) * 128 + d] = silu_f(y);
  }
}

// ---------------- beta / exp(g) ----------------
__global__ void bg_kernel(const float* __restrict__ xb, const float* __restrict__ xa,
                          const float* __restrict__ A_log, const float* __restrict__ dt_bias,
                          float* __restrict__ beta_s, float* __restrict__ ge_s) {
  int bt = blockIdx.x;
  int i = threadIdx.x;
  int b = bt >> 9, t = bt & 511;
  if (i < 16) {
    int j = i >> 3, h = i & 7;
    float v = xb[(size_t)bt * 16 + i];
    float bv = 2.f / (1.f + __expf(-v));
    beta_s[(((size_t)(b * 8 + h)) * 2 + j) * 512 + t] = bv;
  } else if (i < 24) {
    int h = i - 16;
    float v = xa[(size_t)bt * 8 + h] + dt_bias[h];
    float sp = (v > 20.f) ? v : log1pf(__expf(v));
    float g = -__expf(A_log[h]) * sp;
    ge_s[((size_t)(b * 8 + h)) * 512 + t] = __expf(g);
  }
}

// ---------------- sequential gated delta-product scan: 512 waves, 16-way k-split ----
// 512 blocks x 64 thr (ONE wave, no barriers) = 16 chains x 32 v-groups (4 cols).
// lane = vi*16 + kr: kr 0..15 owns state rows [kr*8,kr*8+8) of col v=wg*4+vi
// (2 named f32x4). 16-way k-reduce all-DPP: xor1 + xor2 + half_mirror +
// row_mirror. 8-step LDS tile (CH=12 floats keeps ds_read_b128 16B-aligned;
// banks 12*kr mod 32 -> worst 2-way aliasing = free). beta/g preloaded whole.
// Round-7 lesson: per-step critical path is width-independent (~470cyc of
// dep-chain), so halve per-wave issue work and double SIMD coverage.
#define R4(X) X(0) X(1) X(2) X(3)
#define CH 12                        // padded chunk stride (8 data + 4)
#define TSTEP 8
#define STEPF (3 * 16 * CH)          // 576 floats per step
#define TILEF (TSTEP * STEPF)        // 4608 floats per buffer

__global__ __launch_bounds__(64, 1) void scan_kernel(const float* __restrict__ q_s,
                                                     const float* __restrict__ k_s,
                                                     const float* __restrict__ v_s,
                                                     const float* __restrict__ beta_s,
                                                     const float* __restrict__ ge_s,
                                                     float* __restrict__ o_s,
                                                     float* __restrict__ state_out) {
  const int blk = blockIdx.x;      // 0..511
  const int bh  = blk >> 5;        // chain 0..15
  const int wg  = blk & 31;        // v-group 0..31 (4 cols)
  const int lane = threadIdx.x;    // 0..63
  const int kr = lane & 15;        // k-sixteenth 0..15
  const int vi = lane >> 4;        // 0..3
  const int v  = wg * 4 + vi;      // global v column

  __shared__ __align__(16) float lds[2][TILEF];
  __shared__ __align__(16) float vbuf[2][2][TSTEP][4];
  __shared__ __align__(16) float lds_bg[3][512];

  f32x4 s0 = {0.f, 0.f, 0.f, 0.f}, s1 = {0.f, 0.f, 0.f, 0.f};
#define DECLG(j) f32x4 Gk0_##j, Gk1_##j, Gq_##j;
  R4(DECLG)
#undef DECLG
  float Gv;

  const float* g_k0 = k_s + ((size_t)bh * 2 + 0) * 512 * 128;
  const float* g_k1 = k_s + ((size_t)bh * 2 + 1) * 512 * 128;
  const float* g_q  = q_s + (size_t)bh * 512 * 128;
  const float* g_v0w = v_s + ((size_t)bh * 2 + 0) * 512 * 128 + wg * 4;
  const float* g_v1w = v_s + ((size_t)bh * 2 + 1) * 512 * 128 + wg * 4;
  const float* b0p = beta_s + ((size_t)bh * 2 + 0) * 512;
  const float* b1p = beta_s + ((size_t)bh * 2 + 1) * 512;
  const float* gp  = ge_s + (size_t)bh * 512;

  // preload beta/g wholesale (read-before-first-use within same wave)
#pragma unroll
  for (int i = 0; i < 2; ++i) {
    int c4 = lane + i * 64;
    *(f32x4*)&lds_bg[0][c4 * 4] = *(const f32x4*)(gp  + c4 * 4);
    *(f32x4*)&lds_bg[1][c4 * 4] = *(const f32x4*)(b0p + c4 * 4);
    *(f32x4*)&lds_bg[2][c4 * 4] = *(const f32x4*)(b1p + c4 * 4);
  }

  // V staging lane decomposition: lanes 0-31 -> v0, 32-63 -> v1
  const int vhalf = lane >> 5;
  const int vli = lane & 31;
  const int vtl = vli >> 2, vc = vli & 3;
  const float* vsrc = vhalf ? g_v1w : g_v0w;

#define LD1(j) { Gk0_##j = p0[lane + j * 64]; Gk1_##j = p1[lane + j * 64]; Gq_##j = pq[lane + j * 64]; }
#define LOAD_G(T) { const f32x4* __restrict__ p0 = (const f32x4*)(g_k0 + (size_t)(T) * 1024); \
                    const f32x4* __restrict__ p1 = (const f32x4*)(g_k1 + (size_t)(T) * 1024); \
                    const f32x4* __restrict__ pq = (const f32x4*)(g_q  + (size_t)(T) * 1024); \
                    R4(LD1) }
#define LOAD_V(T) { Gv = vsrc[(size_t)(T) * 1024 + vtl * 128 + vc]; }
  // granule g = lane + 64j over 256 f32x4 (1024 floats = 8 steps x 128):
  // tl = g>>5, kr_ = (g&31)>>1, c = 4*(g&1)
#define WR1(j) { int g_ = lane + 64 * j; int tl_ = g_ >> 5; int kr_ = (g_ & 31) >> 1; \
                 int c_ = 4 * (g_ & 1); \
    *(f32x4*)&lds[bsel][((tl_ * 3 + 0) * 16 + kr_) * CH + c_] = Gk0_##j; \
    *(f32x4*)&lds[bsel][((tl_ * 3 + 1) * 16 + kr_) * CH + c_] = Gk1_##j; \
    *(f32x4*)&lds[bsel][((tl_ * 3 + 2) * 16 + kr_) * CH + c_] = Gq_##j; }
#define WRITE_G(b) { const int bsel = (b); R4(WR1) }
#define WRITE_V(b) { vbuf[b][vhalf][vtl][vc] = Gv; }

  LOAD_G(0) LOAD_V(0)
  WRITE_G(0) WRITE_V(0)
  LOAD_G(1) LOAD_V(1)

  for (int T = 0; T < 64; ++T) {
    const int buf = T & 1;
    if (T < 63) { WRITE_G(buf ^ 1) WRITE_V(buf ^ 1) }
    if (T < 62) { LOAD_G(T + 2) LOAD_V(T + 2) }
#pragma unroll
    for (int tl = 0; tl < TSTEP; ++tl) {
      const int t = T * TSTEP + tl;
      const float eg  = lds_bg[0][t];
      const float bb0 = lds_bg[1][t];
      const float bb1 = lds_bg[2][t];
      const float mv0 = vbuf[buf][0][tl][vi];
      const float mv1 = vbuf[buf][1][tl][vi];
      const f32x4* __restrict__ pk0 = (const f32x4*)&lds[buf][((tl * 3 + 0) * 16 + kr) * CH];
      const f32x4* __restrict__ pk1 = (const f32x4*)&lds[buf][((tl * 3 + 1) * 16 + kr) * CH];
      const f32x4* __restrict__ pq  = (const f32x4*)&lds[buf][((tl * 3 + 2) * 16 + kr) * CH];
      f32x4 a0 = pk0[0], a1 = pk0[1];
      f32x4 b0 = pk1[0], b1 = pk1[1];
      f32x4 c0 = pq[0],  c1 = pq[1];
      // pass 1: decay + corr0
      s0 *= eg; s1 *= eg;
      f32x4 accA = a0 * s0;
      f32x4 accB = a1 * s1;
      f32x4 acc = accA + accB;
      float p = (acc[0] + acc[1]) + (acc[2] + acc[3]);
      p += dpp_xor1(p); p += dpp_xor2(p); p += dpp_hmirror(p); p += dpp_rmirror(p);
      const float u0 = (mv0 - p) * bb0;
      // pass 2: update j0 + corr1
      s0 += a0 * u0; s1 += a1 * u0;
      accA = b0 * s0; accB = b1 * s1;
      acc = accA + accB;
      p = (acc[0] + acc[1]) + (acc[2] + acc[3]);
      p += dpp_xor1(p); p += dpp_xor2(p); p += dpp_hmirror(p); p += dpp_rmirror(p);
      const float u1 = (mv1 - p) * bb1;
      // pass 3: update j1 + output
      s0 += b0 * u1; s1 += b1 * u1;
      accA = c0 * s0; accB = c1 * s1;
      acc = accA + accB;
      p = (acc[0] + acc[1]) + (acc[2] + acc[3]);
      p += dpp_xor1(p); p += dpp_xor2(p); p += dpp_hmirror(p); p += dpp_rmirror(p);
      if (kr == 0) o_s[((size_t)bh * 512 + t) * 128 + v] = p;
    }
  }

  float* base = state_out + (size_t)bh * 128 * 128 + v;
#pragma unroll
  for (int i = 0; i < 4; ++i) {
    base[(kr * 8 + i) * 128]     = s0[i];
    base[(kr * 8 + 4 + i) * 128] = s1[i];
  }
}

// ---------------- rmsnorm + gate silu -> bf16 A for final GEMM ----------------
__global__ __launch_bounds__(128) void post_kernel(const float* __restrict__ o_s,
                                                   const float* __restrict__ qkvg,
                                                   const float* __restrict__ norm_w,
                                                   __hip_bfloat16* __restrict__ Afin) {
  int bt = blockIdx.x;
  int h = blockIdx.y;
  int d = threadIdx.x;
  int b = bt >> 9, t = bt & 511;
  int bh = b * 8 + h;
  float o = o_s[((size_t)bh * 512 + t) * 128 + d];
  __shared__ float red[2];
  float ss = o * o;
#pragma unroll
  for (int off = 32; off; off >>= 1) ss += __shfl_down(ss, off);
  if ((d & 63) == 0) red[d >> 6] = ss;
  __syncthreads();
  float mean = (red[0] + red[1]) * (1.f / 128.f);
  float r = rsqrtf(mean + 1e-5f);
  float gate = qkvg[(size_t)bt * NFUSE + 5120 + h * 128 + d];
  float val = o * r * norm_w[d] * silu_f(gate);
  Afin[(size_t)bt * 1024 + h * 128 + d] = __float2bfloat16(val);
}

extern "C" void kernel_launch(void* const* d_in, const int* in_sizes, int n_in,
                              void* d_out, int out_size, void* d_ws, size_t ws_size,
                              hipStream_t stream) {
  const float* x       = (const float*)d_in[0];
  const float* Wq      = (const float*)d_in[1];
  const float* Wk      = (const float*)d_in[2];
  const float* Wv      = (const float*)d_in[3];
  const float* Wb      = (const float*)d_in[4];
  const float* Wa      = (const float*)d_in[5];
  const float* A_log   = (const float*)d_in[6];
  const float* dt_bias = (const float*)d_in[7];
  const float* cqw     = (const float*)d_in[8];
  const float* ckw     = (const float*)d_in[9];
  const float* cvw     = (const float*)d_in[10];
  const float* Wg      = (const float*)d_in[11];
  const float* norm_w  = (const float*)d_in[12];
  const float* Wo      = (const float*)d_in[13];

  char* ws = (char*)d_ws;
  size_t off = 0;
  auto alloc = [&](size_t bytes) {
    void* p = ws + off;
    off += (bytes + 255) & ~(size_t)255;
    return p;
  };
  __hip_bfloat16* xbf  = (__hip_bfloat16*)alloc((size_t)2097152 * 2);
  __hip_bfloat16* WT   = (__hip_bfloat16*)alloc((size_t)NFUSE * 2048 * 2);  // fused q|k|v|g, [N][K]
  __hip_bfloat16* WoT  = (__hip_bfloat16*)alloc((size_t)2097152 * 2);
  float* qkvg   = (float*)alloc((size_t)ROWS * NFUSE * 4);
  float* xb     = (float*)alloc((size_t)16384 * 4);
  float* xa     = (float*)alloc((size_t)8192 * 4);
  float* q_s    = (float*)alloc((size_t)1048576 * 4);
  float* k_s    = (float*)alloc((size_t)2097152 * 4);
  float* v_s    = (float*)alloc((size_t)2097152 * 4);
  float* beta_s = (float*)alloc((size_t)16384 * 4);
  float* ge_s   = (float*)alloc((size_t)8192 * 4);
  float* o_s    = (float*)alloc((size_t)1048576 * 4);
  __hip_bfloat16* Afin = (__hip_bfloat16*)alloc((size_t)1048576 * 2);

  float* out_main  = (float*)d_out;
  float* out_state = out_main + 2097152;

  dim3 tb(32, 8);
  f2bf_kernel<<<8192, 256, 0, stream>>>(x, xbf, 2097152);
  transpose_f2bf<<<dim3(32, 64), tb, 0, stream>>>(Wq, WT,                        2048, 1024);
  transpose_f2bf<<<dim3(64, 64), tb, 0, stream>>>(Wk, WT + (size_t)1024 * 2048,  2048, 2048);
  transpose_f2bf<<<dim3(64, 64), tb, 0, stream>>>(Wv, WT + (size_t)3072 * 2048,  2048, 2048);
  transpose_f2bf<<<dim3(32, 64), tb, 0, stream>>>(Wg, WT + (size_t)5120 * 2048,  2048, 1024);
  transpose_f2bf<<<dim3(64, 32), tb, 0, stream>>>(Wo, WoT, 1024, 2048);

  gemm_bf16<<<dim3(48, 8), 256, 0, stream>>>(xbf, WT, qkvg, 1024, NFUSE, 2048);
  small_gemm_ba<<<dim3(1024, 24), 64, 0, stream>>>(x, Wb, Wa, xb, xa);

  conv_qkv_kernel<<<dim3(1024, 40), 128, 0, stream>>>(qkvg, cqw, ckw, cvw, q_s, k_s, v_s);
  bg_kernel<<<1024, 32, 0, stream>>>(xb, xa, A_log, dt_bias, beta_s, ge_s);

  scan_kernel<<<512, 64, 0, stream>>>(q_s, k_s, v_s, beta_s, ge_s, o_s, out_state);

  post_kernel<<<dim3(1024, 8), 128, 0, stream>>>(o_s, qkvg, norm_w, Afin);
  gemm_bf16<<<dim3(16, 8), 256, 0, stream>>>(Afin, WoT, out_main, 1024, 2048, 1024);
}

// Round 9
// 352.324 us; speedup vs baseline: 13.5181x; 1.0019x over previous
//
#include <hip/hip_runtime.h>
#include <hip/hip_bf16.h>
#include <cmath>

#define B_   2
#define L_   512
#define HID  2048
#define DH   128
#define NH   8
#define NHH  2
#define ROWS 1024  // B_*L_
#define NFUSE 6144 // 1024(q)+2048(k)+2048(v)+1024(g)

typedef float  f32x2  __attribute__((ext_vector_type(2)));
typedef float  f32x4  __attribute__((ext_vector_type(4)));
typedef __bf16 bf16x8 __attribute__((ext_vector_type(8)));

#define AS1(p) ((const __attribute__((address_space(1))) unsigned int*)(p))
#define AS3(p) ((__attribute__((address_space(3))) unsigned int*)(p))

__device__ __forceinline__ float dpp_xor1(float x) {
  int r = __builtin_amdgcn_update_dpp(0, __float_as_int(x), 0xB1, 0xF, 0xF, true);
  return __int_as_float(r);
}
__device__ __forceinline__ float dpp_xor2(float x) {
  int r = __builtin_amdgcn_update_dpp(0, __float_as_int(x), 0x4E, 0xF, 0xF, true);
  return __int_as_float(r);
}
__device__ __forceinline__ float dpp_hmirror(float x) {  // mirror within 8
  int r = __builtin_amdgcn_update_dpp(0, __float_as_int(x), 0x141, 0xF, 0xF, true);
  return __int_as_float(r);
}
__device__ __forceinline__ float dpp_rmirror(float x) {  // mirror within 16
  int r = __builtin_amdgcn_update_dpp(0, __float_as_int(x), 0x140, 0xF, 0xF, true);
  return __int_as_float(r);
}

// ---------------- f32 -> bf16 elementwise ----------------
__global__ void f2bf_kernel(const float* __restrict__ in, __hip_bfloat16* __restrict__ out, int n) {
  int i = blockIdx.x * 256 + threadIdx.x;
  if (i < n) out[i] = __float2bfloat16(in[i]);
}

// ---------------- f32 (K x N) -> bf16 transposed (N x K) ----------------
__global__ __launch_bounds__(256) void transpose_f2bf(const float* __restrict__ in,
                                                      __hip_bfloat16* __restrict__ out,
                                                      int K, int N) {
  __shared__ float tile[32][33];
  int n0 = blockIdx.x * 32, k0 = blockIdx.y * 32;
  int tx = threadIdx.x, ty = threadIdx.y;  // 32 x 8
#pragma unroll
  for (int i = 0; i < 32; i += 8)
    tile[ty + i][tx] = in[(size_t)(k0 + ty + i) * N + n0 + tx];
  __syncthreads();
#pragma unroll
  for (int i = 0; i < 32; i += 8)
    out[(size_t)(n0 + ty + i) * K + k0 + tx] = __float2bfloat16(tile[tx][ty + i]);
}

// ---------------- bf16 MFMA GEMM: C(MxN) = A(MxK) * BT(NxK)^T ----------------
__global__ __launch_bounds__(256) void gemm_bf16(const __hip_bfloat16* __restrict__ A,
                                                 const __hip_bfloat16* __restrict__ BT,
                                                 float* __restrict__ C, int M, int N, int K) {
  __shared__ __align__(16) __hip_bfloat16 lA[128 * 32];
  __shared__ __align__(16) __hip_bfloat16 lB[128 * 32];
  const int tid = threadIdx.x;
  const int lane = tid & 63;
  const int w = tid >> 6;
  const int wr = w >> 1, wc = w & 1;
  const int row0 = blockIdx.y * 128;
  const int col0 = blockIdx.x * 128;
  f32x4 acc[4][4];
#pragma unroll
  for (int m = 0; m < 4; ++m)
#pragma unroll
    for (int n = 0; n < 4; ++n) acc[m][n] = {0.f, 0.f, 0.f, 0.f};
  const int fr = lane & 15;
  const int ko = (lane >> 4) * 8;
  for (int kt = 0; kt < K; kt += 32) {
#pragma unroll
    for (int i = 0; i < 2; ++i) {
      int elem = (w * 2 + i) * 512 + lane * 8;
      int rr = elem >> 5, cc = elem & 31;
      const __hip_bfloat16* srcA = A + (size_t)(row0 + rr) * K + kt + cc;
      __builtin_amdgcn_global_load_lds(AS1(srcA), AS3(&lA[(w * 2 + i) * 512]), 16, 0, 0);
      const __hip_bfloat16* srcB = BT + (size_t)(col0 + rr) * K + kt + cc;
      __builtin_amdgcn_global_load_lds(AS1(srcB), AS3(&lB[(w * 2 + i) * 512]), 16, 0, 0);
    }
    __syncthreads();
    bf16x8 af[4], bfr[4];
#pragma unroll
    for (int m = 0; m < 4; ++m)
      af[m] = *reinterpret_cast<const bf16x8*>(&lA[(wr * 64 + m * 16 + fr) * 32 + ko]);
#pragma unroll
    for (int n = 0; n < 4; ++n)
      bfr[n] = *reinterpret_cast<const bf16x8*>(&lB[(wc * 64 + n * 16 + fr) * 32 + ko]);
#pragma unroll
    for (int m = 0; m < 4; ++m)
#pragma unroll
      for (int n = 0; n < 4; ++n)
        acc[m][n] = __builtin_amdgcn_mfma_f32_16x16x32_bf16(af[m], bfr[n], acc[m][n], 0, 0, 0);
    __syncthreads();
  }
  const int rq = (lane >> 4) * 4;
#pragma unroll
  for (int m = 0; m < 4; ++m)
#pragma unroll
    for (int n = 0; n < 4; ++n)
#pragma unroll
      for (int r = 0; r < 4; ++r)
        C[(size_t)(row0 + wr * 64 + m * 16 + rq + r) * N + (col0 + wc * 64 + n * 16 + fr)] =
            acc[m][n][r];
}

// ---------------- small GEMM for Wb (16 cols) and Wa (8 cols), f32 ----------------
__global__ void small_gemm_ba(const float* __restrict__ x, const float* __restrict__ Wb,
                              const float* __restrict__ Wa, float* __restrict__ xb,
                              float* __restrict__ xa) {
  int row = blockIdx.x;
  int col = blockIdx.y;
  int lane = threadIdx.x;
  float acc = 0.f;
  if (col < 16) {
    for (int k = lane; k < HID; k += 64) acc += x[(size_t)row * HID + k] * Wb[(size_t)k * 16 + col];
  } else {
    int c = col - 16;
    for (int k = lane; k < HID; k += 64) acc += x[(size_t)row * HID + k] * Wa[(size_t)k * 8 + c];
  }
#pragma unroll
  for (int off = 32; off; off >>= 1) acc += __shfl_down(acc, off);
  if (lane == 0) {
    if (col < 16) xb[(size_t)row * 16 + col] = acc;
    else          xa[(size_t)row * 8 + (col - 16)] = acc;
  }
}

__device__ __forceinline__ float silu_f(float y) { return y / (1.f + __expf(-y)); }

// ---------------- fused conv + silu (+l2norm for q/k) for q,k,v ----------------
__global__ __launch_bounds__(128) void conv_qkv_kernel(const float* __restrict__ qkvg,
                                                       const float* __restrict__ wq,
                                                       const float* __restrict__ wk,
                                                       const float* __restrict__ wv,
                                                       float* __restrict__ q_s,
                                                       float* __restrict__ k_s,
                                                       float* __restrict__ v_s) {
  int bt = blockIdx.x;
  int yy = blockIdx.y;
  int d  = threadIdx.x;
  int b = bt >> 9, t = bt & 511;
  __shared__ float red[2];
  if (yy < 8) {
    int h = yy, c = h * 128 + d;
    float y = 0.f;
#pragma unroll
    for (int tau = 0; tau < 4; ++tau) {
      int tt = t - 3 + tau;
      float xv = (tt >= 0) ? qkvg[(size_t)(b * 512 + tt) * NFUSE + c] : 0.f;
      y += xv * wq[c * 4 + tau];
    }
    y = silu_f(y);
    float ss = y * y;
#pragma unroll
    for (int off = 32; off; off >>= 1) ss += __shfl_down(ss, off);
    if ((d & 63) == 0) red[d >> 6] = ss;
    __syncthreads();
    float scale = (1.f / fmaxf(sqrtf(red[0] + red[1]), 1e-12f)) * 0.08838834764831845f;
    q_s[((size_t)(b * 8 + h) * 512 + t) * 128 + d] = y * scale;
  } else if (yy < 24) {
    int jh = yy - 8;
    int j = jh >> 3, h = jh & 7;
    int c = j * 1024 + h * 128 + d;
    float y = 0.f;
#pragma unroll
    for (int tau = 0; tau < 4; ++tau) {
      int tt = t - 3 + tau;
      float xv = (tt >= 0) ? qkvg[(size_t)(b * 512 + tt) * NFUSE + 1024 + c] : 0.f;
      y += xv * wk[c * 4 + tau];
    }
    y = silu_f(y);
    float ss = y * y;
#pragma unroll
    for (int off = 32; off; off >>= 1) ss += __shfl_down(ss, off);
    if ((d & 63) == 0) red[d >> 6] = ss;
    __syncthreads();
    float scale = 1.f / fmaxf(sqrtf(red[0] + red[1]), 1e-12f);
    k_s[(((size_t)(b * 8 + h) * 2 + j) * 512 + t) * 128 + d] = y * scale;
  } else {
    int jh = yy - 24;
    int j = jh >> 3, h = jh & 7;
    int c = j * 1024 + h * 128 + d;
    float y = 0.f;
#pragma unroll
    for (int tau = 0; tau < 4; ++tau) {
      int tt = t - 3 + tau;
      float xv = (tt >= 0) ? qkvg[(size_t)(b * 512 + tt) * NFUSE + 3072 + c] : 0.f;
      y += xv * wv[c * 4 + tau];
    }
    v_s[(((size_t)(b * 8 + h) * 2 + j) * 512 + t) * 128 + d] = silu_f(y);
  }
}

// ---------------- beta / exp(g) ----------------
__global__ void bg_kernel(const float* __restrict__ xb, const float* __restrict__ xa,
                          const float* __restrict__ A_log, const float* __restrict__ dt_bias,
                          float* __restrict__ beta_s, float* __restrict__ ge_s) {
  int bt = blockIdx.x;
  int i = threadIdx.x;
  int b = bt >> 9, t = bt & 511;
  if (i < 16) {
    int j = i >> 3, h = i & 7;
    float v = xb[(size_t)bt * 16 + i];
    float bv = 2.f / (1.f + __expf(-v));
    beta_s[(((size_t)(b * 8 + h)) * 2 + j) * 512 + t] = bv;
  } else if (i < 24) {
    int h = i - 16;
    float v = xa[(size_t)bt * 8 + h] + dt_bias[h];
    float sp = (v > 20.f) ? v : log1pf(__expf(v));
    float g = -__expf(A_log[h]) * sp;
    ge_s[((size_t)(b * 8 + h)) * 512 + t] = __expf(g);
  }
}

// ---------------- input-only cross dots: d01=k1.k0, dq0=q.k0, dq1=q.k1 ----------
// These make the scan's three reduce phases collapsible into ONE (round-8
// lesson: scan is dep-chain-bound; widening didn't help).
// dots_s layout [bh][3][512].
__global__ __launch_bounds__(64) void dots_kernel(const float* __restrict__ q_s,
                                                  const float* __restrict__ k_s,
                                                  float* __restrict__ dots_s) {
  const int bh = blockIdx.x;     // 0..15
  const int ty = blockIdx.y;     // 0..63, 8 t's per block
  const int lane = threadIdx.x;
  const int e  = lane & 7;       // elem-sixteenth 0..7
  const int tl = lane >> 3;      // 0..7
  const int t = ty * 8 + tl;
  const float* k0 = k_s + ((size_t)bh * 2 + 0) * 512 * 128 + (size_t)t * 128 + e * 16;
  const float* k1 = k_s + ((size_t)bh * 2 + 1) * 512 * 128 + (size_t)t * 128 + e * 16;
  const float* qq = q_s + (size_t)bh * 512 * 128 + (size_t)t * 128 + e * 16;
  float d01 = 0.f, dq0 = 0.f, dq1 = 0.f;
#pragma unroll
  for (int i = 0; i < 4; ++i) {
    f32x4 a = *(const f32x4*)(k0 + i * 4);
    f32x4 b = *(const f32x4*)(k1 + i * 4);
    f32x4 c = *(const f32x4*)(qq + i * 4);
    f32x4 t1 = a * b, t2 = c * a, t3 = c * b;
    d01 += (t1[0] + t1[1]) + (t1[2] + t1[3]);
    dq0 += (t2[0] + t2[1]) + (t2[2] + t2[3]);
    dq1 += (t3[0] + t3[1]) + (t3[2] + t3[3]);
  }
  d01 += dpp_xor1(d01); d01 += dpp_xor2(d01); d01 += dpp_hmirror(d01);
  dq0 += dpp_xor1(dq0); dq0 += dpp_xor2(dq0); dq0 += dpp_hmirror(dq0);
  dq1 += dpp_xor1(dq1); dq1 += dpp_xor2(dq1); dq1 += dpp_hmirror(dq1);
  if (e == 0) {
    float* dst = dots_s + (size_t)bh * 3 * 512;
    dst[0 * 512 + t] = d01;
    dst[1 * 512 + t] = dq0;
    dst[2 * 512 + t] = dq1;
  }
}

// ---------------- scan: single-reduce-phase step via precomputed cross-dots ----
// 512 blocks x 64 thr (ONE wave, no barriers) = 16 chains x 32 v-groups.
// Per step: Sg = S*eg; r0=k0.Sg, r1=k1.Sg, rq=q.Sg reduced IN PARALLEL
// (3 values pipeline through one DPP sequence); then the scalar chain
// u0=(mv0-r0)b0; u1=(mv1-r1-d01*u0)b1; o=rq+dq0*u0+dq1*u1; S=Sg+k0*u0+k1*u1.
// Identical algebra to the 3-pass form, reassociated to remove 2 of 3
// sequential reduce phases from the loop-carried path.
#define R4(X) X(0) X(1) X(2) X(3)
#define CH 12                        // padded chunk stride (8 data + 4)
#define TSTEP 8
#define STEPF (3 * 16 * CH)          // 576 floats per step
#define TILEF (TSTEP * STEPF)        // 4608 floats per buffer

__global__ __launch_bounds__(64, 1) void scan_kernel(const float* __restrict__ q_s,
                                                     const float* __restrict__ k_s,
                                                     const float* __restrict__ v_s,
                                                     const float* __restrict__ beta_s,
                                                     const float* __restrict__ ge_s,
                                                     const float* __restrict__ dots_s,
                                                     float* __restrict__ o_s,
                                                     float* __restrict__ state_out) {
  const int blk = blockIdx.x;      // 0..511
  const int bh  = blk >> 5;        // chain 0..15
  const int wg  = blk & 31;        // v-group 0..31 (4 cols)
  const int lane = threadIdx.x;    // 0..63
  const int kr = lane & 15;        // k-sixteenth 0..15
  const int vi = lane >> 4;        // 0..3
  const int v  = wg * 4 + vi;      // global v column

  __shared__ __align__(16) float lds[2][TILEF];
  __shared__ __align__(16) float vbuf[2][2][TSTEP][4];
  __shared__ __align__(16) float lds_bg[6][512];   // eg, b0, b1, d01, dq0, dq1

  f32x4 s0 = {0.f, 0.f, 0.f, 0.f}, s1 = {0.f, 0.f, 0.f, 0.f};
#define DECLG(j) f32x4 Gk0_##j, Gk1_##j, Gq_##j;
  R4(DECLG)
#undef DECLG
  float Gv;

  const float* g_k0 = k_s + ((size_t)bh * 2 + 0) * 512 * 128;
  const float* g_k1 = k_s + ((size_t)bh * 2 + 1) * 512 * 128;
  const float* g_q  = q_s + (size_t)bh * 512 * 128;
  const float* g_v0w = v_s + ((size_t)bh * 2 + 0) * 512 * 128 + wg * 4;
  const float* g_v1w = v_s + ((size_t)bh * 2 + 1) * 512 * 128 + wg * 4;
  const float* b0p = beta_s + ((size_t)bh * 2 + 0) * 512;
  const float* b1p = beta_s + ((size_t)bh * 2 + 1) * 512;
  const float* gp  = ge_s + (size_t)bh * 512;
  const float* dp  = dots_s + (size_t)bh * 3 * 512;

  // preload eg/beta/dots wholesale (same-wave read-before-use ordering)
#pragma unroll
  for (int i = 0; i < 2; ++i) {
    int c4 = lane + i * 64;
    *(f32x4*)&lds_bg[0][c4 * 4] = *(const f32x4*)(gp  + c4 * 4);
    *(f32x4*)&lds_bg[1][c4 * 4] = *(const f32x4*)(b0p + c4 * 4);
    *(f32x4*)&lds_bg[2][c4 * 4] = *(const f32x4*)(b1p + c4 * 4);
    *(f32x4*)&lds_bg[3][c4 * 4] = *(const f32x4*)(dp + 0 * 512 + c4 * 4);
    *(f32x4*)&lds_bg[4][c4 * 4] = *(const f32x4*)(dp + 1 * 512 + c4 * 4);
    *(f32x4*)&lds_bg[5][c4 * 4] = *(const f32x4*)(dp + 2 * 512 + c4 * 4);
  }

  // V staging: lanes 0-31 -> v0, 32-63 -> v1
  const int vhalf = lane >> 5;
  const int vli = lane & 31;
  const int vtl = vli >> 2, vc = vli & 3;
  const float* vsrc = vhalf ? g_v1w : g_v0w;

#define LD1(j) { Gk0_##j = p0[lane + j * 64]; Gk1_##j = p1[lane + j * 64]; Gq_##j = pq[lane + j * 64]; }
#define LOAD_G(T) { const f32x4* __restrict__ p0 = (const f32x4*)(g_k0 + (size_t)(T) * 1024); \
                    const f32x4* __restrict__ p1 = (const f32x4*)(g_k1 + (size_t)(T) * 1024); \
                    const f32x4* __restrict__ pq = (const f32x4*)(g_q  + (size_t)(T) * 1024); \
                    R4(LD1) }
#define LOAD_V(T) { Gv = vsrc[(size_t)(T) * 1024 + vtl * 128 + vc]; }
#define WR1(j) { int g_ = lane + 64 * j; int tl_ = g_ >> 5; int kr_ = (g_ & 31) >> 1; \
                 int c_ = 4 * (g_ & 1); \
    *(f32x4*)&lds[bsel][((tl_ * 3 + 0) * 16 + kr_) * CH + c_] = Gk0_##j; \
    *(f32x4*)&lds[bsel][((tl_ * 3 + 1) * 16 + kr_) * CH + c_] = Gk1_##j; \
    *(f32x4*)&lds[bsel][((tl_ * 3 + 2) * 16 + kr_) * CH + c_] = Gq_##j; }
#define WRITE_G(b) { const int bsel = (b); R4(WR1) }
#define WRITE_V(b) { vbuf[b][vhalf][vtl][vc] = Gv; }

  LOAD_G(0) LOAD_V(0)
  WRITE_G(0) WRITE_V(0)
  LOAD_G(1) LOAD_V(1)

  for (int T = 0; T < 64; ++T) {
    const int buf = T & 1;
    if (T < 63) { WRITE_G(buf ^ 1) WRITE_V(buf ^ 1) }
    if (T < 62) { LOAD_G(T + 2) LOAD_V(T + 2) }
#pragma unroll
    for (int tl = 0; tl < TSTEP; ++tl) {
      const int t = T * TSTEP + tl;
      const float eg  = lds_bg[0][t];
      const float bb0 = lds_bg[1][t];
      const float bb1 = lds_bg[2][t];
      const float d01 = lds_bg[3][t];
      const float dq0 = lds_bg[4][t];
      const float dq1 = lds_bg[5][t];
      const float mv0 = vbuf[buf][0][tl][vi];
      const float mv1 = vbuf[buf][1][tl][vi];
      const f32x4* __restrict__ pk0 = (const f32x4*)&lds[buf][((tl * 3 + 0) * 16 + kr) * CH];
      const f32x4* __restrict__ pk1 = (const f32x4*)&lds[buf][((tl * 3 + 1) * 16 + kr) * CH];
      const f32x4* __restrict__ pq  = (const f32x4*)&lds[buf][((tl * 3 + 2) * 16 + kr) * CH];
      f32x4 a0 = pk0[0], a1 = pk0[1];
      f32x4 b0 = pk1[0], b1 = pk1[1];
      f32x4 c0 = pq[0],  c1 = pq[1];
      // decay + three parallel state dots
      s0 *= eg; s1 *= eg;
      f32x4 r0v = a0 * s0; r0v += a1 * s1;
      f32x4 r1v = b0 * s0; r1v += b1 * s1;
      f32x4 rqv = c0 * s0; rqv += c1 * s1;
      float p0 = (r0v[0] + r0v[1]) + (r0v[2] + r0v[3]);
      float p1 = (r1v[0] + r1v[1]) + (r1v[2] + r1v[3]);
      float pq2 = (rqv[0] + rqv[1]) + (rqv[2] + rqv[3]);
      p0 += dpp_xor1(p0);   p1 += dpp_xor1(p1);   pq2 += dpp_xor1(pq2);
      p0 += dpp_xor2(p0);   p1 += dpp_xor2(p1);   pq2 += dpp_xor2(pq2);
      p0 += dpp_hmirror(p0); p1 += dpp_hmirror(p1); pq2 += dpp_hmirror(pq2);
      p0 += dpp_rmirror(p0); p1 += dpp_rmirror(p1); pq2 += dpp_rmirror(pq2);
      // short scalar chain
      const float u0 = (mv0 - p0) * bb0;
      const float u1 = (mv1 - p1 - d01 * u0) * bb1;
      const float o  = pq2 + dq0 * u0 + dq1 * u1;
      // fused state update
      s0 += a0 * u0; s1 += a1 * u0;
      s0 += b0 * u1; s1 += b1 * u1;
      if (kr == 0) o_s[((size_t)bh * 512 + t) * 128 + v] = o;
    }
  }

  float* base = state_out + (size_t)bh * 128 * 128 + v;
#pragma unroll
  for (int i = 0; i < 4; ++i) {
    base[(kr * 8 + i) * 128]     = s0[i];
    base[(kr * 8 + 4 + i) * 128] = s1[i];
  }
}

// ---------------- rmsnorm + gate silu -> bf16 A for final GEMM ----------------
__global__ __launch_bounds__(128) void post_kernel(const float* __restrict__ o_s,
                                                   const float* __restrict__ qkvg,
                                                   const float* __restrict__ norm_w,
                                                   __hip_bfloat16* __restrict__ Afin) {
  int bt = blockIdx.x;
  int h = blockIdx.y;
  int d = threadIdx.x;
  int b = bt >> 9, t = bt & 511;
  int bh = b * 8 + h;
  float o = o_s[((size_t)bh * 512 + t) * 128 + d];
  __shared__ float red[2];
  float ss = o * o;
#pragma unroll
  for (int off = 32; off; off >>= 1) ss += __shfl_down(ss, off);
  if ((d & 63) == 0) red[d >> 6] = ss;
  __syncthreads();
  float mean = (red[0] + red[1]) * (1.f / 128.f);
  float r = rsqrtf(mean + 1e-5f);
  float gate = qkvg[(size_t)bt * NFUSE + 5120 + h * 128 + d];
  float val = o * r * norm_w[d] * silu_f(gate);
  Afin[(size_t)bt * 1024 + h * 128 + d] = __float2bfloat16(val);
}

extern "C" void kernel_launch(void* const* d_in, const int* in_sizes, int n_in,
                              void* d_out, int out_size, void* d_ws, size_t ws_size,
                              hipStream_t stream) {
  const float* x       = (const float*)d_in[0];
  const float* Wq      = (const float*)d_in[1];
  const float* Wk      = (const float*)d_in[2];
  const float* Wv      = (const float*)d_in[3];
  const float* Wb      = (const float*)d_in[4];
  const float* Wa      = (const float*)d_in[5];
  const float* A_log   = (const float*)d_in[6];
  const float* dt_bias = (const float*)d_in[7];
  const float* cqw     = (const float*)d_in[8];
  const float* ckw     = (const float*)d_in[9];
  const float* cvw     = (const float*)d_in[10];
  const float* Wg      = (const float*)d_in[11];
  const float* norm_w  = (const float*)d_in[12];
  const float* Wo      = (const float*)d_in[13];

  char* ws = (char*)d_ws;
  size_t off = 0;
  auto alloc = [&](size_t bytes) {
    void* p = ws + off;
    off += (bytes + 255) & ~(size_t)255;
    return p;
  };
  __hip_bfloat16* xbf  = (__hip_bfloat16*)alloc((size_t)2097152 * 2);
  __hip_bfloat16* WT   = (__hip_bfloat16*)alloc((size_t)NFUSE * 2048 * 2);  // fused q|k|v|g, [N][K]
  __hip_bfloat16* WoT  = (__hip_bfloat16*)alloc((size_t)2097152 * 2);
  float* qkvg   = (float*)alloc((size_t)ROWS * NFUSE * 4);
  float* xb     = (float*)alloc((size_t)16384 * 4);
  float* xa     = (float*)alloc((size_t)8192 * 4);
  float* q_s    = (float*)alloc((size_t)1048576 * 4);
  float* k_s    = (float*)alloc((size_t)2097152 * 4);
  float* v_s    = (float*)alloc((size_t)2097152 * 4);
  float* beta_s = (float*)alloc((size_t)16384 * 4);
  float* ge_s   = (float*)alloc((size_t)8192 * 4);
  float* dots_s = (float*)alloc((size_t)16 * 3 * 512 * 4);
  float* o_s    = (float*)alloc((size_t)1048576 * 4);
  __hip_bfloat16* Afin = (__hip_bfloat16*)alloc((size_t)1048576 * 2);

  float* out_main  = (float*)d_out;
  float* out_state = out_main + 2097152;

  dim3 tb(32, 8);
  f2bf_kernel<<<8192, 256, 0, stream>>>(x, xbf, 2097152);
  transpose_f2bf<<<dim3(32, 64), tb, 0, stream>>>(Wq, WT,                        2048, 1024);
  transpose_f2bf<<<dim3(64, 64), tb, 0, stream>>>(Wk, WT + (size_t)1024 * 2048,  2048, 2048);
  transpose_f2bf<<<dim3(64, 64), tb, 0, stream>>>(Wv, WT + (size_t)3072 * 2048,  2048, 2048);
  transpose_f2bf<<<dim3(32, 64), tb, 0, stream>>>(Wg, WT + (size_t)5120 * 2048,  2048, 1024);
  transpose_f2bf<<<dim3(64, 32), tb, 0, stream>>>(Wo, WoT, 1024, 2048);

  gemm_bf16<<<dim3(48, 8), 256, 0, stream>>>(xbf, WT, qkvg, 1024, NFUSE, 2048);
  small_gemm_ba<<<dim3(1024, 24), 64, 0, stream>>>(x, Wb, Wa, xb, xa);

  conv_qkv_kernel<<<dim3(1024, 40), 128, 0, stream>>>(qkvg, cqw, ckw, cvw, q_s, k_s, v_s);
  bg_kernel<<<1024, 32, 0, stream>>>(xb, xa, A_log, dt_bias, beta_s, ge_s);
  dots_kernel<<<dim3(16, 64), 64, 0, stream>>>(q_s, k_s, dots_s);

  scan_kernel<<<512, 64, 0, stream>>>(q_s, k_s, v_s, beta_s, ge_s, dots_s, o_s, out_state);

  post_kernel<<<dim3(1024, 8), 128, 0, stream>>>(o_s, qkvg, norm_w, Afin);
  gemm_bf16<<<dim3(16, 8), 256, 0, stream>>>(Afin, WoT, out_main, 1024, 2048, 1024);
}

// Round 10
// 256.010 us; speedup vs baseline: 18.6037x; 1.3762x over previous
//
#include <hip/hip_runtime.h>
#include <hip/hip_bf16.h>
#include <cmath>

#define B_   2
#define L_   512
#define HID  2048
#define DH   128
#define NH   8
#define NHH  2
#define ROWS 1024  // B_*L_
#define NFUSE 6144 // 1024(q)+2048(k)+2048(v)+1024(g)

typedef float  f32x2  __attribute__((ext_vector_type(2)));
typedef float  f32x4  __attribute__((ext_vector_type(4)));
typedef __bf16 bf16x8 __attribute__((ext_vector_type(8)));

#define AS1(p) ((const __attribute__((address_space(1))) unsigned int*)(p))
#define AS3(p) ((__attribute__((address_space(3))) unsigned int*)(p))

__device__ __forceinline__ float dpp_xor1(float x) {
  int r = __builtin_amdgcn_update_dpp(0, __float_as_int(x), 0xB1, 0xF, 0xF, true);
  return __int_as_float(r);
}
__device__ __forceinline__ float dpp_xor2(float x) {
  int r = __builtin_amdgcn_update_dpp(0, __float_as_int(x), 0x4E, 0xF, 0xF, true);
  return __int_as_float(r);
}
__device__ __forceinline__ float dpp_hmirror(float x) {  // mirror within 8
  int r = __builtin_amdgcn_update_dpp(0, __float_as_int(x), 0x141, 0xF, 0xF, true);
  return __int_as_float(r);
}
__device__ __forceinline__ float dpp_rmirror(float x) {  // mirror within 16
  int r = __builtin_amdgcn_update_dpp(0, __float_as_int(x), 0x140, 0xF, 0xF, true);
  return __int_as_float(r);
}

// ---------------- f32 -> bf16 elementwise ----------------
__global__ void f2bf_kernel(const float* __restrict__ in, __hip_bfloat16* __restrict__ out, int n) {
  int i = blockIdx.x * 256 + threadIdx.x;
  if (i < n) out[i] = __float2bfloat16(in[i]);
}

// ---------------- 5 weight transposes in one dispatch (blockIdx.z selects) -------
__global__ __launch_bounds__(256) void transpose5_kernel(const float* __restrict__ Wq,
                                                         const float* __restrict__ Wk,
                                                         const float* __restrict__ Wv,
                                                         const float* __restrict__ Wg,
                                                         const float* __restrict__ Wo,
                                                         __hip_bfloat16* __restrict__ WT,
                                                         __hip_bfloat16* __restrict__ WoT) {
  const float* in; __hip_bfloat16* out; int K, N;
  switch (blockIdx.z) {
    case 0: in = Wq; out = WT;                          K = 2048; N = 1024; break;
    case 1: in = Wk; out = WT + (size_t)1024 * 2048;    K = 2048; N = 2048; break;
    case 2: in = Wv; out = WT + (size_t)3072 * 2048;    K = 2048; N = 2048; break;
    case 3: in = Wg; out = WT + (size_t)5120 * 2048;    K = 2048; N = 1024; break;
    default: in = Wo; out = WoT;                        K = 1024; N = 2048; break;
  }
  __shared__ float tile[32][33];
  int n0 = blockIdx.x * 32, k0 = blockIdx.y * 32;
  if (n0 >= N || k0 >= K) return;
  int tx = threadIdx.x, ty = threadIdx.y;  // 32 x 8
#pragma unroll
  for (int i = 0; i < 32; i += 8)
    tile[ty + i][tx] = in[(size_t)(k0 + ty + i) * N + n0 + tx];
  __syncthreads();
#pragma unroll
  for (int i = 0; i < 32; i += 8)
    out[(size_t)(n0 + ty + i) * K + k0 + tx] = __float2bfloat16(tile[tx][ty + i]);
}

// ---------------- bf16 MFMA GEMM: C(MxN) = A(MxK) * BT(NxK)^T ----------------
__global__ __launch_bounds__(256) void gemm_bf16(const __hip_bfloat16* __restrict__ A,
                                                 const __hip_bfloat16* __restrict__ BT,
                                                 float* __restrict__ C, int M, int N, int K) {
  __shared__ __align__(16) __hip_bfloat16 lA[128 * 32];
  __shared__ __align__(16) __hip_bfloat16 lB[128 * 32];
  const int tid = threadIdx.x;
  const int lane = tid & 63;
  const int w = tid >> 6;
  const int wr = w >> 1, wc = w & 1;
  const int row0 = blockIdx.y * 128;
  const int col0 = blockIdx.x * 128;
  f32x4 acc[4][4];
#pragma unroll
  for (int m = 0; m < 4; ++m)
#pragma unroll
    for (int n = 0; n < 4; ++n) acc[m][n] = {0.f, 0.f, 0.f, 0.f};
  const int fr = lane & 15;
  const int ko = (lane >> 4) * 8;
  for (int kt = 0; kt < K; kt += 32) {
#pragma unroll
    for (int i = 0; i < 2; ++i) {
      int elem = (w * 2 + i) * 512 + lane * 8;
      int rr = elem >> 5, cc = elem & 31;
      const __hip_bfloat16* srcA = A + (size_t)(row0 + rr) * K + kt + cc;
      __builtin_amdgcn_global_load_lds(AS1(srcA), AS3(&lA[(w * 2 + i) * 512]), 16, 0, 0);
      const __hip_bfloat16* srcB = BT + (size_t)(col0 + rr) * K + kt + cc;
      __builtin_amdgcn_global_load_lds(AS1(srcB), AS3(&lB[(w * 2 + i) * 512]), 16, 0, 0);
    }
    __syncthreads();
    bf16x8 af[4], bfr[4];
#pragma unroll
    for (int m = 0; m < 4; ++m)
      af[m] = *reinterpret_cast<const bf16x8*>(&lA[(wr * 64 + m * 16 + fr) * 32 + ko]);
#pragma unroll
    for (int n = 0; n < 4; ++n)
      bfr[n] = *reinterpret_cast<const bf16x8*>(&lB[(wc * 64 + n * 16 + fr) * 32 + ko]);
#pragma unroll
    for (int m = 0; m < 4; ++m)
#pragma unroll
      for (int n = 0; n < 4; ++n)
        acc[m][n] = __builtin_amdgcn_mfma_f32_16x16x32_bf16(af[m], bfr[n], acc[m][n], 0, 0, 0);
    __syncthreads();
  }
  const int rq = (lane >> 4) * 4;
#pragma unroll
  for (int m = 0; m < 4; ++m)
#pragma unroll
    for (int n = 0; n < 4; ++n)
#pragma unroll
      for (int r = 0; r < 4; ++r)
        C[(size_t)(row0 + wr * 64 + m * 16 + rq + r) * N + (col0 + wc * 64 + n * 16 + fr)] =
            acc[m][n][r];
}

__device__ __forceinline__ float silu_f(float y) { return y / (1.f + __expf(-y)); }

// ---------------- fused x@Wb / x@Wa + beta/g transforms (one block per row) ------
// Replaces small_gemm_ba (x re-read 24x) + bg_kernel: x row read ONCE per block.
__global__ __launch_bounds__(64) void ba_fused_kernel(const float* __restrict__ x,
                                                      const float* __restrict__ Wb,
                                                      const float* __restrict__ Wa,
                                                      const float* __restrict__ A_log,
                                                      const float* __restrict__ dt_bias,
                                                      float* __restrict__ beta_s,
                                                      float* __restrict__ ge_s) {
  const int row = blockIdx.x;   // b*512 + t
  const int lane = threadIdx.x;
  f32x4 aB0 = {0,0,0,0}, aB1 = {0,0,0,0}, aB2 = {0,0,0,0}, aB3 = {0,0,0,0};
  f32x4 aA0 = {0,0,0,0}, aA1 = {0,0,0,0};
  const float* xr = x + (size_t)row * HID;
  for (int i = 0; i < 32; ++i) {
    int k = lane + i * 64;
    float xv = xr[k];
    const f32x4* wb4 = (const f32x4*)(Wb + (size_t)k * 16);
    const f32x4* wa4 = (const f32x4*)(Wa + (size_t)k * 8);
    aB0 += wb4[0] * xv; aB1 += wb4[1] * xv; aB2 += wb4[2] * xv; aB3 += wb4[3] * xv;
    aA0 += wa4[0] * xv; aA1 += wa4[1] * xv;
  }
  __shared__ float red[64][25];
#pragma unroll
  for (int c = 0; c < 4; ++c) {
    red[lane][0 + c]  = aB0[c];
    red[lane][4 + c]  = aB1[c];
    red[lane][8 + c]  = aB2[c];
    red[lane][12 + c] = aB3[c];
    red[lane][16 + c] = aA0[c];
    red[lane][20 + c] = aA1[c];
  }
  // single wave: in-order LDS, no barrier needed
  if (lane < 24) {
    float s = 0.f;
#pragma unroll 8
    for (int i = 0; i < 64; ++i) s += red[i][lane];
    int b = row >> 9, t = row & 511;
    if (lane < 16) {
      int j = lane >> 3, h = lane & 7;
      beta_s[(((size_t)(b * 8 + h)) * 2 + j) * 512 + t] = 2.f / (1.f + __expf(-s));
    } else {
      int h = lane - 16;
      float vv = s + dt_bias[h];
      float sp = (vv > 20.f) ? vv : log1pf(__expf(vv));
      ge_s[((size_t)(b * 8 + h)) * 512 + t] = __expf(-__expf(A_log[h]) * sp);
    }
  }
}

// ---------------- fused conv + silu (+l2norm for q/k) for q,k,v ----------------
__global__ __launch_bounds__(128) void conv_qkv_kernel(const float* __restrict__ qkvg,
                                                       const float* __restrict__ wq,
                                                       const float* __restrict__ wk,
                                                       const float* __restrict__ wv,
                                                       float* __restrict__ q_s,
                                                       float* __restrict__ k_s,
                                                       float* __restrict__ v_s) {
  int bt = blockIdx.x;
  int yy = blockIdx.y;
  int d  = threadIdx.x;
  int b = bt >> 9, t = bt & 511;
  __shared__ float red[2];
  if (yy < 8) {
    int h = yy, c = h * 128 + d;
    float y = 0.f;
#pragma unroll
    for (int tau = 0; tau < 4; ++tau) {
      int tt = t - 3 + tau;
      float xv = (tt >= 0) ? qkvg[(size_t)(b * 512 + tt) * NFUSE + c] : 0.f;
      y += xv * wq[c * 4 + tau];
    }
    y = silu_f(y);
    float ss = y * y;
#pragma unroll
    for (int off = 32; off; off >>= 1) ss += __shfl_down(ss, off);
    if ((d & 63) == 0) red[d >> 6] = ss;
    __syncthreads();
    float scale = (1.f / fmaxf(sqrtf(red[0] + red[1]), 1e-12f)) * 0.08838834764831845f;
    q_s[((size_t)(b * 8 + h) * 512 + t) * 128 + d] = y * scale;
  } else if (yy < 24) {
    int jh = yy - 8;
    int j = jh >> 3, h = jh & 7;
    int c = j * 1024 + h * 128 + d;
    float y = 0.f;
#pragma unroll
    for (int tau = 0; tau < 4; ++tau) {
      int tt = t - 3 + tau;
      float xv = (tt >= 0) ? qkvg[(size_t)(b * 512 + tt) * NFUSE + 1024 + c] : 0.f;
      y += xv * wk[c * 4 + tau];
    }
    y = silu_f(y);
    float ss = y * y;
#pragma unroll
    for (int off = 32; off; off >>= 1) ss += __shfl_down(ss, off);
    if ((d & 63) == 0) red[d >> 6] = ss;
    __syncthreads();
    float scale = 1.f / fmaxf(sqrtf(red[0] + red[1]), 1e-12f);
    k_s[(((size_t)(b * 8 + h) * 2 + j) * 512 + t) * 128 + d] = y * scale;
  } else {
    int jh = yy - 24;
    int j = jh >> 3, h = jh & 7;
    int c = j * 1024 + h * 128 + d;
    float y = 0.f;
#pragma unroll
    for (int tau = 0; tau < 4; ++tau) {
      int tt = t - 3 + tau;
      float xv = (tt >= 0) ? qkvg[(size_t)(b * 512 + tt) * NFUSE + 3072 + c] : 0.f;
      y += xv * wv[c * 4 + tau];
    }
    v_s[(((size_t)(b * 8 + h) * 2 + j) * 512 + t) * 128 + d] = silu_f(y);
  }
}

// ---------------- input-only cross dots: d01=k1.k0, dq0=q.k0, dq1=q.k1 ----------
__global__ __launch_bounds__(64) void dots_kernel(const float* __restrict__ q_s,
                                                  const float* __restrict__ k_s,
                                                  float* __restrict__ dots_s) {
  const int bh = blockIdx.x;     // 0..15
  const int ty = blockIdx.y;     // 0..63, 8 t's per block
  const int lane = threadIdx.x;
  const int e  = lane & 7;
  const int tl = lane >> 3;
  const int t = ty * 8 + tl;
  const float* k0 = k_s + ((size_t)bh * 2 + 0) * 512 * 128 + (size_t)t * 128 + e * 16;
  const float* k1 = k_s + ((size_t)bh * 2 + 1) * 512 * 128 + (size_t)t * 128 + e * 16;
  const float* qq = q_s + (size_t)bh * 512 * 128 + (size_t)t * 128 + e * 16;
  float d01 = 0.f, dq0 = 0.f, dq1 = 0.f;
#pragma unroll
  for (int i = 0; i < 4; ++i) {
    f32x4 a = *(const f32x4*)(k0 + i * 4);
    f32x4 b = *(const f32x4*)(k1 + i * 4);
    f32x4 c = *(const f32x4*)(qq + i * 4);
    f32x4 t1 = a * b, t2 = c * a, t3 = c * b;
    d01 += (t1[0] + t1[1]) + (t1[2] + t1[3]);
    dq0 += (t2[0] + t2[1]) + (t2[2] + t2[3]);
    dq1 += (t3[0] + t3[1]) + (t3[2] + t3[3]);
  }
  d01 += dpp_xor1(d01); d01 += dpp_xor2(d01); d01 += dpp_hmirror(d01);
  dq0 += dpp_xor1(dq0); dq0 += dpp_xor2(dq0); dq0 += dpp_hmirror(dq0);
  dq1 += dpp_xor1(dq1); dq1 += dpp_xor2(dq1); dq1 += dpp_hmirror(dq1);
  if (e == 0) {
    float* dst = dots_s + (size_t)bh * 3 * 512;
    dst[0 * 512 + t] = d01;
    dst[1 * 512 + t] = dq0;
    dst[2 * 512 + t] = dq1;
  }
}

// ---------------- scan: single-reduce step + 2-deep LDS-read register pipeline ---
// 512 blocks x 64 thr (ONE wave, no barriers) = 16 chains x 32 v-groups.
// Round-9 lesson: width & reduce-chain changes were null -> the ~380cyc/step
// residual is per-step DS latency the compiler wasn't pipelining. Fix: named
// A/B operand sets; LOAD_SET(t+1) issues before COMPUTE(t), pinned with
// sched_barrier(0). Tile-boundary prefetch reads next tile's step 0 (already
// staged; in-wave DS ordering guarantees visibility).
#define R4(X) X(0) X(1) X(2) X(3)
#define CH 12                        // padded chunk stride (8 data + 4)
#define TSTEP 8
#define STEPF (3 * 16 * CH)          // 576 floats per step
#define TILEF (TSTEP * STEPF)        // 4608 floats per buffer

__global__ __launch_bounds__(64, 1) void scan_kernel(const float* __restrict__ q_s,
                                                     const float* __restrict__ k_s,
                                                     const float* __restrict__ v_s,
                                                     const float* __restrict__ beta_s,
                                                     const float* __restrict__ ge_s,
                                                     const float* __restrict__ dots_s,
                                                     float* __restrict__ o_s,
                                                     float* __restrict__ state_out) {
  const int blk = blockIdx.x;      // 0..511
  const int bh  = blk >> 5;        // chain 0..15
  const int wg  = blk & 31;        // v-group 0..31 (4 cols)
  const int lane = threadIdx.x;    // 0..63
  const int kr = lane & 15;        // k-sixteenth 0..15
  const int vi = lane >> 4;        // 0..3
  const int v  = wg * 4 + vi;      // global v column

  __shared__ __align__(16) float lds[2][TILEF];
  __shared__ __align__(16) float vbuf[2][2][TSTEP][4];
  __shared__ __align__(16) float lds_bg[6][512];   // eg, b0, b1, d01, dq0, dq1

  f32x4 s0 = {0.f, 0.f, 0.f, 0.f}, s1 = {0.f, 0.f, 0.f, 0.f};
#define DECLG(j) f32x4 Gk0_##j, Gk1_##j, Gq_##j;
  R4(DECLG)
#undef DECLG
  float Gv;
#define DECLSET(S) f32x4 S##_a0, S##_a1, S##_b0, S##_b1, S##_c0, S##_c1; \
  float S##_eg, S##_bb0, S##_bb1, S##_d01, S##_dq0, S##_dq1, S##_mv0, S##_mv1;
  DECLSET(A) DECLSET(B)
#undef DECLSET

  const float* g_k0 = k_s + ((size_t)bh * 2 + 0) * 512 * 128;
  const float* g_k1 = k_s + ((size_t)bh * 2 + 1) * 512 * 128;
  const float* g_q  = q_s + (size_t)bh * 512 * 128;
  const float* g_v0w = v_s + ((size_t)bh * 2 + 0) * 512 * 128 + wg * 4;
  const float* g_v1w = v_s + ((size_t)bh * 2 + 1) * 512 * 128 + wg * 4;
  const float* b0p = beta_s + ((size_t)bh * 2 + 0) * 512;
  const float* b1p = beta_s + ((size_t)bh * 2 + 1) * 512;
  const float* gp  = ge_s + (size_t)bh * 512;
  const float* dp  = dots_s + (size_t)bh * 3 * 512;

#pragma unroll
  for (int i = 0; i < 2; ++i) {
    int c4 = lane + i * 64;
    *(f32x4*)&lds_bg[0][c4 * 4] = *(const f32x4*)(gp  + c4 * 4);
    *(f32x4*)&lds_bg[1][c4 * 4] = *(const f32x4*)(b0p + c4 * 4);
    *(f32x4*)&lds_bg[2][c4 * 4] = *(const f32x4*)(b1p + c4 * 4);
    *(f32x4*)&lds_bg[3][c4 * 4] = *(const f32x4*)(dp + 0 * 512 + c4 * 4);
    *(f32x4*)&lds_bg[4][c4 * 4] = *(const f32x4*)(dp + 1 * 512 + c4 * 4);
    *(f32x4*)&lds_bg[5][c4 * 4] = *(const f32x4*)(dp + 2 * 512 + c4 * 4);
  }

  const int vhalf = lane >> 5;
  const int vli = lane & 31;
  const int vtl = vli >> 2, vc = vli & 3;
  const float* vsrc = vhalf ? g_v1w : g_v0w;

#define LD1(j) { Gk0_##j = p0[lane + j * 64]; Gk1_##j = p1[lane + j * 64]; Gq_##j = pq[lane + j * 64]; }
#define LOAD_G(T) { const f32x4* __restrict__ p0 = (const f32x4*)(g_k0 + (size_t)(T) * 1024); \
                    const f32x4* __restrict__ p1 = (const f32x4*)(g_k1 + (size_t)(T) * 1024); \
                    const f32x4* __restrict__ pq = (const f32x4*)(g_q  + (size_t)(T) * 1024); \
                    R4(LD1) }
#define LOAD_V(T) { Gv = vsrc[(size_t)(T) * 1024 + vtl * 128 + vc]; }
#define WR1(j) { int g_ = lane + 64 * j; int tl_ = g_ >> 5; int kr_ = (g_ & 31) >> 1; \
                 int c_ = 4 * (g_ & 1); \
    *(f32x4*)&lds[bsel][((tl_ * 3 + 0) * 16 + kr_) * CH + c_] = Gk0_##j; \
    *(f32x4*)&lds[bsel][((tl_ * 3 + 1) * 16 + kr_) * CH + c_] = Gk1_##j; \
    *(f32x4*)&lds[bsel][((tl_ * 3 + 2) * 16 + kr_) * CH + c_] = Gq_##j; }
#define WRITE_G(b) { const int bsel = (b); R4(WR1) }
#define WRITE_V(b) { vbuf[b][vhalf][vtl][vc] = Gv; }

#define LOAD_SET(S, bufx, tlx, tg) { \
    const f32x4* __restrict__ pk0 = (const f32x4*)&lds[bufx][(((tlx) * 3 + 0) * 16 + kr) * CH]; \
    const f32x4* __restrict__ pk1 = (const f32x4*)&lds[bufx][(((tlx) * 3 + 1) * 16 + kr) * CH]; \
    const f32x4* __restrict__ pqq = (const f32x4*)&lds[bufx][(((tlx) * 3 + 2) * 16 + kr) * CH]; \
    S##_a0 = pk0[0]; S##_a1 = pk0[1]; \
    S##_b0 = pk1[0]; S##_b1 = pk1[1]; \
    S##_c0 = pqq[0]; S##_c1 = pqq[1]; \
    S##_eg  = lds_bg[0][tg]; S##_bb0 = lds_bg[1][tg]; S##_bb1 = lds_bg[2][tg]; \
    S##_d01 = lds_bg[3][tg]; S##_dq0 = lds_bg[4][tg]; S##_dq1 = lds_bg[5][tg]; \
    S##_mv0 = vbuf[bufx][0][tlx][vi]; S##_mv1 = vbuf[bufx][1][tlx][vi]; } \
    __builtin_amdgcn_sched_barrier(0);

#define COMPUTE(S, tt) { \
    s0 *= S##_eg; s1 *= S##_eg; \
    f32x4 r0v = S##_a0 * s0; r0v += S##_a1 * s1; \
    f32x4 r1v = S##_b0 * s0; r1v += S##_b1 * s1; \
    f32x4 rqv = S##_c0 * s0; rqv += S##_c1 * s1; \
    float p0 = (r0v[0] + r0v[1]) + (r0v[2] + r0v[3]); \
    float p1 = (r1v[0] + r1v[1]) + (r1v[2] + r1v[3]); \
    float pq2 = (rqv[0] + rqv[1]) + (rqv[2] + rqv[3]); \
    p0 += dpp_xor1(p0);    p1 += dpp_xor1(p1);    pq2 += dpp_xor1(pq2); \
    p0 += dpp_xor2(p0);    p1 += dpp_xor2(p1);    pq2 += dpp_xor2(pq2); \
    p0 += dpp_hmirror(p0); p1 += dpp_hmirror(p1); pq2 += dpp_hmirror(pq2); \
    p0 += dpp_rmirror(p0); p1 += dpp_rmirror(p1); pq2 += dpp_rmirror(pq2); \
    const float u0 = (S##_mv0 - p0) * S##_bb0; \
    const float u1 = (S##_mv1 - p1 - S##_d01 * u0) * S##_bb1; \
    const float oo = pq2 + S##_dq0 * u0 + S##_dq1 * u1; \
    s0 += S##_a0 * u0; s1 += S##_a1 * u0; \
    s0 += S##_b0 * u1; s1 += S##_b1 * u1; \
    if (kr == 0) o_s[((size_t)bh * 512 + (tt)) * 128 + v] = oo; }

  LOAD_G(0) LOAD_V(0)
  WRITE_G(0) WRITE_V(0)
  LOAD_G(1) LOAD_V(1)
  LOAD_SET(A, 0, 0, 0)

  for (int T = 0; T < 64; ++T) {
    const int buf = T & 1;
    if (T < 63) { WRITE_G(buf ^ 1) WRITE_V(buf ^ 1) }
    if (T < 62) { LOAD_G(T + 2) LOAD_V(T + 2) }
    const int t0 = T * 8;
    LOAD_SET(B, buf, 1, t0 + 1)                  COMPUTE(A, t0 + 0)
    LOAD_SET(A, buf, 2, t0 + 2)                  COMPUTE(B, t0 + 1)
    LOAD_SET(B, buf, 3, t0 + 3)                  COMPUTE(A, t0 + 2)
    LOAD_SET(A, buf, 4, t0 + 4)                  COMPUTE(B, t0 + 3)
    LOAD_SET(B, buf, 5, t0 + 5)                  COMPUTE(A, t0 + 4)
    LOAD_SET(A, buf, 6, t0 + 6)                  COMPUTE(B, t0 + 5)
    LOAD_SET(B, buf, 7, t0 + 7)                  COMPUTE(A, t0 + 6)
    LOAD_SET(A, buf ^ 1, 0, (t0 + 8) & 511)     COMPUTE(B, t0 + 7)
  }

  float* base = state_out + (size_t)bh * 128 * 128 + v;
#pragma unroll
  for (int i = 0; i < 4; ++i) {
    base[(kr * 8 + i) * 128]     = s0[i];
    base[(kr * 8 + 4 + i) * 128] = s1[i];
  }
}

// ---------------- rmsnorm + gate silu -> bf16 A for final GEMM ----------------
__global__ __launch_bounds__(128) void post_kernel(const float* __restrict__ o_s,
                                                   const float* __restrict__ qkvg,
                                                   const float* __restrict__ norm_w,
                                                   __hip_bfloat16* __restrict__ Afin) {
  int bt = blockIdx.x;
  int h = blockIdx.y;
  int d = threadIdx.x;
  int b = bt >> 9, t = bt & 511;
  int bh = b * 8 + h;
  float o = o_s[((size_t)bh * 512 + t) * 128 + d];
  __shared__ float red[2];
  float ss = o * o;
#pragma unroll
  for (int off = 32; off; off >>= 1) ss += __shfl_down(ss, off);
  if ((d & 63) == 0) red[d >> 6] = ss;
  __syncthreads();
  float mean = (red[0] + red[1]) * (1.f / 128.f);
  float r = rsqrtf(mean + 1e-5f);
  float gate = qkvg[(size_t)bt * NFUSE + 5120 + h * 128 + d];
  float val = o * r * norm_w[d] * silu_f(gate);
  Afin[(size_t)bt * 1024 + h * 128 + d] = __float2bfloat16(val);
}

extern "C" void kernel_launch(void* const* d_in, const int* in_sizes, int n_in,
                              void* d_out, int out_size, void* d_ws, size_t ws_size,
                              hipStream_t stream) {
  const float* x       = (const float*)d_in[0];
  const float* Wq      = (const float*)d_in[1];
  const float* Wk      = (const float*)d_in[2];
  const float* Wv      = (const float*)d_in[3];
  const float* Wb      = (const float*)d_in[4];
  const float* Wa      = (const float*)d_in[5];
  const float* A_log   = (const float*)d_in[6];
  const float* dt_bias = (const float*)d_in[7];
  const float* cqw     = (const float*)d_in[8];
  const float* ckw     = (const float*)d_in[9];
  const float* cvw     = (const float*)d_in[10];
  const float* Wg      = (const float*)d_in[11];
  const float* norm_w  = (const float*)d_in[12];
  const float* Wo      = (const float*)d_in[13];

  char* ws = (char*)d_ws;
  size_t off = 0;
  auto alloc = [&](size_t bytes) {
    void* p = ws + off;
    off += (bytes + 255) & ~(size_t)255;
    return p;
  };
  __hip_bfloat16* xbf  = (__hip_bfloat16*)alloc((size_t)2097152 * 2);
  __hip_bfloat16* WT   = (__hip_bfloat16*)alloc((size_t)NFUSE * 2048 * 2);  // fused q|k|v|g, [N][K]
  __hip_bfloat16* WoT  = (__hip_bfloat16*)alloc((size_t)2097152 * 2);
  float* qkvg   = (float*)alloc((size_t)ROWS * NFUSE * 4);
  float* q_s    = (float*)alloc((size_t)1048576 * 4);
  float* k_s    = (float*)alloc((size_t)2097152 * 4);
  float* v_s    = (float*)alloc((size_t)2097152 * 4);
  float* beta_s = (float*)alloc((size_t)16384 * 4);
  float* ge_s   = (float*)alloc((size_t)8192 * 4);
  float* dots_s = (float*)alloc((size_t)16 * 3 * 512 * 4);
  float* o_s    = (float*)alloc((size_t)1048576 * 4);
  __hip_bfloat16* Afin = (__hip_bfloat16*)alloc((size_t)1048576 * 2);

  float* out_main  = (float*)d_out;
  float* out_state = out_main + 2097152;

  dim3 tb(32, 8);
  f2bf_kernel<<<8192, 256, 0, stream>>>(x, xbf, 2097152);
  transpose5_kernel<<<dim3(64, 64, 5), tb, 0, stream>>>(Wq, Wk, Wv, Wg, Wo, WT, WoT);

  gemm_bf16<<<dim3(48, 8), 256, 0, stream>>>(xbf, WT, qkvg, 1024, NFUSE, 2048);
  ba_fused_kernel<<<1024, 64, 0, stream>>>(x, Wb, Wa, A_log, dt_bias, beta_s, ge_s);

  conv_qkv_kernel<<<dim3(1024, 40), 128, 0, stream>>>(qkvg, cqw, ckw, cvw, q_s, k_s, v_s);
  dots_kernel<<<dim3(16, 64), 64, 0, stream>>>(q_s, k_s, dots_s);

  scan_kernel<<<512, 64, 0, stream>>>(q_s, k_s, v_s, beta_s, ge_s, dots_s, o_s, out_state);

  post_kernel<<<dim3(1024, 8), 128, 0, stream>>>(o_s, qkvg, norm_w, Afin);
  gemm_bf16<<<dim3(16, 8), 256, 0, stream>>>(Afin, WoT, out_main, 1024, 2048, 1024);
}

// Round 11
// 251.183 us; speedup vs baseline: 18.9613x; 1.0192x over previous
//
#include <hip/hip_runtime.h>
#include <hip/hip_bf16.h>
#include <cmath>

#define B_   2
#define L_   512
#define HID  2048
#define DH   128
#define NH   8
#define NHH  2
#define ROWS 1024  // B_*L_
#define NFUSE 6144 // 1024(q)+2048(k)+2048(v)+1024(g)

typedef float  f32x2  __attribute__((ext_vector_type(2)));
typedef float  f32x4  __attribute__((ext_vector_type(4)));
typedef __bf16 bf16x8 __attribute__((ext_vector_type(8)));

#define AS1(p) ((const __attribute__((address_space(1))) unsigned int*)(p))
#define AS3(p) ((__attribute__((address_space(3))) unsigned int*)(p))

__device__ __forceinline__ float dpp_xor1(float x) {
  int r = __builtin_amdgcn_update_dpp(0, __float_as_int(x), 0xB1, 0xF, 0xF, true);
  return __int_as_float(r);
}
__device__ __forceinline__ float dpp_xor2(float x) {
  int r = __builtin_amdgcn_update_dpp(0, __float_as_int(x), 0x4E, 0xF, 0xF, true);
  return __int_as_float(r);
}
__device__ __forceinline__ float dpp_hmirror(float x) {  // mirror within 8
  int r = __builtin_amdgcn_update_dpp(0, __float_as_int(x), 0x141, 0xF, 0xF, true);
  return __int_as_float(r);
}
__device__ __forceinline__ float dpp_rmirror(float x) {  // mirror within 16
  int r = __builtin_amdgcn_update_dpp(0, __float_as_int(x), 0x140, 0xF, 0xF, true);
  return __int_as_float(r);
}

// ---------------- f32 -> bf16 elementwise ----------------
__global__ void f2bf_kernel(const float* __restrict__ in, __hip_bfloat16* __restrict__ out, int n) {
  int i = blockIdx.x * 256 + threadIdx.x;
  if (i < n) out[i] = __float2bfloat16(in[i]);
}

// ---------------- 5 weight transposes in one dispatch (blockIdx.z selects) -------
__global__ __launch_bounds__(256) void transpose5_kernel(const float* __restrict__ Wq,
                                                         const float* __restrict__ Wk,
                                                         const float* __restrict__ Wv,
                                                         const float* __restrict__ Wg,
                                                         const float* __restrict__ Wo,
                                                         __hip_bfloat16* __restrict__ WT,
                                                         __hip_bfloat16* __restrict__ WoT) {
  const float* in; __hip_bfloat16* out; int K, N;
  switch (blockIdx.z) {
    case 0: in = Wq; out = WT;                          K = 2048; N = 1024; break;
    case 1: in = Wk; out = WT + (size_t)1024 * 2048;    K = 2048; N = 2048; break;
    case 2: in = Wv; out = WT + (size_t)3072 * 2048;    K = 2048; N = 2048; break;
    case 3: in = Wg; out = WT + (size_t)5120 * 2048;    K = 2048; N = 1024; break;
    default: in = Wo; out = WoT;                        K = 1024; N = 2048; break;
  }
  __shared__ float tile[32][33];
  int n0 = blockIdx.x * 32, k0 = blockIdx.y * 32;
  if (n0 >= N || k0 >= K) return;
  int tx = threadIdx.x, ty = threadIdx.y;  // 32 x 8
#pragma unroll
  for (int i = 0; i < 32; i += 8)
    tile[ty + i][tx] = in[(size_t)(k0 + ty + i) * N + n0 + tx];
  __syncthreads();
#pragma unroll
  for (int i = 0; i < 32; i += 8)
    out[(size_t)(n0 + ty + i) * K + k0 + tx] = __float2bfloat16(tile[tx][ty + i]);
}

// ---------------- bf16 MFMA GEMM: C(MxN) = A(MxK) * BT(NxK)^T ----------------
__global__ __launch_bounds__(256) void gemm_bf16(const __hip_bfloat16* __restrict__ A,
                                                 const __hip_bfloat16* __restrict__ BT,
                                                 float* __restrict__ C, int M, int N, int K) {
  __shared__ __align__(16) __hip_bfloat16 lA[128 * 32];
  __shared__ __align__(16) __hip_bfloat16 lB[128 * 32];
  const int tid = threadIdx.x;
  const int lane = tid & 63;
  const int w = tid >> 6;
  const int wr = w >> 1, wc = w & 1;
  const int row0 = blockIdx.y * 128;
  const int col0 = blockIdx.x * 128;
  f32x4 acc[4][4];
#pragma unroll
  for (int m = 0; m < 4; ++m)
#pragma unroll
    for (int n = 0; n < 4; ++n) acc[m][n] = {0.f, 0.f, 0.f, 0.f};
  const int fr = lane & 15;
  const int ko = (lane >> 4) * 8;
  for (int kt = 0; kt < K; kt += 32) {
#pragma unroll
    for (int i = 0; i < 2; ++i) {
      int elem = (w * 2 + i) * 512 + lane * 8;
      int rr = elem >> 5, cc = elem & 31;
      const __hip_bfloat16* srcA = A + (size_t)(row0 + rr) * K + kt + cc;
      __builtin_amdgcn_global_load_lds(AS1(srcA), AS3(&lA[(w * 2 + i) * 512]), 16, 0, 0);
      const __hip_bfloat16* srcB = BT + (size_t)(col0 + rr) * K + kt + cc;
      __builtin_amdgcn_global_load_lds(AS1(srcB), AS3(&lB[(w * 2 + i) * 512]), 16, 0, 0);
    }
    __syncthreads();
    bf16x8 af[4], bfr[4];
#pragma unroll
    for (int m = 0; m < 4; ++m)
      af[m] = *reinterpret_cast<const bf16x8*>(&lA[(wr * 64 + m * 16 + fr) * 32 + ko]);
#pragma unroll
    for (int n = 0; n < 4; ++n)
      bfr[n] = *reinterpret_cast<const bf16x8*>(&lB[(wc * 64 + n * 16 + fr) * 32 + ko]);
#pragma unroll
    for (int m = 0; m < 4; ++m)
#pragma unroll
      for (int n = 0; n < 4; ++n)
        acc[m][n] = __builtin_amdgcn_mfma_f32_16x16x32_bf16(af[m], bfr[n], acc[m][n], 0, 0, 0);
    __syncthreads();
  }
  const int rq = (lane >> 4) * 4;
#pragma unroll
  for (int m = 0; m < 4; ++m)
#pragma unroll
    for (int n = 0; n < 4; ++n)
#pragma unroll
      for (int r = 0; r < 4; ++r)
        C[(size_t)(row0 + wr * 64 + m * 16 + rq + r) * N + (col0 + wc * 64 + n * 16 + fr)] =
            acc[m][n][r];
}

__device__ __forceinline__ float silu_f(float y) { return y / (1.f + __expf(-y)); }

// ---------------- fused x@Wb / x@Wa + beta/g transforms (one block per row) ------
__global__ __launch_bounds__(64) void ba_fused_kernel(const float* __restrict__ x,
                                                      const float* __restrict__ Wb,
                                                      const float* __restrict__ Wa,
                                                      const float* __restrict__ A_log,
                                                      const float* __restrict__ dt_bias,
                                                      float* __restrict__ beta_s,
                                                      float* __restrict__ ge_s) {
  const int row = blockIdx.x;   // b*512 + t
  const int lane = threadIdx.x;
  f32x4 aB0 = {0,0,0,0}, aB1 = {0,0,0,0}, aB2 = {0,0,0,0}, aB3 = {0,0,0,0};
  f32x4 aA0 = {0,0,0,0}, aA1 = {0,0,0,0};
  const float* xr = x + (size_t)row * HID;
  for (int i = 0; i < 32; ++i) {
    int k = lane + i * 64;
    float xv = xr[k];
    const f32x4* wb4 = (const f32x4*)(Wb + (size_t)k * 16);
    const f32x4* wa4 = (const f32x4*)(Wa + (size_t)k * 8);
    aB0 += wb4[0] * xv; aB1 += wb4[1] * xv; aB2 += wb4[2] * xv; aB3 += wb4[3] * xv;
    aA0 += wa4[0] * xv; aA1 += wa4[1] * xv;
  }
  __shared__ float red[64][25];
#pragma unroll
  for (int c = 0; c < 4; ++c) {
    red[lane][0 + c]  = aB0[c];
    red[lane][4 + c]  = aB1[c];
    red[lane][8 + c]  = aB2[c];
    red[lane][12 + c] = aB3[c];
    red[lane][16 + c] = aA0[c];
    red[lane][20 + c] = aA1[c];
  }
  // single wave: in-order LDS, no barrier needed
  if (lane < 24) {
    float s = 0.f;
#pragma unroll 8
    for (int i = 0; i < 64; ++i) s += red[i][lane];
    int b = row >> 9, t = row & 511;
    if (lane < 16) {
      int j = lane >> 3, h = lane & 7;
      beta_s[(((size_t)(b * 8 + h)) * 2 + j) * 512 + t] = 2.f / (1.f + __expf(-s));
    } else {
      int h = lane - 16;
      float vv = s + dt_bias[h];
      float sp = (vv > 20.f) ? vv : log1pf(__expf(vv));
      ge_s[((size_t)(b * 8 + h)) * 512 + t] = __expf(-__expf(A_log[h]) * sp);
    }
  }
}

// ---------------- fused conv + silu (+l2norm for q/k) for q,k,v ----------------
__global__ __launch_bounds__(128) void conv_qkv_kernel(const float* __restrict__ qkvg,
                                                       const float* __restrict__ wq,
                                                       const float* __restrict__ wk,
                                                       const float* __restrict__ wv,
                                                       float* __restrict__ q_s,
                                                       float* __restrict__ k_s,
                                                       float* __restrict__ v_s) {
  int bt = blockIdx.x;
  int yy = blockIdx.y;
  int d  = threadIdx.x;
  int b = bt >> 9, t = bt & 511;
  __shared__ float red[2];
  if (yy < 8) {
    int h = yy, c = h * 128 + d;
    float y = 0.f;
#pragma unroll
    for (int tau = 0; tau < 4; ++tau) {
      int tt = t - 3 + tau;
      float xv = (tt >= 0) ? qkvg[(size_t)(b * 512 + tt) * NFUSE + c] : 0.f;
      y += xv * wq[c * 4 + tau];
    }
    y = silu_f(y);
    float ss = y * y;
#pragma unroll
    for (int off = 32; off; off >>= 1) ss += __shfl_down(ss, off);
    if ((d & 63) == 0) red[d >> 6] = ss;
    __syncthreads();
    float scale = (1.f / fmaxf(sqrtf(red[0] + red[1]), 1e-12f)) * 0.08838834764831845f;
    q_s[((size_t)(b * 8 + h) * 512 + t) * 128 + d] = y * scale;
  } else if (yy < 24) {
    int jh = yy - 8;
    int j = jh >> 3, h = jh & 7;
    int c = j * 1024 + h * 128 + d;
    float y = 0.f;
#pragma unroll
    for (int tau = 0; tau < 4; ++tau) {
      int tt = t - 3 + tau;
      float xv = (tt >= 0) ? qkvg[(size_t)(b * 512 + tt) * NFUSE + 1024 + c] : 0.f;
      y += xv * wk[c * 4 + tau];
    }
    y = silu_f(y);
    float ss = y * y;
#pragma unroll
    for (int off = 32; off; off >>= 1) ss += __shfl_down(ss, off);
    if ((d & 63) == 0) red[d >> 6] = ss;
    __syncthreads();
    float scale = 1.f / fmaxf(sqrtf(red[0] + red[1]), 1e-12f);
    k_s[(((size_t)(b * 8 + h) * 2 + j) * 512 + t) * 128 + d] = y * scale;
  } else {
    int jh = yy - 24;
    int j = jh >> 3, h = jh & 7;
    int c = j * 1024 + h * 128 + d;
    float y = 0.f;
#pragma unroll
    for (int tau = 0; tau < 4; ++tau) {
      int tt = t - 3 + tau;
      float xv = (tt >= 0) ? qkvg[(size_t)(b * 512 + tt) * NFUSE + 3072 + c] : 0.f;
      y += xv * wv[c * 4 + tau];
    }
    v_s[(((size_t)(b * 8 + h) * 2 + j) * 512 + t) * 128 + d] = silu_f(y);
  }
}

// ---------------- pair cross-dots (input-only), 12 scalars per pair p=t/2 -------
// 0:d01A 1:dq0A 2:dq1A 3:d01B 4:dq0B 5:dq1B 6:c00 7:c01 8:c10 9:c11 10:cq0 11:cq1
// A = step 2p, B = step 2p+1; cXY = k{X}B . k{Y}A, cqY = qB . k{Y}A.
__global__ __launch_bounds__(64) void dots_kernel(const float* __restrict__ q_s,
                                                  const float* __restrict__ k_s,
                                                  float* __restrict__ dots_s) {
  const int bh = blockIdx.x;     // 0..15
  const int py = blockIdx.y;     // 0..31
  const int lane = threadIdx.x;
  const int e  = lane & 7;       // 16-float slice
  const int pl = lane >> 3;      // pair-in-block 0..7
  const int p = py * 8 + pl;     // pair 0..255
  const int tA = 2 * p;
  const float* k0A = k_s + ((size_t)bh * 2 + 0) * 512 * 128 + (size_t)tA * 128 + e * 16;
  const float* k1A = k_s + ((size_t)bh * 2 + 1) * 512 * 128 + (size_t)tA * 128 + e * 16;
  const float* qA  = q_s + (size_t)bh * 512 * 128 + (size_t)tA * 128 + e * 16;
  float d0=0,d1=0,d2=0,d3=0,d4=0,d5=0,d6=0,d7=0,d8=0,d9=0,d10=0,d11=0;
#pragma unroll
  for (int i = 0; i < 4; ++i) {
    f32x4 a0 = *(const f32x4*)(k0A + i * 4);
    f32x4 a1 = *(const f32x4*)(k1A + i * 4);
    f32x4 qa = *(const f32x4*)(qA  + i * 4);
    f32x4 b0 = *(const f32x4*)(k0A + 128 + i * 4);
    f32x4 b1 = *(const f32x4*)(k1A + 128 + i * 4);
    f32x4 qb = *(const f32x4*)(qA  + 128 + i * 4);
    f32x4 t;
#define HS(acc, u, w) t = (u) * (w); acc += (t[0] + t[1]) + (t[2] + t[3]);
    HS(d0, a1, a0) HS(d1, qa, a0) HS(d2, qa, a1)
    HS(d3, b1, b0) HS(d4, qb, b0) HS(d5, qb, b1)
    HS(d6, b0, a0) HS(d7, b0, a1) HS(d8, b1, a0) HS(d9, b1, a1)
    HS(d10, qb, a0) HS(d11, qb, a1)
#undef HS
  }
#define RED(dd) dd += dpp_xor1(dd); dd += dpp_xor2(dd); dd += dpp_hmirror(dd);
  RED(d0) RED(d1) RED(d2) RED(d3) RED(d4) RED(d5)
  RED(d6) RED(d7) RED(d8) RED(d9) RED(d10) RED(d11)
#undef RED
  if (e == 0) {
    float* dst = dots_s + (size_t)bh * 12 * 256 + p;
    dst[0*256]=d0; dst[1*256]=d1; dst[2*256]=d2;  dst[3*256]=d3;
    dst[4*256]=d4; dst[5*256]=d5; dst[6*256]=d6;  dst[7*256]=d7;
    dst[8*256]=d8; dst[9*256]=d9; dst[10*256]=d10; dst[11*256]=d11;
  }
}

// ---------------- scan: 2-step blocked (mini-WY) — ONE dep-round per 2 steps -----
// 512 blocks x 64 thr (one wave, no barriers) = 16 chains x 32 v-groups.
// Rounds 8-10 lesson: wall time == sequential-round count x round latency;
// widening/pipelining were null. So: merge steps (A=2p, B=2p+1) into one round.
// 6 state-dots on OLD S (parallel, one DPP pipeline), cross-step interactions
// via precomputed input dots, scalar chain -> u0A,u1A,u0B,u1B,oA,oB, fused
// update S = gA*gB*S + k0A(gB u0A) + k1A(gB u1A) + k0B u0B + k1B u1B.
// Per-pair scalars packed 20-wide in LDS -> 5 broadcast ds_read_b128.
#define R4(X) X(0) X(1) X(2) X(3)
#define CH 12                        // padded chunk stride (8 data + 4)
#define TSTEP 8
#define STEPF (3 * 16 * CH)          // 576 floats per step
#define TILEF (TSTEP * STEPF)        // 4608 floats per buffer

__global__ __launch_bounds__(64, 1) void scan_kernel(const float* __restrict__ q_s,
                                                     const float* __restrict__ k_s,
                                                     const float* __restrict__ v_s,
                                                     const float* __restrict__ beta_s,
                                                     const float* __restrict__ ge_s,
                                                     const float* __restrict__ dots_s,
                                                     float* __restrict__ o_s,
                                                     float* __restrict__ state_out) {
  const int blk = blockIdx.x;      // 0..511
  const int bh  = blk >> 5;        // chain 0..15
  const int wg  = blk & 31;        // v-group 0..31 (4 cols)
  const int lane = threadIdx.x;    // 0..63
  const int kr = lane & 15;        // k-sixteenth 0..15
  const int vi = lane >> 4;        // 0..3
  const int v  = wg * 4 + vi;      // global v column

  __shared__ __align__(16) float lds[2][TILEF];
  __shared__ __align__(16) float vbuf[2][2][TSTEP][4];
  __shared__ __align__(16) float lds_sc[256][20];  // packed per-pair scalars

  f32x4 s0 = {0.f, 0.f, 0.f, 0.f}, s1 = {0.f, 0.f, 0.f, 0.f};
#define DECLG(j) f32x4 Gk0_##j, Gk1_##j, Gq_##j;
  R4(DECLG)
#undef DECLG
  float Gv;
#define DECLSET(S) f32x4 S##_a0A,S##_a1A,S##_b0A,S##_b1A,S##_c0A,S##_c1A, \
                         S##_a0B,S##_a1B,S##_b0B,S##_b1B,S##_c0B,S##_c1B; \
  float S##_gA,S##_gB,S##_bb0A,S##_bb1A,S##_bb0B,S##_bb1B, \
        S##_d01A,S##_dq0A,S##_dq1A,S##_d01B,S##_dq0B,S##_dq1B, \
        S##_c00,S##_c01,S##_c10,S##_c11,S##_cq0,S##_cq1, \
        S##_mv0A,S##_mv1A,S##_mv0B,S##_mv1B;
  DECLSET(A) DECLSET(B)
#undef DECLSET

  const float* g_k0 = k_s + ((size_t)bh * 2 + 0) * 512 * 128;
  const float* g_k1 = k_s + ((size_t)bh * 2 + 1) * 512 * 128;
  const float* g_q  = q_s + (size_t)bh * 512 * 128;
  const float* g_v0w = v_s + ((size_t)bh * 2 + 0) * 512 * 128 + wg * 4;
  const float* g_v1w = v_s + ((size_t)bh * 2 + 1) * 512 * 128 + wg * 4;
  const float* b0p = beta_s + ((size_t)bh * 2 + 0) * 512;
  const float* b1p = beta_s + ((size_t)bh * 2 + 1) * 512;
  const float* gp  = ge_s + (size_t)bh * 512;
  const float* dp  = dots_s + (size_t)bh * 12 * 256;

  // pack per-pair scalars: {gA,gB,b0A,b1A, b0B,b1B,d01A,dq0A, dq1A,d01B,dq0B,dq1B,
  //                         c00,c01,c10,c11, cq0,cq1,pad,pad}
#pragma unroll
  for (int i = 0; i < 4; ++i) {
    int p = lane + i * 64;
    int tA = 2 * p;
    lds_sc[p][0] = gp[tA];      lds_sc[p][1] = gp[tA + 1];
    lds_sc[p][2] = b0p[tA];     lds_sc[p][3] = b1p[tA];
    lds_sc[p][4] = b0p[tA + 1]; lds_sc[p][5] = b1p[tA + 1];
#pragma unroll
    for (int j = 0; j < 12; ++j) lds_sc[p][6 + j] = dp[j * 256 + p];
  }

  const int vhalf = lane >> 5;
  const int vli = lane & 31;
  const int vtl = vli >> 2, vc = vli & 3;
  const float* vsrc = vhalf ? g_v1w : g_v0w;

#define LD1(j) { Gk0_##j = p0[lane + j * 64]; Gk1_##j = p1[lane + j * 64]; Gq_##j = pq[lane + j * 64]; }
#define LOAD_G(T) { const f32x4* __restrict__ p0 = (const f32x4*)(g_k0 + (size_t)(T) * 1024); \
                    const f32x4* __restrict__ p1 = (const f32x4*)(g_k1 + (size_t)(T) * 1024); \
                    const f32x4* __restrict__ pq = (const f32x4*)(g_q  + (size_t)(T) * 1024); \
                    R4(LD1) }
#define LOAD_V(T) { Gv = vsrc[(size_t)(T) * 1024 + vtl * 128 + vc]; }
#define WR1(j) { int g_ = lane + 64 * j; int tl_ = g_ >> 5; int kr_ = (g_ & 31) >> 1; \
                 int c_ = 4 * (g_ & 1); \
    *(f32x4*)&lds[bsel][((tl_ * 3 + 0) * 16 + kr_) * CH + c_] = Gk0_##j; \
    *(f32x4*)&lds[bsel][((tl_ * 3 + 1) * 16 + kr_) * CH + c_] = Gk1_##j; \
    *(f32x4*)&lds[bsel][((tl_ * 3 + 2) * 16 + kr_) * CH + c_] = Gq_##j; }
#define WRITE_G(b) { const int bsel = (b); R4(WR1) }
#define WRITE_V(b) { vbuf[b][vhalf][vtl][vc] = Gv; }

#define LOAD_PAIR(S, bufx, tlx, pg) { \
    const f32x4* pk0A_ = (const f32x4*)&lds[bufx][(((tlx) * 3 + 0) * 16 + kr) * CH]; \
    const f32x4* pk1A_ = (const f32x4*)&lds[bufx][(((tlx) * 3 + 1) * 16 + kr) * CH]; \
    const f32x4* pqA_  = (const f32x4*)&lds[bufx][(((tlx) * 3 + 2) * 16 + kr) * CH]; \
    const f32x4* pk0B_ = (const f32x4*)&lds[bufx][((((tlx) + 1) * 3 + 0) * 16 + kr) * CH]; \
    const f32x4* pk1B_ = (const f32x4*)&lds[bufx][((((tlx) + 1) * 3 + 1) * 16 + kr) * CH]; \
    const f32x4* pqB_  = (const f32x4*)&lds[bufx][((((tlx) + 1) * 3 + 2) * 16 + kr) * CH]; \
    S##_a0A = pk0A_[0]; S##_a1A = pk0A_[1]; \
    S##_b0A = pk1A_[0]; S##_b1A = pk1A_[1]; \
    S##_c0A = pqA_[0];  S##_c1A = pqA_[1]; \
    S##_a0B = pk0B_[0]; S##_a1B = pk0B_[1]; \
    S##_b0B = pk1B_[0]; S##_b1B = pk1B_[1]; \
    S##_c0B = pqB_[0];  S##_c1B = pqB_[1]; \
    const f32x4* sc_ = (const f32x4*)&lds_sc[(pg) & 255][0]; \
    f32x4 y0_ = sc_[0], y1_ = sc_[1], y2_ = sc_[2], y3_ = sc_[3], y4_ = sc_[4]; \
    S##_gA = y0_[0]; S##_gB = y0_[1]; S##_bb0A = y0_[2]; S##_bb1A = y0_[3]; \
    S##_bb0B = y1_[0]; S##_bb1B = y1_[1]; S##_d01A = y1_[2]; S##_dq0A = y1_[3]; \
    S##_dq1A = y2_[0]; S##_d01B = y2_[1]; S##_dq0B = y2_[2]; S##_dq1B = y2_[3]; \
    S##_c00 = y3_[0]; S##_c01 = y3_[1]; S##_c10 = y3_[2]; S##_c11 = y3_[3]; \
    S##_cq0 = y4_[0]; S##_cq1 = y4_[1]; \
    S##_mv0A = vbuf[bufx][0][tlx][vi]; S##_mv1A = vbuf[bufx][1][tlx][vi]; \
    S##_mv0B = vbuf[bufx][0][(tlx) + 1][vi]; S##_mv1B = vbuf[bufx][1][(tlx) + 1][vi]; } \
    __builtin_amdgcn_sched_barrier(0);

#define COMPUTE_PAIR(S, pg) { \
    f32x4 r0A_ = S##_a0A * s0; r0A_ += S##_a1A * s1; \
    f32x4 r1A_ = S##_b0A * s0; r1A_ += S##_b1A * s1; \
    f32x4 rqA_ = S##_c0A * s0; rqA_ += S##_c1A * s1; \
    f32x4 r0B_ = S##_a0B * s0; r0B_ += S##_a1B * s1; \
    f32x4 r1B_ = S##_b0B * s0; r1B_ += S##_b1B * s1; \
    f32x4 rqB_ = S##_c0B * s0; rqB_ += S##_c1B * s1; \
    float h0A = (r0A_[0] + r0A_[1]) + (r0A_[2] + r0A_[3]); \
    float h1A = (r1A_[0] + r1A_[1]) + (r1A_[2] + r1A_[3]); \
    float hqA = (rqA_[0] + rqA_[1]) + (rqA_[2] + rqA_[3]); \
    float h0B = (r0B_[0] + r0B_[1]) + (r0B_[2] + r0B_[3]); \
    float h1B = (r1B_[0] + r1B_[1]) + (r1B_[2] + r1B_[3]); \
    float hqB = (rqB_[0] + rqB_[1]) + (rqB_[2] + rqB_[3]); \
    h0A += dpp_xor1(h0A); h1A += dpp_xor1(h1A); hqA += dpp_xor1(hqA); \
    h0B += dpp_xor1(h0B); h1B += dpp_xor1(h1B); hqB += dpp_xor1(hqB); \
    h0A += dpp_xor2(h0A); h1A += dpp_xor2(h1A); hqA += dpp_xor2(hqA); \
    h0B += dpp_xor2(h0B); h1B += dpp_xor2(h1B); hqB += dpp_xor2(hqB); \
    h0A += dpp_hmirror(h0A); h1A += dpp_hmirror(h1A); hqA += dpp_hmirror(hqA); \
    h0B += dpp_hmirror(h0B); h1B += dpp_hmirror(h1B); hqB += dpp_hmirror(hqB); \
    h0A += dpp_rmirror(h0A); h1A += dpp_rmirror(h1A); hqA += dpp_rmirror(hqA); \
    h0B += dpp_rmirror(h0B); h1B += dpp_rmirror(h1B); hqB += dpp_rmirror(hqB); \
    const float u0A_ = (S##_mv0A - S##_gA * h0A) * S##_bb0A; \
    const float u1A_ = (S##_mv1A - S##_gA * h1A - S##_d01A * u0A_) * S##_bb1A; \
    const float u0B_ = (S##_mv0B - S##_gB * (S##_gA * h0B + S##_c00 * u0A_ + S##_c01 * u1A_)) * S##_bb0B; \
    const float u1B_ = (S##_mv1B - S##_gB * (S##_gA * h1B + S##_c10 * u0A_ + S##_c11 * u1A_) \
                        - S##_d01B * u0B_) * S##_bb1B; \
    const float oA_ = S##_gA * hqA + S##_dq0A * u0A_ + S##_dq1A * u1A_; \
    const float oB_ = S##_gB * (S##_gA * hqB + S##_cq0 * u0A_ + S##_cq1 * u1A_) \
                      + S##_dq0B * u0B_ + S##_dq1B * u1B_; \
    const float gg_ = S##_gA * S##_gB; \
    const float w0_ = S##_gB * u0A_, w1_ = S##_gB * u1A_; \
    s0 *= gg_; s0 += S##_a0A * w0_; s0 += S##_b0A * w1_; s0 += S##_a0B * u0B_; s0 += S##_b0B * u1B_; \
    s1 *= gg_; s1 += S##_a1A * w0_; s1 += S##_b1A * w1_; s1 += S##_a1B * u0B_; s1 += S##_b1B * u1B_; \
    if (kr == 0) { const int tA_ = 2 * (pg); \
      o_s[((size_t)bh * 512 + tA_) * 128 + v] = oA_; \
      o_s[((size_t)bh * 512 + tA_ + 1) * 128 + v] = oB_; } }

  LOAD_G(0) LOAD_V(0)
  WRITE_G(0) WRITE_V(0)
  LOAD_G(1) LOAD_V(1)
  LOAD_PAIR(A, 0, 0, 0)

  for (int T = 0; T < 64; ++T) {
    const int buf = T & 1;
    if (T < 63) { WRITE_G(buf ^ 1) WRITE_V(buf ^ 1) }
    if (T < 62) { LOAD_G(T + 2) LOAD_V(T + 2) }
    const int p0i = T * 4;
    LOAD_PAIR(B, buf, 2, p0i + 1)              COMPUTE_PAIR(A, p0i + 0)
    LOAD_PAIR(A, buf, 4, p0i + 2)              COMPUTE_PAIR(B, p0i + 1)
    LOAD_PAIR(B, buf, 6, p0i + 3)              COMPUTE_PAIR(A, p0i + 2)
    LOAD_PAIR(A, buf ^ 1, 0, (p0i + 4) & 255)  COMPUTE_PAIR(B, p0i + 3)
  }

  float* base = state_out + (size_t)bh * 128 * 128 + v;
#pragma unroll
  for (int i = 0; i < 4; ++i) {
    base[(kr * 8 + i) * 128]     = s0[i];
    base[(kr * 8 + 4 + i) * 128] = s1[i];
  }
}

// ---------------- rmsnorm + gate silu -> bf16 A for final GEMM ----------------
__global__ __launch_bounds__(128) void post_kernel(const float* __restrict__ o_s,
                                                   const float* __restrict__ qkvg,
                                                   const float* __restrict__ norm_w,
                                                   __hip_bfloat16* __restrict__ Afin) {
  int bt = blockIdx.x;
  int h = blockIdx.y;
  int d = threadIdx.x;
  int b = bt >> 9, t = bt & 511;
  int bh = b * 8 + h;
  float o = o_s[((size_t)bh * 512 + t) * 128 + d];
  __shared__ float red[2];
  float ss = o * o;
#pragma unroll
  for (int off = 32; off; off >>= 1) ss += __shfl_down(ss, off);
  if ((d & 63) == 0) red[d >> 6] = ss;
  __syncthreads();
  float mean = (red[0] + red[1]) * (1.f / 128.f);
  float r = rsqrtf(mean + 1e-5f);
  float gate = qkvg[(size_t)bt * NFUSE + 5120 + h * 128 + d];
  float val = o * r * norm_w[d] * silu_f(gate);
  Afin[(size_t)bt * 1024 + h * 128 + d] = __float2bfloat16(val);
}

extern "C" void kernel_launch(void* const* d_in, const int* in_sizes, int n_in,
                              void* d_out, int out_size, void* d_ws, size_t ws_size,
                              hipStream_t stream) {
  const float* x       = (const float*)d_in[0];
  const float* Wq      = (const float*)d_in[1];
  const float* Wk      = (const float*)d_in[2];
  const float* Wv      = (const float*)d_in[3];
  const float* Wb      = (const float*)d_in[4];
  const float* Wa      = (const float*)d_in[5];
  const float* A_log   = (const float*)d_in[6];
  const float* dt_bias = (const float*)d_in[7];
  const float* cqw     = (const float*)d_in[8];
  const float* ckw     = (const float*)d_in[9];
  const float* cvw     = (const float*)d_in[10];
  const float* Wg      = (const float*)d_in[11];
  const float* norm_w  = (const float*)d_in[12];
  const float* Wo      = (const float*)d_in[13];

  char* ws = (char*)d_ws;
  size_t off = 0;
  auto alloc = [&](size_t bytes) {
    void* p = ws + off;
    off += (bytes + 255) & ~(size_t)255;
    return p;
  };
  __hip_bfloat16* xbf  = (__hip_bfloat16*)alloc((size_t)2097152 * 2);
  __hip_bfloat16* WT   = (__hip_bfloat16*)alloc((size_t)NFUSE * 2048 * 2);  // fused q|k|v|g, [N][K]
  __hip_bfloat16* WoT  = (__hip_bfloat16*)alloc((size_t)2097152 * 2);
  float* qkvg   = (float*)alloc((size_t)ROWS * NFUSE * 4);
  float* q_s    = (float*)alloc((size_t)1048576 * 4);
  float* k_s    = (float*)alloc((size_t)2097152 * 4);
  float* v_s    = (float*)alloc((size_t)2097152 * 4);
  float* beta_s = (float*)alloc((size_t)16384 * 4);
  float* ge_s   = (float*)alloc((size_t)8192 * 4);
  float* dots_s = (float*)alloc((size_t)16 * 12 * 256 * 4);
  float* o_s    = (float*)alloc((size_t)1048576 * 4);
  __hip_bfloat16* Afin = (__hip_bfloat16*)alloc((size_t)1048576 * 2);

  float* out_main  = (float*)d_out;
  float* out_state = out_main + 2097152;

  dim3 tb(32, 8);
  f2bf_kernel<<<8192, 256, 0, stream>>>(x, xbf, 2097152);
  transpose5_kernel<<<dim3(64, 64, 5), tb, 0, stream>>>(Wq, Wk, Wv, Wg, Wo, WT, WoT);

  gemm_bf16<<<dim3(48, 8), 256, 0, stream>>>(xbf, WT, qkvg, 1024, NFUSE, 2048);
  ba_fused_kernel<<<1024, 64, 0, stream>>>(x, Wb, Wa, A_log, dt_bias, beta_s, ge_s);

  conv_qkv_kernel<<<dim3(1024, 40), 128, 0, stream>>>(qkvg, cqw, ckw, cvw, q_s, k_s, v_s);
  dots_kernel<<<dim3(16, 32), 64, 0, stream>>>(q_s, k_s, dots_s);

  scan_kernel<<<512, 64, 0, stream>>>(q_s, k_s, v_s, beta_s, ge_s, dots_s, o_s, out_state);

  post_kernel<<<dim3(1024, 8), 128, 0, stream>>>(o_s, qkvg, norm_w, Afin);
  gemm_bf16<<<dim3(16, 8), 256, 0, stream>>>(Afin, WoT, out_main, 1024, 2048, 1024);
}

// Round 12
// 241.317 us; speedup vs baseline: 19.7365x; 1.0409x over previous
//
#include <hip/hip_runtime.h>
#include <hip/hip_bf16.h>
#include <cmath>

#define B_   2
#define L_   512
#define HID  2048
#define DH   128
#define NH   8
#define NHH  2
#define ROWS 1024  // B_*L_
#define NFUSE 6144 // 1024(q)+2048(k)+2048(v)+1024(g)

typedef float  f32x2  __attribute__((ext_vector_type(2)));
typedef float  f32x4  __attribute__((ext_vector_type(4)));
typedef __bf16 bf16x8 __attribute__((ext_vector_type(8)));

#define AS1(p) ((const __attribute__((address_space(1))) unsigned int*)(p))
#define AS3(p) ((__attribute__((address_space(3))) unsigned int*)(p))

__device__ __forceinline__ float dpp_xor1(float x) {
  int r = __builtin_amdgcn_update_dpp(0, __float_as_int(x), 0xB1, 0xF, 0xF, true);
  return __int_as_float(r);
}
__device__ __forceinline__ float dpp_xor2(float x) {
  int r = __builtin_amdgcn_update_dpp(0, __float_as_int(x), 0x4E, 0xF, 0xF, true);
  return __int_as_float(r);
}
__device__ __forceinline__ float dpp_hmirror(float x) {  // mirror within 8
  int r = __builtin_amdgcn_update_dpp(0, __float_as_int(x), 0x141, 0xF, 0xF, true);
  return __int_as_float(r);
}
__device__ __forceinline__ float dpp_rmirror(float x) {  // mirror within 16
  int r = __builtin_amdgcn_update_dpp(0, __float_as_int(x), 0x140, 0xF, 0xF, true);
  return __int_as_float(r);
}

// ---------------- f32 -> bf16 elementwise ----------------
__global__ void f2bf_kernel(const float* __restrict__ in, __hip_bfloat16* __restrict__ out, int n) {
  int i = blockIdx.x * 256 + threadIdx.x;
  if (i < n) out[i] = __float2bfloat16(in[i]);
}

// ---------------- 5 weight transposes in one dispatch (blockIdx.z selects) -------
__global__ __launch_bounds__(256) void transpose5_kernel(const float* __restrict__ Wq,
                                                         const float* __restrict__ Wk,
                                                         const float* __restrict__ Wv,
                                                         const float* __restrict__ Wg,
                                                         const float* __restrict__ Wo,
                                                         __hip_bfloat16* __restrict__ WT,
                                                         __hip_bfloat16* __restrict__ WoT) {
  const float* in; __hip_bfloat16* out; int K, N;
  switch (blockIdx.z) {
    case 0: in = Wq; out = WT;                          K = 2048; N = 1024; break;
    case 1: in = Wk; out = WT + (size_t)1024 * 2048;    K = 2048; N = 2048; break;
    case 2: in = Wv; out = WT + (size_t)3072 * 2048;    K = 2048; N = 2048; break;
    case 3: in = Wg; out = WT + (size_t)5120 * 2048;    K = 2048; N = 1024; break;
    default: in = Wo; out = WoT;                        K = 1024; N = 2048; break;
  }
  __shared__ float tile[32][33];
  int n0 = blockIdx.x * 32, k0 = blockIdx.y * 32;
  if (n0 >= N || k0 >= K) return;
  int tx = threadIdx.x, ty = threadIdx.y;  // 32 x 8
#pragma unroll
  for (int i = 0; i < 32; i += 8)
    tile[ty + i][tx] = in[(size_t)(k0 + ty + i) * N + n0 + tx];
  __syncthreads();
#pragma unroll
  for (int i = 0; i < 32; i += 8)
    out[(size_t)(n0 + ty + i) * K + k0 + tx] = __float2bfloat16(tile[tx][ty + i]);
}

// ---------------- bf16 MFMA GEMM, 64x128 tile: C(MxN) = A(MxK) * BT(NxK)^T -------
// BM=64 BN=128 BK=32, 256 thr = 4 waves; wave w owns 64x32 output (cols w*32..),
// frags 4(m) x 2(n) of 16x16x32. Round-11 rationale: the 128x128-tile grids gave
// 1.5 blocks/CU (gemm1) and 0.5 blocks/CU (gemm2) -> idle CUs; 64-row tiles give
// 768 / 256 blocks = balanced 3 / 1 blocks per CU.
__global__ __launch_bounds__(256) void gemm_bf16_64(const __hip_bfloat16* __restrict__ A,
                                                    const __hip_bfloat16* __restrict__ BT,
                                                    float* __restrict__ C, int M, int N, int K) {
  __shared__ __align__(16) __hip_bfloat16 lA[64 * 32];
  __shared__ __align__(16) __hip_bfloat16 lB[128 * 32];
  const int tid = threadIdx.x;
  const int lane = tid & 63;
  const int w = tid >> 6;          // wave 0..3 = output col block
  const int row0 = blockIdx.y * 64;
  const int col0 = blockIdx.x * 128;
  f32x4 acc[4][2];
#pragma unroll
  for (int m = 0; m < 4; ++m)
#pragma unroll
    for (int n = 0; n < 2; ++n) acc[m][n] = {0.f, 0.f, 0.f, 0.f};
  const int fr = lane & 15;
  const int ko = (lane >> 4) * 8;
  for (int kt = 0; kt < K; kt += 32) {
    {  // stage A: 2048 elems, one 16B/lane load per wave
      int elem = (w * 64 + lane) * 8;
      int rr = elem >> 5, cc = elem & 31;
      const __hip_bfloat16* srcA = A + (size_t)(row0 + rr) * K + kt + cc;
      __builtin_amdgcn_global_load_lds(AS1(srcA), AS3(&lA[w * 512]), 16, 0, 0);
    }
#pragma unroll
    for (int i = 0; i < 2; ++i) {  // stage B: 4096 elems, two loads per wave
      int elem = ((i * 4 + w) * 64 + lane) * 8;
      int rr = elem >> 5, cc = elem & 31;
      const __hip_bfloat16* srcB = BT + (size_t)(col0 + rr) * K + kt + cc;
      __builtin_amdgcn_global_load_lds(AS1(srcB), AS3(&lB[(i * 4 + w) * 512]), 16, 0, 0);
    }
    __syncthreads();
    bf16x8 af[4], bfr[2];
#pragma unroll
    for (int m = 0; m < 4; ++m)
      af[m] = *reinterpret_cast<const bf16x8*>(&lA[(m * 16 + fr) * 32 + ko]);
#pragma unroll
    for (int n = 0; n < 2; ++n)
      bfr[n] = *reinterpret_cast<const bf16x8*>(&lB[(w * 32 + n * 16 + fr) * 32 + ko]);
#pragma unroll
    for (int m = 0; m < 4; ++m)
#pragma unroll
      for (int n = 0; n < 2; ++n)
        acc[m][n] = __builtin_amdgcn_mfma_f32_16x16x32_bf16(af[m], bfr[n], acc[m][n], 0, 0, 0);
    __syncthreads();
  }
  const int rq = (lane >> 4) * 4;
#pragma unroll
  for (int m = 0; m < 4; ++m)
#pragma unroll
    for (int n = 0; n < 2; ++n)
#pragma unroll
      for (int r = 0; r < 4; ++r)
        C[(size_t)(row0 + m * 16 + rq + r) * N + (col0 + w * 32 + n * 16 + fr)] =
            acc[m][n][r];
}

__device__ __forceinline__ float silu_f(float y) { return y / (1.f + __expf(-y)); }

// ---------------- fused x@Wb / x@Wa + beta/g transforms (one block per row) ------
__global__ __launch_bounds__(64) void ba_fused_kernel(const float* __restrict__ x,
                                                      const float* __restrict__ Wb,
                                                      const float* __restrict__ Wa,
                                                      const float* __restrict__ A_log,
                                                      const float* __restrict__ dt_bias,
                                                      float* __restrict__ beta_s,
                                                      float* __restrict__ ge_s) {
  const int row = blockIdx.x;   // b*512 + t
  const int lane = threadIdx.x;
  f32x4 aB0 = {0,0,0,0}, aB1 = {0,0,0,0}, aB2 = {0,0,0,0}, aB3 = {0,0,0,0};
  f32x4 aA0 = {0,0,0,0}, aA1 = {0,0,0,0};
  const float* xr = x + (size_t)row * HID;
  for (int i = 0; i < 32; ++i) {
    int k = lane + i * 64;
    float xv = xr[k];
    const f32x4* wb4 = (const f32x4*)(Wb + (size_t)k * 16);
    const f32x4* wa4 = (const f32x4*)(Wa + (size_t)k * 8);
    aB0 += wb4[0] * xv; aB1 += wb4[1] * xv; aB2 += wb4[2] * xv; aB3 += wb4[3] * xv;
    aA0 += wa4[0] * xv; aA1 += wa4[1] * xv;
  }
  __shared__ float red[64][25];
#pragma unroll
  for (int c = 0; c < 4; ++c) {
    red[lane][0 + c]  = aB0[c];
    red[lane][4 + c]  = aB1[c];
    red[lane][8 + c]  = aB2[c];
    red[lane][12 + c] = aB3[c];
    red[lane][16 + c] = aA0[c];
    red[lane][20 + c] = aA1[c];
  }
  // single wave: in-order LDS, no barrier needed
  if (lane < 24) {
    float s = 0.f;
#pragma unroll 8
    for (int i = 0; i < 64; ++i) s += red[i][lane];
    int b = row >> 9, t = row & 511;
    if (lane < 16) {
      int j = lane >> 3, h = lane & 7;
      beta_s[(((size_t)(b * 8 + h)) * 2 + j) * 512 + t] = 2.f / (1.f + __expf(-s));
    } else {
      int h = lane - 16;
      float vv = s + dt_bias[h];
      float sp = (vv > 20.f) ? vv : log1pf(__expf(vv));
      ge_s[((size_t)(b * 8 + h)) * 512 + t] = __expf(-__expf(A_log[h]) * sp);
    }
  }
}

// ---------------- fused conv + silu (+l2norm for q/k) for q,k,v ----------------
__global__ __launch_bounds__(128) void conv_qkv_kernel(const float* __restrict__ qkvg,
                                                       const float* __restrict__ wq,
                                                       const float* __restrict__ wk,
                                                       const float* __restrict__ wv,
                                                       float* __restrict__ q_s,
                                                       float* __restrict__ k_s,
                                                       float* __restrict__ v_s) {
  int bt = blockIdx.x;
  int yy = blockIdx.y;
  int d  = threadIdx.x;
  int b = bt >> 9, t = bt & 511;
  __shared__ float red[2];
  if (yy < 8) {
    int h = yy, c = h * 128 + d;
    float y = 0.f;
#pragma unroll
    for (int tau = 0; tau < 4; ++tau) {
      int tt = t - 3 + tau;
      float xv = (tt >= 0) ? qkvg[(size_t)(b * 512 + tt) * NFUSE + c] : 0.f;
      y += xv * wq[c * 4 + tau];
    }
    y = silu_f(y);
    float ss = y * y;
#pragma unroll
    for (int off = 32; off; off >>= 1) ss += __shfl_down(ss, off);
    if ((d & 63) == 0) red[d >> 6] = ss;
    __syncthreads();
    float scale = (1.f / fmaxf(sqrtf(red[0] + red[1]), 1e-12f)) * 0.08838834764831845f;
    q_s[((size_t)(b * 8 + h) * 512 + t) * 128 + d] = y * scale;
  } else if (yy < 24) {
    int jh = yy - 8;
    int j = jh >> 3, h = jh & 7;
    int c = j * 1024 + h * 128 + d;
    float y = 0.f;
#pragma unroll
    for (int tau = 0; tau < 4; ++tau) {
      int tt = t - 3 + tau;
      float xv = (tt >= 0) ? qkvg[(size_t)(b * 512 + tt) * NFUSE + 1024 + c] : 0.f;
      y += xv * wk[c * 4 + tau];
    }
    y = silu_f(y);
    float ss = y * y;
#pragma unroll
    for (int off = 32; off; off >>= 1) ss += __shfl_down(ss, off);
    if ((d & 63) == 0) red[d >> 6] = ss;
    __syncthreads();
    float scale = 1.f / fmaxf(sqrtf(red[0] + red[1]), 1e-12f);
    k_s[(((size_t)(b * 8 + h) * 2 + j) * 512 + t) * 128 + d] = y * scale;
  } else {
    int jh = yy - 24;
    int j = jh >> 3, h = jh & 7;
    int c = j * 1024 + h * 128 + d;
    float y = 0.f;
#pragma unroll
    for (int tau = 0; tau < 4; ++tau) {
      int tt = t - 3 + tau;
      float xv = (tt >= 0) ? qkvg[(size_t)(b * 512 + tt) * NFUSE + 3072 + c] : 0.f;
      y += xv * wv[c * 4 + tau];
    }
    v_s[(((size_t)(b * 8 + h) * 2 + j) * 512 + t) * 128 + d] = silu_f(y);
  }
}

// ---------------- pair cross-dots (input-only), 12 scalars per pair p=t/2 -------
__global__ __launch_bounds__(64) void dots_kernel(const float* __restrict__ q_s,
                                                  const float* __restrict__ k_s,
                                                  float* __restrict__ dots_s) {
  const int bh = blockIdx.x;     // 0..15
  const int py = blockIdx.y;     // 0..31
  const int lane = threadIdx.x;
  const int e  = lane & 7;       // 16-float slice
  const int pl = lane >> 3;      // pair-in-block 0..7
  const int p = py * 8 + pl;     // pair 0..255
  const int tA = 2 * p;
  const float* k0A = k_s + ((size_t)bh * 2 + 0) * 512 * 128 + (size_t)tA * 128 + e * 16;
  const float* k1A = k_s + ((size_t)bh * 2 + 1) * 512 * 128 + (size_t)tA * 128 + e * 16;
  const float* qA  = q_s + (size_t)bh * 512 * 128 + (size_t)tA * 128 + e * 16;
  float d0=0,d1=0,d2=0,d3=0,d4=0,d5=0,d6=0,d7=0,d8=0,d9=0,d10=0,d11=0;
#pragma unroll
  for (int i = 0; i < 4; ++i) {
    f32x4 a0 = *(const f32x4*)(k0A + i * 4);
    f32x4 a1 = *(const f32x4*)(k1A + i * 4);
    f32x4 qa = *(const f32x4*)(qA  + i * 4);
    f32x4 b0 = *(const f32x4*)(k0A + 128 + i * 4);
    f32x4 b1 = *(const f32x4*)(k1A + 128 + i * 4);
    f32x4 qb = *(const f32x4*)(qA  + 128 + i * 4);
    f32x4 t;
#define HS(acc, u, w) t = (u) * (w); acc += (t[0] + t[1]) + (t[2] + t[3]);
    HS(d0, a1, a0) HS(d1, qa, a0) HS(d2, qa, a1)
    HS(d3, b1, b0) HS(d4, qb, b0) HS(d5, qb, b1)
    HS(d6, b0, a0) HS(d7, b0, a1) HS(d8, b1, a0) HS(d9, b1, a1)
    HS(d10, qb, a0) HS(d11, qb, a1)
#undef HS
  }
#define RED(dd) dd += dpp_xor1(dd); dd += dpp_xor2(dd); dd += dpp_hmirror(dd);
  RED(d0) RED(d1) RED(d2) RED(d3) RED(d4) RED(d5)
  RED(d6) RED(d7) RED(d8) RED(d9) RED(d10) RED(d11)
#undef RED
  if (e == 0) {
    float* dst = dots_s + (size_t)bh * 12 * 256 + p;
    dst[0*256]=d0; dst[1*256]=d1; dst[2*256]=d2;  dst[3*256]=d3;
    dst[4*256]=d4; dst[5*256]=d5; dst[6*256]=d6;  dst[7*256]=d7;
    dst[8*256]=d8; dst[9*256]=d9; dst[10*256]=d10; dst[11*256]=d11;
  }
}

// ---------------- scan: 2-step blocked (mini-WY) — ONE dep-round per 2 steps -----
#define R4(X) X(0) X(1) X(2) X(3)
#define CH 12                        // padded chunk stride (8 data + 4)
#define TSTEP 8
#define STEPF (3 * 16 * CH)          // 576 floats per step
#define TILEF (TSTEP * STEPF)        // 4608 floats per buffer

__global__ __launch_bounds__(64, 1) void scan_kernel(const float* __restrict__ q_s,
                                                     const float* __restrict__ k_s,
                                                     const float* __restrict__ v_s,
                                                     const float* __restrict__ beta_s,
                                                     const float* __restrict__ ge_s,
                                                     const float* __restrict__ dots_s,
                                                     float* __restrict__ o_s,
                                                     float* __restrict__ state_out) {
  const int blk = blockIdx.x;      // 0..511
  const int bh  = blk >> 5;        // chain 0..15
  const int wg  = blk & 31;        // v-group 0..31 (4 cols)
  const int lane = threadIdx.x;    // 0..63
  const int kr = lane & 15;        // k-sixteenth 0..15
  const int vi = lane >> 4;        // 0..3
  const int v  = wg * 4 + vi;      // global v column

  __shared__ __align__(16) float lds[2][TILEF];
  __shared__ __align__(16) float vbuf[2][2][TSTEP][4];
  __shared__ __align__(16) float lds_sc[256][20];  // packed per-pair scalars

  f32x4 s0 = {0.f, 0.f, 0.f, 0.f}, s1 = {0.f, 0.f, 0.f, 0.f};
#define DECLG(j) f32x4 Gk0_##j, Gk1_##j, Gq_##j;
  R4(DECLG)
#undef DECLG
  float Gv;
#define DECLSET(S) f32x4 S##_a0A,S##_a1A,S##_b0A,S##_b1A,S##_c0A,S##_c1A, \
                         S##_a0B,S##_a1B,S##_b0B,S##_b1B,S##_c0B,S##_c1B; \
  float S##_gA,S##_gB,S##_bb0A,S##_bb1A,S##_bb0B,S##_bb1B, \
        S##_d01A,S##_dq0A,S##_dq1A,S##_d01B,S##_dq0B,S##_dq1B, \
        S##_c00,S##_c01,S##_c10,S##_c11,S##_cq0,S##_cq1, \
        S##_mv0A,S##_mv1A,S##_mv0B,S##_mv1B;
  DECLSET(A) DECLSET(B)
#undef DECLSET

  const float* g_k0 = k_s + ((size_t)bh * 2 + 0) * 512 * 128;
  const float* g_k1 = k_s + ((size_t)bh * 2 + 1) * 512 * 128;
  const float* g_q  = q_s + (size_t)bh * 512 * 128;
  const float* g_v0w = v_s + ((size_t)bh * 2 + 0) * 512 * 128 + wg * 4;
  const float* g_v1w = v_s + ((size_t)bh * 2 + 1) * 512 * 128 + wg * 4;
  const float* b0p = beta_s + ((size_t)bh * 2 + 0) * 512;
  const float* b1p = beta_s + ((size_t)bh * 2 + 1) * 512;
  const float* gp  = ge_s + (size_t)bh * 512;
  const float* dp  = dots_s + (size_t)bh * 12 * 256;

  // pack per-pair scalars: {gA,gB,b0A,b1A, b0B,b1B,d01A,dq0A, dq1A,d01B,dq0B,dq1B,
  //                         c00,c01,c10,c11, cq0,cq1,pad,pad}
#pragma unroll
  for (int i = 0; i < 4; ++i) {
    int p = lane + i * 64;
    int tA = 2 * p;
    lds_sc[p][0] = gp[tA];      lds_sc[p][1] = gp[tA + 1];
    lds_sc[p][2] = b0p[tA];     lds_sc[p][3] = b1p[tA];
    lds_sc[p][4] = b0p[tA + 1]; lds_sc[p][5] = b1p[tA + 1];
#pragma unroll
    for (int j = 0; j < 12; ++j) lds_sc[p][6 + j] = dp[j * 256 + p];
  }

  const int vhalf = lane >> 5;
  const int vli = lane & 31;
  const int vtl = vli >> 2, vc = vli & 3;
  const float* vsrc = vhalf ? g_v1w : g_v0w;

#define LD1(j) { Gk0_##j = p0[lane + j * 64]; Gk1_##j = p1[lane + j * 64]; Gq_##j = pq[lane + j * 64]; }
#define LOAD_G(T) { const f32x4* __restrict__ p0 = (const f32x4*)(g_k0 + (size_t)(T) * 1024); \
                    const f32x4* __restrict__ p1 = (const f32x4*)(g_k1 + (size_t)(T) * 1024); \
                    const f32x4* __restrict__ pq = (const f32x4*)(g_q  + (size_t)(T) * 1024); \
                    R4(LD1) }
#define LOAD_V(T) { Gv = vsrc[(size_t)(T) * 1024 + vtl * 128 + vc]; }
#define WR1(j) { int g_ = lane + 64 * j; int tl_ = g_ >> 5; int kr_ = (g_ & 31) >> 1; \
                 int c_ = 4 * (g_ & 1); \
    *(f32x4*)&lds[bsel][((tl_ * 3 + 0) * 16 + kr_) * CH + c_] = Gk0_##j; \
    *(f32x4*)&lds[bsel][((tl_ * 3 + 1) * 16 + kr_) * CH + c_] = Gk1_##j; \
    *(f32x4*)&lds[bsel][((tl_ * 3 + 2) * 16 + kr_) * CH + c_] = Gq_##j; }
#define WRITE_G(b) { const int bsel = (b); R4(WR1) }
#define WRITE_V(b) { vbuf[b][vhalf][vtl][vc] = Gv; }

#define LOAD_PAIR(S, bufx, tlx, pg) { \
    const f32x4* pk0A_ = (const f32x4*)&lds[bufx][(((tlx) * 3 + 0) * 16 + kr) * CH]; \
    const f32x4* pk1A_ = (const f32x4*)&lds[bufx][(((tlx) * 3 + 1) * 16 + kr) * CH]; \
    const f32x4* pqA_  = (const f32x4*)&lds[bufx][(((tlx) * 3 + 2) * 16 + kr) * CH]; \
    const f32x4* pk0B_ = (const f32x4*)&lds[bufx][((((tlx) + 1) * 3 + 0) * 16 + kr) * CH]; \
    const f32x4* pk1B_ = (const f32x4*)&lds[bufx][((((tlx) + 1) * 3 + 1) * 16 + kr) * CH]; \
    const f32x4* pqB_  = (const f32x4*)&lds[bufx][((((tlx) + 1) * 3 + 2) * 16 + kr) * CH]; \
    S##_a0A = pk0A_[0]; S##_a1A = pk0A_[1]; \
    S##_b0A = pk1A_[0]; S##_b1A = pk1A_[1]; \
    S##_c0A = pqA_[0];  S##_c1A = pqA_[1]; \
    S##_a0B = pk0B_[0]; S##_a1B = pk0B_[1]; \
    S##_b0B = pk1B_[0]; S##_b1B = pk1B_[1]; \
    S##_c0B = pqB_[0];  S##_c1B = pqB_[1]; \
    const f32x4* sc_ = (const f32x4*)&lds_sc[(pg) & 255][0]; \
    f32x4 y0_ = sc_[0], y1_ = sc_[1], y2_ = sc_[2], y3_ = sc_[3], y4_ = sc_[4]; \
    S##_gA = y0_[0]; S##_gB = y0_[1]; S##_bb0A = y0_[2]; S##_bb1A = y0_[3]; \
    S##_bb0B = y1_[0]; S##_bb1B = y1_[1]; S##_d01A = y1_[2]; S##_dq0A = y1_[3]; \
    S##_dq1A = y2_[0]; S##_d01B = y2_[1]; S##_dq0B = y2_[2]; S##_dq1B = y2_[3]; \
    S##_c00 = y3_[0]; S##_c01 = y3_[1]; S##_c10 = y3_[2]; S##_c11 = y3_[3]; \
    S##_cq0 = y4_[0]; S##_cq1 = y4_[1]; \
    S##_mv0A = vbuf[bufx][0][tlx][vi]; S##_mv1A = vbuf[bufx][1][tlx][vi]; \
    S##_mv0B = vbuf[bufx][0][(tlx) + 1][vi]; S##_mv1B = vbuf[bufx][1][(tlx) + 1][vi]; } \
    __builtin_amdgcn_sched_barrier(0);

#define COMPUTE_PAIR(S, pg) { \
    f32x4 r0A_ = S##_a0A * s0; r0A_ += S##_a1A * s1; \
    f32x4 r1A_ = S##_b0A * s0; r1A_ += S##_b1A * s1; \
    f32x4 rqA_ = S##_c0A * s0; rqA_ += S##_c1A * s1; \
    f32x4 r0B_ = S##_a0B * s0; r0B_ += S##_a1B * s1; \
    f32x4 r1B_ = S##_b0B * s0; r1B_ += S##_b1B * s1; \
    f32x4 rqB_ = S##_c0B * s0; rqB_ += S##_c1B * s1; \
    float h0A = (r0A_[0] + r0A_[1]) + (r0A_[2] + r0A_[3]); \
    float h1A = (r1A_[0] + r1A_[1]) + (r1A_[2] + r1A_[3]); \
    float hqA = (rqA_[0] + rqA_[1]) + (rqA_[2] + rqA_[3]); \
    float h0B = (r0B_[0] + r0B_[1]) + (r0B_[2] + r0B_[3]); \
    float h1B = (r1B_[0] + r1B_[1]) + (r1B_[2] + r1B_[3]); \
    float hqB = (rqB_[0] + rqB_[1]) + (rqB_[2] + rqB_[3]); \
    h0A += dpp_xor1(h0A); h1A += dpp_xor1(h1A); hqA += dpp_xor1(hqA); \
    h0B += dpp_xor1(h0B); h1B += dpp_xor1(h1B); hqB += dpp_xor1(hqB); \
    h0A += dpp_xor2(h0A); h1A += dpp_xor2(h1A); hqA += dpp_xor2(hqA); \
    h0B += dpp_xor2(h0B); h1B += dpp_xor2(h1B); hqB += dpp_xor2(hqB); \
    h0A += dpp_hmirror(h0A); h1A += dpp_hmirror(h1A); hqA += dpp_hmirror(hqA); \
    h0B += dpp_hmirror(h0B); h1B += dpp_hmirror(h1B); hqB += dpp_hmirror(hqB); \
    h0A += dpp_rmirror(h0A); h1A += dpp_rmirror(h1A); hqA += dpp_rmirror(hqA); \
    h0B += dpp_rmirror(h0B); h1B += dpp_rmirror(h1B); hqB += dpp_rmirror(hqB); \
    const float u0A_ = (S##_mv0A - S##_gA * h0A) * S##_bb0A; \
    const float u1A_ = (S##_mv1A - S##_gA * h1A - S##_d01A * u0A_) * S##_bb1A; \
    const float u0B_ = (S##_mv0B - S##_gB * (S##_gA * h0B + S##_c00 * u0A_ + S##_c01 * u1A_)) * S##_bb0B; \
    const float u1B_ = (S##_mv1B - S##_gB * (S##_gA * h1B + S##_c10 * u0A_ + S##_c11 * u1A_) \
                        - S##_d01B * u0B_) * S##_bb1B; \
    const float oA_ = S##_gA * hqA + S##_dq0A * u0A_ + S##_dq1A * u1A_; \
    const float oB_ = S##_gB * (S##_gA * hqB + S##_cq0 * u0A_ + S##_cq1 * u1A_) \
                      + S##_dq0B * u0B_ + S##_dq1B * u1B_; \
    const float gg_ = S##_gA * S##_gB; \
    const float w0_ = S##_gB * u0A_, w1_ = S##_gB * u1A_; \
    s0 *= gg_; s0 += S##_a0A * w0_; s0 += S##_b0A * w1_; s0 += S##_a0B * u0B_; s0 += S##_b0B * u1B_; \
    s1 *= gg_; s1 += S##_a1A * w0_; s1 += S##_b1A * w1_; s1 += S##_a1B * u0B_; s1 += S##_b1B * u1B_; \
    if (kr == 0) { const int tA_ = 2 * (pg); \
      o_s[((size_t)bh * 512 + tA_) * 128 + v] = oA_; \
      o_s[((size_t)bh * 512 + tA_ + 1) * 128 + v] = oB_; } }

  LOAD_G(0) LOAD_V(0)
  WRITE_G(0) WRITE_V(0)
  LOAD_G(1) LOAD_V(1)
  LOAD_PAIR(A, 0, 0, 0)

  for (int T = 0; T < 64; ++T) {
    const int buf = T & 1;
    if (T < 63) { WRITE_G(buf ^ 1) WRITE_V(buf ^ 1) }
    if (T < 62) { LOAD_G(T + 2) LOAD_V(T + 2) }
    const int p0i = T * 4;
    LOAD_PAIR(B, buf, 2, p0i + 1)              COMPUTE_PAIR(A, p0i + 0)
    LOAD_PAIR(A, buf, 4, p0i + 2)              COMPUTE_PAIR(B, p0i + 1)
    LOAD_PAIR(B, buf, 6, p0i + 3)              COMPUTE_PAIR(A, p0i + 2)
    LOAD_PAIR(A, buf ^ 1, 0, (p0i + 4) & 255)  COMPUTE_PAIR(B, p0i + 3)
  }

  float* base = state_out + (size_t)bh * 128 * 128 + v;
#pragma unroll
  for (int i = 0; i < 4; ++i) {
    base[(kr * 8 + i) * 128]     = s0[i];
    base[(kr * 8 + 4 + i) * 128] = s1[i];
  }
}

// ---------------- rmsnorm + gate silu -> bf16 A for final GEMM ----------------
__global__ __launch_bounds__(128) void post_kernel(const float* __restrict__ o_s,
                                                   const float* __restrict__ qkvg,
                                                   const float* __restrict__ norm_w,
                                                   __hip_bfloat16* __restrict__ Afin) {
  int bt = blockIdx.x;
  int h = blockIdx.y;
  int d = threadIdx.x;
  int b = bt >> 9, t = bt & 511;
  int bh = b * 8 + h;
  float o = o_s[((size_t)bh * 512 + t) * 128 + d];
  __shared__ float red[2];
  float ss = o * o;
#pragma unroll
  for (int off = 32; off; off >>= 1) ss += __shfl_down(ss, off);
  if ((d & 63) == 0) red[d >> 6] = ss;
  __syncthreads();
  float mean = (red[0] + red[1]) * (1.f / 128.f);
  float r = rsqrtf(mean + 1e-5f);
  float gate = qkvg[(size_t)bt * NFUSE + 5120 + h * 128 + d];
  float val = o * r * norm_w[d] * silu_f(gate);
  Afin[(size_t)bt * 1024 + h * 128 + d] = __float2bfloat16(val);
}

extern "C" void kernel_launch(void* const* d_in, const int* in_sizes, int n_in,
                              void* d_out, int out_size, void* d_ws, size_t ws_size,
                              hipStream_t stream) {
  const float* x       = (const float*)d_in[0];
  const float* Wq      = (const float*)d_in[1];
  const float* Wk      = (const float*)d_in[2];
  const float* Wv      = (const float*)d_in[3];
  const float* Wb      = (const float*)d_in[4];
  const float* Wa      = (const float*)d_in[5];
  const float* A_log   = (const float*)d_in[6];
  const float* dt_bias = (const float*)d_in[7];
  const float* cqw     = (const float*)d_in[8];
  const float* ckw     = (const float*)d_in[9];
  const float* cvw     = (const float*)d_in[10];
  const float* Wg      = (const float*)d_in[11];
  const float* norm_w  = (const float*)d_in[12];
  const float* Wo      = (const float*)d_in[13];

  char* ws = (char*)d_ws;
  size_t off = 0;
  auto alloc = [&](size_t bytes) {
    void* p = ws + off;
    off += (bytes + 255) & ~(size_t)255;
    return p;
  };
  __hip_bfloat16* xbf  = (__hip_bfloat16*)alloc((size_t)2097152 * 2);
  __hip_bfloat16* WT   = (__hip_bfloat16*)alloc((size_t)NFUSE * 2048 * 2);  // fused q|k|v|g, [N][K]
  __hip_bfloat16* WoT  = (__hip_bfloat16*)alloc((size_t)2097152 * 2);
  float* qkvg   = (float*)alloc((size_t)ROWS * NFUSE * 4);
  float* q_s    = (float*)alloc((size_t)1048576 * 4);
  float* k_s    = (float*)alloc((size_t)2097152 * 4);
  float* v_s    = (float*)alloc((size_t)2097152 * 4);
  float* beta_s = (float*)alloc((size_t)16384 * 4);
  float* ge_s   = (float*)alloc((size_t)8192 * 4);
  float* dots_s = (float*)alloc((size_t)16 * 12 * 256 * 4);
  float* o_s    = (float*)alloc((size_t)1048576 * 4);
  __hip_bfloat16* Afin = (__hip_bfloat16*)alloc((size_t)1048576 * 2);

  float* out_main  = (float*)d_out;
  float* out_state = out_main + 2097152;

  dim3 tb(32, 8);
  f2bf_kernel<<<8192, 256, 0, stream>>>(x, xbf, 2097152);
  transpose5_kernel<<<dim3(64, 64, 5), tb, 0, stream>>>(Wq, Wk, Wv, Wg, Wo, WT, WoT);

  gemm_bf16_64<<<dim3(48, 16), 256, 0, stream>>>(xbf, WT, qkvg, 1024, NFUSE, 2048);
  ba_fused_kernel<<<1024, 64, 0, stream>>>(x, Wb, Wa, A_log, dt_bias, beta_s, ge_s);

  conv_qkv_kernel<<<dim3(1024, 40), 128, 0, stream>>>(qkvg, cqw, ckw, cvw, q_s, k_s, v_s);
  dots_kernel<<<dim3(16, 32), 64, 0, stream>>>(q_s, k_s, dots_s);

  scan_kernel<<<512, 64, 0, stream>>>(q_s, k_s, v_s, beta_s, ge_s, dots_s, o_s, out_state);

  post_kernel<<<dim3(1024, 8), 128, 0, stream>>>(o_s, qkvg, norm_w, Afin);
  gemm_bf16_64<<<dim3(16, 16), 256, 0, stream>>>(Afin, WoT, out_main, 1024, 2048, 1024);
}